// Round 10
// baseline (467.092 us; speedup 1.0000x reference)
//
#include <hip/hip_runtime.h>

#define N_TILE 50000
#define N_RR   50000
#define D      128
#define E_TT   800000
#define E_RT   400000
#define E_TR   400000
#define N_G    16
#define NB     ((N_TILE + 1023) / 1024)   // scan blocks per array (=49)
#define E_ALL  (E_TT + E_RT + E_TR)
#define BKT    16384                       // bins per bucket (16-bit packed LDS counters)
#define NBKT   ((N_TILE + BKT - 1) / BKT)  // =4
#define NCHK   25                          // edge chunks (all E divisible by 25)

static_assert(NB <= 64, "scan2 uses one wave per array");
static_assert(N_TILE == N_RR, "shared bucket geometry assumes equal node counts");
static_assert((BKT & (BKT - 1)) == 0, "bucket must be pow2");
static_assert(E_TT % NCHK == 0 && E_RT % NCHK == 0 && E_TR % NCHK == 0, "chunking");

typedef __attribute__((ext_vector_type(8))) short bf16x8;
typedef __attribute__((ext_vector_type(4))) float f32x4;
typedef unsigned short u16;

__device__ inline u16 f2bf(float f) {
  unsigned u = __float_as_uint(f);
  unsigned r = (u + 0x7FFFu + ((u >> 16) & 1u)) >> 16;   // RNE
  return (u16)r;
}
__device__ inline float bf2f(u16 h) { return __uint_as_float(((unsigned)h) << 16); }

// ---------------- bucketed LDS histogram + rank capture: NO global atomics ----
// 16384 bins / bucket, packed two 16-bit counters per LDS word.
// rank[e] (dst sides) = 16-bit half of the atomic return.
__global__ __launch_bounds__(256) void k_hist(
    const int* __restrict__ tt_src, const int* __restrict__ tt_dst,
    const int* __restrict__ rt_src, const int* __restrict__ rt_dst,
    const int* __restrict__ tr_src, const int* __restrict__ tr_dst,
    int* __restrict__ partial, int* __restrict__ rank) {
  __shared__ unsigned h[BKT / 2];
  int bid = blockIdx.x;
  int s = bid / (NBKT * NCHK);
  int rem = bid % (NBKT * NCHK);
  int b = rem / NCHK;
  int c = rem % NCHK;
  const int* arr; int E; int roff = 0;
  switch (s) {
    case 0: arr = tt_dst; E = E_TT; roff = 0; break;
    case 1: arr = rt_dst; E = E_RT; roff = E_TT; break;
    case 2: arr = tr_dst; E = E_TR; roff = E_TT + E_RT; break;
    case 3: arr = tt_src; E = E_TT; break;
    case 4: arr = rt_src; E = E_RT; break;
    default: arr = tr_src; E = E_TR; break;
  }
  bool isdst = s < 3;
  for (int j = threadIdx.x; j < BKT / 2; j += 256) h[j] = 0;
  __syncthreads();
  int ec = E / NCHK;
  int lo = c * ec, hi = lo + ec;
  int base = b * BKT;
  for (int i = lo + threadIdx.x; i < hi; i += 256) {
    unsigned int off = (unsigned int)(arr[i] - base);
    if (off < BKT) {
      unsigned sh = (off & 1u) << 4;
      unsigned r = atomicAdd(&h[off >> 1], 1u << sh);
      if (isdst) rank[roff + i] = (int)((r >> sh) & 0xffffu);
    }
  }
  __syncthreads();
  int* dst = partial + (size_t)(s * NCHK + c) * N_TILE;
  for (int j = threadIdx.x; j < BKT; j += 256) {
    int bin = base + j;
    if (bin < N_TILE)
      dst[bin] = (int)((h[j >> 1] >> ((j & 1) << 4)) & 0xffffu);
  }
}

// ---------------- reduce partials ----------------
__global__ __launch_bounds__(256) void k_hreduce(
    int* __restrict__ partial,
    int* __restrict__ id_tt, int* __restrict__ id_rt, int* __restrict__ id_tr,
    float* __restrict__ os_tt, float* __restrict__ os_rt, float* __restrict__ os_tr) {
  int t = blockIdx.x * 256 + threadIdx.x;
  if (t >= 6 * N_TILE) return;
  int s = t / N_TILE;
  int i = t - s * N_TILE;
  int* p = partial + (size_t)s * NCHK * N_TILE + i;
  int run = 0;
  if (s < 3) {
#pragma unroll
    for (int c = 0; c < NCHK; ++c) {
      int v = p[(size_t)c * N_TILE];
      p[(size_t)c * N_TILE] = run;
      run += v;
    }
    if (s == 0) id_tt[i] = run;
    else if (s == 1) id_rt[i] = run;
    else id_tr[i] = run;
  } else {
#pragma unroll
    for (int c = 0; c < NCHK; ++c) run += p[(size_t)c * N_TILE];
    float v = rsqrtf((float)max(run, 1));
    if (s == 3) os_tt[i] = v;
    else if (s == 4) os_rt[i] = v;
    else os_tr[i] = v;
  }
}

// ---------------- scan stage 1 ----------------
__global__ __launch_bounds__(1024) void k_scan1(const int* __restrict__ d0,
                                                const int* __restrict__ d1,
                                                const int* __restrict__ d2,
                                                int* __restrict__ p0,
                                                int* __restrict__ p1,
                                                int* __restrict__ p2,
                                                int* __restrict__ bsum) {
  int arr = blockIdx.x / NB;
  int blk = blockIdx.x % NB;
  const int* deg = arr == 0 ? d0 : (arr == 1 ? d1 : d2);
  int* part = arr == 0 ? p0 : (arr == 1 ? p1 : p2);
  __shared__ int ts[1024];
  int tid = threadIdx.x;
  int i = blk * 1024 + tid;
  int v = (i < N_TILE) ? deg[i] : 0;
  ts[tid] = v;
  __syncthreads();
  for (int d = 1; d < 1024; d <<= 1) {
    int t = (tid >= d) ? ts[tid - d] : 0;
    __syncthreads();
    ts[tid] += t;
    __syncthreads();
  }
  if (i < N_TILE) part[i] = ts[tid] - v;
  if (tid == 1023) bsum[arr * NB + blk] = ts[1023];
}

// ---------------- scan stage 2 ----------------
__global__ __launch_bounds__(256) void k_scan2(const int* __restrict__ bsum,
                                               int* __restrict__ bs) {
  int wv = threadIdx.x >> 6;
  int lane = threadIdx.x & 63;
  if (wv >= 3) return;
  int v = (lane < NB) ? bsum[wv * NB + lane] : 0;
  int orig = v;
#pragma unroll
  for (int o = 1; o < 64; o <<= 1) {
    int t = __shfl_up(v, o);
    if (lane >= o) v += t;
  }
  if (lane < NB) bs[wv * (NB + 1) + lane] = v - orig;
  if (lane == NB - 1) bs[wv * (NB + 1) + NB] = v;
}

// ---------------- finalize ----------------
__global__ void k_finalize(const int* __restrict__ pp_tt, const int* __restrict__ pp_rt,
                           const int* __restrict__ pp_tr, const int* __restrict__ bs,
                           int* __restrict__ rp_tt, int* __restrict__ rp_rt,
                           int* __restrict__ rp_tr,
                           const int* __restrict__ id_tt, const int* __restrict__ id_rt,
                           const int* __restrict__ id_tr,
                           float* __restrict__ is_tt, float* __restrict__ is_rt,
                           float* __restrict__ is_tr) {
  int i = blockIdx.x * blockDim.x + threadIdx.x;
  if (i >= N_TILE) return;
  int b = i >> 10;
  rp_tt[i] = pp_tt[i] + bs[0 * (NB + 1) + b];
  rp_rt[i] = pp_rt[i] + bs[1 * (NB + 1) + b];
  rp_tr[i] = pp_tr[i] + bs[2 * (NB + 1) + b];
  if (i == 0) {
    rp_tt[N_TILE] = bs[0 * (NB + 1) + NB];
    rp_rt[N_TILE] = bs[1 * (NB + 1) + NB];
    rp_tr[N_RR] = bs[2 * (NB + 1) + NB];
  }
  is_tt[i] = rsqrtf((float)max(id_tt[i], 1));
  is_rt[i] = rsqrtf((float)max(id_rt[i], 1));
  is_tr[i] = rsqrtf((float)max(id_tr[i], 1));
}

// ---------------- CSR fill: one thread per edge, atomic-free ----------------
__global__ __launch_bounds__(256) void k_fill(
    const int* __restrict__ tt_src, const int* __restrict__ tt_dst,
    const int* __restrict__ rt_src, const int* __restrict__ rt_dst,
    const int* __restrict__ tr_src, const int* __restrict__ tr_dst,
    const int* __restrict__ rp_tt, const int* __restrict__ rp_rt,
    const int* __restrict__ rp_tr,
    const float* __restrict__ os_tt, const float* __restrict__ os_rt,
    const float* __restrict__ os_tr,
    const int* __restrict__ partial, const int* __restrict__ rank,
    int2* __restrict__ pr_tt, int2* __restrict__ pr_rt, int2* __restrict__ pr_tr) {
  int i = blockIdx.x * 256 + threadIdx.x;
  if (i >= E_ALL) return;
  const int* srcA; const int* dstA; const int* rp; const float* os; int2* pr;
  int j, s, ec;
  if (i < E_TT) {
    s = 0; j = i; ec = E_TT / NCHK;
    srcA = tt_src; dstA = tt_dst; rp = rp_tt; os = os_tt; pr = pr_tt;
  } else if (i < E_TT + E_RT) {
    s = 1; j = i - E_TT; ec = E_RT / NCHK;
    srcA = rt_src; dstA = rt_dst; rp = rp_rt; os = os_rt; pr = pr_rt;
  } else {
    s = 2; j = i - E_TT - E_RT; ec = E_TR / NCHK;
    srcA = tr_src; dstA = tr_dst; rp = rp_tr; os = os_tr; pr = pr_tr;
  }
  int d = dstA[j];
  int c = j / ec;
  int slot = rp[d] + partial[(size_t)(s * NCHK + c) * N_TILE + d] + rank[i];
  int sv = srcA[j];
  int2 v;
  v.x = sv;
  v.y = __float_as_int(os[sv]);
  pr[slot] = v;
}

// ---------------- XCD-steered fused aggregation -> split-bf16 planes --------
// Relation A (source xA) runs on XCDs [0, splitA); relations B1,B2 (shared
// source xB) on XCDs [splitA, 8). Each XCD group re-reads only its own source
// table -> per-XCD compulsory fetch drops ~2x. blockIdx%8 ~ XCD (heuristic;
// wrong mapping is perf-neutral, correctness-safe).
__global__ __launch_bounds__(256) void k_agg3(
    int splitA, int nA, int nB1, int nB2,
    const float* __restrict__ xA, const int* __restrict__ rpA, const int2* __restrict__ prA,
    const float* __restrict__ iscA, u16* __restrict__ ohA, u16* __restrict__ olA,
    const float* __restrict__ xB,
    const int* __restrict__ rp1, const int2* __restrict__ pr1,
    const float* __restrict__ isc1, u16* __restrict__ oh1, u16* __restrict__ ol1,
    const int* __restrict__ rp2, const int2* __restrict__ pr2,
    const float* __restrict__ isc2, u16* __restrict__ oh2, u16* __restrict__ ol2) {
  int xcd = blockIdx.x & 7;
  int slot = blockIdx.x >> 3;
  int w = threadIdx.x >> 6;
  int lane = threadIdx.x & 63;
  int half = lane >> 5;
  int l5 = lane & 31;
  const float* x; const int* rp; const int2* pr; const float* isc;
  u16* oh; u16* ol; int wid;
  if (xcd < splitA) {
    int i = slot * splitA + xcd;
    wid = i * 4 + w;
    if (wid >= nA) return;
    x = xA; rp = rpA; pr = prA; isc = iscA; oh = ohA; ol = olA;
  } else {
    int i = slot * (8 - splitA) + (xcd - splitA);
    int nblk1 = (nB1 + 3) >> 2;
    if (i < nblk1) {
      wid = i * 4 + w;
      if (wid >= nB1) return;
      x = xB; rp = rp1; pr = pr1; isc = isc1; oh = oh1; ol = ol1;
    } else {
      wid = (i - nblk1) * 4 + w;
      if (wid >= nB2) return;
      x = xB; rp = rp2; pr = pr2; isc = isc2; oh = oh2; ol = ol2;
    }
  }
  int beg = rp[wid], end = rp[wid + 1];
  float4 a0 = make_float4(0.f, 0.f, 0.f, 0.f);
  float4 a1 = a0, a2 = a0, a3 = a0;
  const float4* xb = (const float4*)x + l5;
  for (int e = beg; e < end; e += 8) {
    int2 p0, p1, p2, p3;
    float w0, w1, w2, w3;
    {
      int i0 = e + 0 + half, i1 = e + 2 + half, i2 = e + 4 + half, i3 = e + 6 + half;
      int lim = end - 1;
      p0 = pr[min(i0, lim)];
      p1 = pr[min(i1, lim)];
      p2 = pr[min(i2, lim)];
      p3 = pr[min(i3, lim)];
      w0 = (i0 < end) ? __int_as_float(p0.y) : 0.f;
      w1 = (i1 < end) ? __int_as_float(p1.y) : 0.f;
      w2 = (i2 < end) ? __int_as_float(p2.y) : 0.f;
      w3 = (i3 < end) ? __int_as_float(p3.y) : 0.f;
    }
    float4 v0 = xb[(size_t)p0.x * 32];
    float4 v1 = xb[(size_t)p1.x * 32];
    float4 v2 = xb[(size_t)p2.x * 32];
    float4 v3 = xb[(size_t)p3.x * 32];
    a0.x = fmaf(v0.x, w0, a0.x); a0.y = fmaf(v0.y, w0, a0.y);
    a0.z = fmaf(v0.z, w0, a0.z); a0.w = fmaf(v0.w, w0, a0.w);
    a1.x = fmaf(v1.x, w1, a1.x); a1.y = fmaf(v1.y, w1, a1.y);
    a1.z = fmaf(v1.z, w1, a1.z); a1.w = fmaf(v1.w, w1, a1.w);
    a2.x = fmaf(v2.x, w2, a2.x); a2.y = fmaf(v2.y, w2, a2.y);
    a2.z = fmaf(v2.z, w2, a2.z); a2.w = fmaf(v2.w, w2, a2.w);
    a3.x = fmaf(v3.x, w3, a3.x); a3.y = fmaf(v3.y, w3, a3.y);
    a3.z = fmaf(v3.z, w3, a3.z); a3.w = fmaf(v3.w, w3, a3.w);
  }
  float4 s;
  s.x = (a0.x + a1.x) + (a2.x + a3.x);
  s.y = (a0.y + a1.y) + (a2.y + a3.y);
  s.z = (a0.z + a1.z) + (a2.z + a3.z);
  s.w = (a0.w + a1.w) + (a2.w + a3.w);
  s.x += __shfl_xor(s.x, 32);
  s.y += __shfl_xor(s.y, 32);
  s.z += __shfl_xor(s.z, 32);
  s.w += __shfl_xor(s.w, 32);
  if (half == 0) {
    float iv = isc[wid];
    float4 r;
    r.x = s.x * iv; r.y = s.y * iv; r.z = s.z * iv; r.w = s.w * iv;
    ushort4 hv, lv;
    hv.x = f2bf(r.x); lv.x = f2bf(r.x - bf2f(hv.x));
    hv.y = f2bf(r.y); lv.y = f2bf(r.y - bf2f(hv.y));
    hv.z = f2bf(r.z); lv.z = f2bf(r.z - bf2f(hv.z));
    hv.w = f2bf(r.w); lv.w = f2bf(r.w - bf2f(hv.w));
    *(ushort4*)(oh + (size_t)wid * D + l5 * 4) = hv;
    *(ushort4*)(ol + (size_t)wid * D + l5 * 4) = lv;
  }
}

// ---------------- weight prep: split fp32 W[k][n] -> bf16 Wt{hi,lo}[n][k] ----------------
__global__ __launch_bounds__(256) void k_wprep(
    const float* __restrict__ W0, const float* __restrict__ W1,
    const float* __restrict__ W2, const float* __restrict__ W3,
    const float* __restrict__ W4,
    u16* __restrict__ T0h, u16* __restrict__ T0l,
    u16* __restrict__ T1h, u16* __restrict__ T1l,
    u16* __restrict__ T2h, u16* __restrict__ T2l,
    u16* __restrict__ T3h, u16* __restrict__ T3l,
    u16* __restrict__ T4h, u16* __restrict__ T4l) {
  int bid = blockIdx.x;
  int s = bid >> 6;                      // 64 blocks per weight
  int idx = ((bid & 63) << 8) + threadIdx.x;   // 0..16383 = n*128+k
  const float* W = s == 0 ? W0 : (s == 1 ? W1 : (s == 2 ? W2 : (s == 3 ? W3 : W4)));
  u16* Th = s == 0 ? T0h : (s == 1 ? T1h : (s == 2 ? T2h : (s == 3 ? T3h : T4h)));
  u16* Tl = s == 0 ? T0l : (s == 1 ? T1l : (s == 2 ? T2l : (s == 3 ? T3l : T4l)));
  int n = idx >> 7, k = idx & 127;
  float w = W[k * 128 + n];
  u16 h = f2bf(w);
  Th[idx] = h;
  Tl[idx] = f2bf(w - bf2f(h));
}

// ---------------- MFMA split-bf16 GEMM(+GEMM) + bias + relu ----------------
// out = relu( A1@W1 (+ A2@W2) + b1 (+ b2) ), A in split-bf16 planes, Wt=[n][k] planes.
// C = Ahi@Whi + Ahi@Wlo + Alo@Whi (3-product split reconstruction).
template<int NREL>
__global__ __launch_bounds__(256) void k_gemm_m(
    const u16* __restrict__ A1h, const u16* __restrict__ A1l,
    const u16* __restrict__ A2h, const u16* __restrict__ A2l,
    const u16* __restrict__ Wt1h, const u16* __restrict__ Wt1l,
    const u16* __restrict__ Wt2h, const u16* __restrict__ Wt2l,
    const float* __restrict__ b1, const float* __restrict__ b2,
    float* __restrict__ out, int nrows) {
  __shared__ u16 Ah[128][40];   // pad 40: 2-way-only LDS conflicts on b128 reads
  __shared__ u16 Al[128][40];
  __shared__ u16 Wh[128][40];   // [n][k]
  __shared__ u16 Wl[128][40];
  int tid = threadIdx.x;
  int wv = tid >> 6, lane = tid & 63;
  int l15 = lane & 15, lg = lane >> 4;
  int r0 = blockIdx.x * 128;
  f32x4 acc[2][8];
#pragma unroll
  for (int i = 0; i < 2; ++i)
#pragma unroll
    for (int j = 0; j < 8; ++j) acc[i][j] = (f32x4){0.f, 0.f, 0.f, 0.f};

  int srow = tid >> 1;             // 0..127
  int c0 = (tid & 1) * 16;         // u16 col base 0 or 16; each thread writes cols c0..c0+15
  int gr = r0 + srow;

  for (int rel = 0; rel < NREL; ++rel) {
    const u16* pAh = (NREL == 2 && rel) ? A2h : A1h;
    const u16* pAl = (NREL == 2 && rel) ? A2l : A1l;
    const u16* pWh = (NREL == 2 && rel) ? Wt2h : Wt1h;
    const u16* pWl = (NREL == 2 && rel) ? Wt2l : Wt1l;
    for (int k0 = 0; k0 < 128; k0 += 32) {
      __syncthreads();
      uint4 z = {0, 0, 0, 0};
      uint4 va0 = z, va1 = z, vb0 = z, vb1 = z;
      if (gr < nrows) {
        va0 = *(const uint4*)(pAh + (size_t)gr * 128 + k0 + c0);
        va1 = *(const uint4*)(pAh + (size_t)gr * 128 + k0 + c0 + 8);
        vb0 = *(const uint4*)(pAl + (size_t)gr * 128 + k0 + c0);
        vb1 = *(const uint4*)(pAl + (size_t)gr * 128 + k0 + c0 + 8);
      }
      *(uint4*)&Ah[srow][c0] = va0;
      *(uint4*)&Ah[srow][c0 + 8] = va1;
      *(uint4*)&Al[srow][c0] = vb0;
      *(uint4*)&Al[srow][c0 + 8] = vb1;
      *(uint4*)&Wh[srow][c0]     = *(const uint4*)(pWh + (size_t)srow * 128 + k0 + c0);
      *(uint4*)&Wh[srow][c0 + 8] = *(const uint4*)(pWh + (size_t)srow * 128 + k0 + c0 + 8);
      *(uint4*)&Wl[srow][c0]     = *(const uint4*)(pWl + (size_t)srow * 128 + k0 + c0);
      *(uint4*)&Wl[srow][c0 + 8] = *(const uint4*)(pWl + (size_t)srow * 128 + k0 + c0 + 8);
      __syncthreads();
      bf16x8 a0h = *(const bf16x8*)&Ah[wv * 32 + l15][lg * 8];
      bf16x8 a0l = *(const bf16x8*)&Al[wv * 32 + l15][lg * 8];
      bf16x8 a1h = *(const bf16x8*)&Ah[wv * 32 + 16 + l15][lg * 8];
      bf16x8 a1l = *(const bf16x8*)&Al[wv * 32 + 16 + l15][lg * 8];
#pragma unroll
      for (int ct = 0; ct < 8; ++ct) {
        bf16x8 bh = *(const bf16x8*)&Wh[ct * 16 + l15][lg * 8];
        bf16x8 bl = *(const bf16x8*)&Wl[ct * 16 + l15][lg * 8];
        acc[0][ct] = __builtin_amdgcn_mfma_f32_16x16x32_bf16(a0h, bh, acc[0][ct], 0, 0, 0);
        acc[0][ct] = __builtin_amdgcn_mfma_f32_16x16x32_bf16(a0h, bl, acc[0][ct], 0, 0, 0);
        acc[0][ct] = __builtin_amdgcn_mfma_f32_16x16x32_bf16(a0l, bh, acc[0][ct], 0, 0, 0);
        acc[1][ct] = __builtin_amdgcn_mfma_f32_16x16x32_bf16(a1h, bh, acc[1][ct], 0, 0, 0);
        acc[1][ct] = __builtin_amdgcn_mfma_f32_16x16x32_bf16(a1h, bl, acc[1][ct], 0, 0, 0);
        acc[1][ct] = __builtin_amdgcn_mfma_f32_16x16x32_bf16(a1l, bh, acc[1][ct], 0, 0, 0);
      }
    }
  }
  // epilogue: bias + relu; C layout col=lane&15, row=(lane>>4)*4+reg
#pragma unroll
  for (int ct = 0; ct < 8; ++ct) {
    int col = ct * 16 + l15;
    float bias = b1[col];
    if (NREL == 2) bias += b2[col];
#pragma unroll
    for (int rt = 0; rt < 2; ++rt) {
      int rowb = r0 + wv * 32 + rt * 16 + lg * 4;
#pragma unroll
      for (int r = 0; r < 4; ++r) {
        int row = rowb + r;
        if (row < nrows)
          out[(size_t)row * 128 + col] = fmaxf(acc[rt][ct][r] + bias, 0.f);
      }
    }
  }
}

// ---------------- per-graph mean pooling ----------------
#define PCHUNK 256
__global__ __launch_bounds__(128) void k_pool(const float* __restrict__ H,
                                              const int* __restrict__ gid,
                                              float* __restrict__ sums,
                                              float* __restrict__ cnt, int n) {
  int col = threadIdx.x;
  int start = blockIdx.x * PCHUNK;
  if (start >= n) return;
  int end = min(start + PCHUNK, n);
  float acc = 0.f;
  int cur = gid[start];
  int seglen = 0;
  for (int r = start; r < end; ++r) {
    int g = gid[r];
    if (g != cur) {
      atomicAdd(&sums[cur * D + col], acc);
      if (col == 0) atomicAdd(&cnt[cur], (float)seglen);
      acc = 0.f; seglen = 0; cur = g;
    }
    acc += H[(size_t)r * D + col];
    seglen++;
  }
  atomicAdd(&sums[cur * D + col], acc);
  if (col == 0) atomicAdd(&cnt[cur], (float)seglen);
}

// ---------------- final MLP on [16,128] ----------------
__global__ __launch_bounds__(256) void k_final(const float* __restrict__ sums,
                                               const float* __restrict__ cnt,
                                               const float* __restrict__ Wm1,
                                               const float* __restrict__ bm1,
                                               const float* __restrict__ Wm2,
                                               const float* __restrict__ bm2,
                                               float* __restrict__ out) {
  __shared__ float hg[16][128];
  __shared__ float t1[16][128];
  int tid = threadIdx.x;
  for (int i = tid; i < 16 * 128; i += 256) {
    int g = i >> 7, c = i & 127;
    hg[g][c] = sums[i] / fmaxf(cnt[g], 1.f);
  }
  __syncthreads();
  for (int i = tid; i < 16 * 128; i += 256) {
    int g = i >> 7, c = i & 127;
    float a = bm1[c];
    for (int k = 0; k < 128; ++k) a = fmaf(hg[g][k], Wm1[k * 128 + c], a);
    t1[g][c] = fmaxf(a, 0.f);
  }
  __syncthreads();
  int g = tid >> 4, l = tid & 15;
  float p = 0.f;
  for (int c = l; c < 128; c += 16) p = fmaf(t1[g][c], Wm2[c], p);
#pragma unroll
  for (int o = 8; o; o >>= 1) p += __shfl_down(p, o, 16);
  if (l == 0) out[g] = p + bm2[0];
}

extern "C" void kernel_launch(void* const* d_in, const int* in_sizes, int n_in,
                              void* d_out, int out_size, void* d_ws, size_t ws_size,
                              hipStream_t stream) {
  const float* x_tile = (const float*)d_in[0];
  const float* x_rr   = (const float*)d_in[1];
  const int* tt_src = (const int*)d_in[2];
  const int* tt_dst = (const int*)d_in[3];
  const int* rt_src = (const int*)d_in[4];
  const int* rt_dst = (const int*)d_in[5];
  const int* tr_src = (const int*)d_in[6];
  const int* tr_dst = (const int*)d_in[7];
  const int* tile_gid = (const int*)d_in[8];
  const float* W1_tt = (const float*)d_in[9];  const float* b1_tt = (const float*)d_in[10];
  const float* W1_rt = (const float*)d_in[11]; const float* b1_rt = (const float*)d_in[12];
  const float* W1_tr = (const float*)d_in[13]; const float* b1_tr = (const float*)d_in[14];
  const float* W2_tt = (const float*)d_in[15]; const float* b2_tt = (const float*)d_in[16];
  const float* W2_rt = (const float*)d_in[17]; const float* b2_rt = (const float*)d_in[18];
  const float* Wm1 = (const float*)d_in[21]; const float* bm1 = (const float*)d_in[22];
  const float* Wm2 = (const float*)d_in[23]; const float* bm2 = (const float*)d_in[24];

  char* ws = (char*)d_ws;
  size_t off = 0;
  auto allocB = [&](size_t bytes) {
    void* p = ws + off;
    off += (bytes + 255) & ~(size_t)255;
    return p;
  };
  // ---- zero region (memset each call) ----
  float* psum = (float*)allocB(N_G * D * 4);
  float* pcnt = (float*)allocB(N_G * 4);
  size_t zero_bytes = off;
  // ---- rest (all fully written before read) ----
  int* partial = (int*)allocB((size_t)6 * NCHK * N_TILE * 4);
  int* rank = (int*)allocB((size_t)E_ALL * 4);
  int* ideg_tt = (int*)allocB(N_TILE * 4);
  int* ideg_rt = (int*)allocB(N_TILE * 4);
  int* ideg_tr = (int*)allocB(N_RR * 4);
  int* pp_tt = (int*)allocB(N_TILE * 4);
  int* pp_rt = (int*)allocB(N_TILE * 4);
  int* pp_tr = (int*)allocB(N_RR * 4);
  int* bsum = (int*)allocB(3 * NB * 4);
  int* bs = (int*)allocB(3 * (NB + 1) * 4);
  int* rp_tt = (int*)allocB((N_TILE + 1) * 4);
  int* rp_rt = (int*)allocB((N_TILE + 1) * 4);
  int* rp_tr = (int*)allocB((N_RR + 1) * 4);
  int2* pr_tt = (int2*)allocB((size_t)E_TT * 8);
  int2* pr_rt = (int2*)allocB((size_t)E_RT * 8);
  int2* pr_tr = (int2*)allocB((size_t)E_TR * 8);
  float* osc_tt = (float*)allocB(N_TILE * 4);
  float* osc_rt = (float*)allocB(N_RR * 4);
  float* osc_tr = (float*)allocB(N_TILE * 4);
  float* isc_tt = (float*)allocB(N_TILE * 4);
  float* isc_rt = (float*)allocB(N_TILE * 4);
  float* isc_tr = (float*)allocB(N_RR * 4);
  u16* Ahi = (u16*)allocB((size_t)N_TILE * D * 2);
  u16* Alo = (u16*)allocB((size_t)N_TILE * D * 2);
  u16* Bhi = (u16*)allocB((size_t)N_TILE * D * 2);
  u16* Blo = (u16*)allocB((size_t)N_TILE * D * 2);
  u16* Chi = (u16*)allocB((size_t)N_RR * D * 2);
  u16* Clo = (u16*)allocB((size_t)N_RR * D * 2);
  float* Htile = (float*)allocB((size_t)N_TILE * D * 4);
  float* Hrr = (float*)allocB((size_t)N_RR * D * 4);
  u16* Wt1tt_h = (u16*)allocB(D * D * 2); u16* Wt1tt_l = (u16*)allocB(D * D * 2);
  u16* Wt1rt_h = (u16*)allocB(D * D * 2); u16* Wt1rt_l = (u16*)allocB(D * D * 2);
  u16* Wt1tr_h = (u16*)allocB(D * D * 2); u16* Wt1tr_l = (u16*)allocB(D * D * 2);
  u16* Wt2tt_h = (u16*)allocB(D * D * 2); u16* Wt2tt_l = (u16*)allocB(D * D * 2);
  u16* Wt2rt_h = (u16*)allocB(D * D * 2); u16* Wt2rt_l = (u16*)allocB(D * D * 2);
  (void)ws_size; (void)in_sizes; (void)n_in; (void)out_size;

  hipMemsetAsync(d_ws, 0, zero_bytes, stream);

  // ---- weight split (independent of CSR path) ----
  k_wprep<<<5 * 64, 256, 0, stream>>>(
      W1_tt, W1_rt, W1_tr, W2_tt, W2_rt,
      Wt1tt_h, Wt1tt_l, Wt1rt_h, Wt1rt_l, Wt1tr_h, Wt1tr_l,
      Wt2tt_h, Wt2tt_l, Wt2rt_h, Wt2rt_l);

  // ---- CSR build: zero global atomics, atomic-free fill via hist-rank ----
  k_hist<<<6 * NBKT * NCHK, 256, 0, stream>>>(
      tt_src, tt_dst, rt_src, rt_dst, tr_src, tr_dst, partial, rank);
  k_hreduce<<<(6 * N_TILE + 255) / 256, 256, 0, stream>>>(
      partial, ideg_tt, ideg_rt, ideg_tr, osc_tt, osc_rt, osc_tr);
  k_scan1<<<3 * NB, 1024, 0, stream>>>(ideg_tt, ideg_rt, ideg_tr, pp_tt, pp_rt, pp_tr, bsum);
  k_scan2<<<1, 256, 0, stream>>>(bsum, bs);
  k_finalize<<<(N_TILE + 255) / 256, 256, 0, stream>>>(
      pp_tt, pp_rt, pp_tr, bs, rp_tt, rp_rt, rp_tr,
      ideg_tt, ideg_rt, ideg_tr, isc_tt, isc_rt, isc_tr);
  k_fill<<<(E_ALL + 255) / 256, 256, 0, stream>>>(
      tt_src, tt_dst, rt_src, rt_dst, tr_src, tr_dst,
      rp_tt, rp_rt, rp_tr, osc_tt, osc_rt, osc_tr,
      partial, rank, pr_tt, pr_rt, pr_tr);

  const int gemmBlocks = (N_TILE + 127) / 128;

  // XCD-steered agg launch helper: grid = 8 * max(slotsA, slotsB)
  auto aggGrid = [](int splitA, int nA, int nB1, int nB2) {
    int blkA = (nA + 3) / 4;
    int blkB = (nB1 + 3) / 4 + (nB2 + 3) / 4;
    int slotsA = (blkA + splitA - 1) / splitA;
    int slotsB = (blkB + (8 - splitA) - 1) / (8 - splitA);
    int slots = slotsA > slotsB ? slotsA : slotsB;
    return slots * 8;
  };

  // ---- layer 1: rt (x_rr) on 2 XCDs; tt+tr (x_tile) on 6 XCDs ----
  k_agg3<<<aggGrid(2, N_TILE, N_TILE, N_RR), 256, 0, stream>>>(
      2, N_TILE, N_TILE, N_RR,
      x_rr, rp_rt, pr_rt, isc_rt, Bhi, Blo,
      x_tile,
      rp_tt, pr_tt, isc_tt, Ahi, Alo,
      rp_tr, pr_tr, isc_tr, Chi, Clo);
  k_gemm_m<1><<<gemmBlocks, 256, 0, stream>>>(
      Chi, Clo, nullptr, nullptr, Wt1tr_h, Wt1tr_l, nullptr, nullptr,
      b1_tr, nullptr, Hrr, N_RR);
  k_gemm_m<2><<<gemmBlocks, 256, 0, stream>>>(
      Ahi, Alo, Bhi, Blo, Wt1tt_h, Wt1tt_l, Wt1rt_h, Wt1rt_l,
      b1_tt, b1_rt, Htile, N_TILE);

  // ---- layer 2: rt (Hrr) on 3 XCDs; tt (Htile) on 5 XCDs ----
  k_agg3<<<aggGrid(3, N_TILE, N_TILE, 0), 256, 0, stream>>>(
      3, N_TILE, N_TILE, 0,
      Hrr, rp_rt, pr_rt, isc_rt, Bhi, Blo,
      Htile,
      rp_tt, pr_tt, isc_tt, Ahi, Alo,
      rp_tt, pr_tt, isc_tt, Ahi, Alo);
  k_gemm_m<2><<<gemmBlocks, 256, 0, stream>>>(
      Ahi, Alo, Bhi, Blo, Wt2tt_h, Wt2tt_l, Wt2rt_h, Wt2rt_l,
      b2_tt, b2_rt, Htile, N_TILE);

  // ---- pooling + MLP head ----
  k_pool<<<(N_TILE + PCHUNK - 1) / PCHUNK, 128, 0, stream>>>(Htile, tile_gid, psum, pcnt, N_TILE);
  k_final<<<1, 256, 0, stream>>>(psum, pcnt, Wm1, bm1, Wm2, bm2, (float*)d_out);
}

// Round 11
// 444.707 us; speedup vs baseline: 1.0503x; 1.0503x over previous
//
#include <hip/hip_runtime.h>

#define N_TILE 50000
#define N_RR   50000
#define D      128
#define E_TT   800000
#define E_RT   400000
#define E_TR   400000
#define N_G    16
#define NB     ((N_TILE + 1023) / 1024)   // scan blocks per array (=49)
#define E_ALL  (E_TT + E_RT + E_TR)
#define BKT    16384                       // bins per bucket (16-bit packed LDS counters)
#define NBKT   ((N_TILE + BKT - 1) / BKT)  // =4
#define NCHK   25                          // edge chunks (all E divisible by 25)

static_assert(NB <= 64, "scan2 uses one wave per array");
static_assert(N_TILE == N_RR, "shared bucket geometry assumes equal node counts");
static_assert((BKT & (BKT - 1)) == 0, "bucket must be pow2");
static_assert(E_TT % NCHK == 0 && E_RT % NCHK == 0 && E_TR % NCHK == 0, "chunking");

typedef __attribute__((ext_vector_type(8))) short bf16x8;
typedef __attribute__((ext_vector_type(4))) float f32x4;
typedef unsigned short u16;

__device__ inline u16 f2bf(float f) {
  unsigned u = __float_as_uint(f);
  unsigned r = (u + 0x7FFFu + ((u >> 16) & 1u)) >> 16;   // RNE
  return (u16)r;
}
__device__ inline float bf2f(u16 h) { return __uint_as_float(((unsigned)h) << 16); }

// ---------------- bucketed LDS histogram + rank capture: NO global atomics ----
// 16384 bins / bucket, packed two 16-bit counters per LDS word.
// rank[e] (dst sides) = 16-bit half of the atomic return.
__global__ __launch_bounds__(256) void k_hist(
    const int* __restrict__ tt_src, const int* __restrict__ tt_dst,
    const int* __restrict__ rt_src, const int* __restrict__ rt_dst,
    const int* __restrict__ tr_src, const int* __restrict__ tr_dst,
    int* __restrict__ partial, int* __restrict__ rank) {
  __shared__ unsigned h[BKT / 2];
  int bid = blockIdx.x;
  int s = bid / (NBKT * NCHK);
  int rem = bid % (NBKT * NCHK);
  int b = rem / NCHK;
  int c = rem % NCHK;
  const int* arr; int E; int roff = 0;
  switch (s) {
    case 0: arr = tt_dst; E = E_TT; roff = 0; break;
    case 1: arr = rt_dst; E = E_RT; roff = E_TT; break;
    case 2: arr = tr_dst; E = E_TR; roff = E_TT + E_RT; break;
    case 3: arr = tt_src; E = E_TT; break;
    case 4: arr = rt_src; E = E_RT; break;
    default: arr = tr_src; E = E_TR; break;
  }
  bool isdst = s < 3;
  for (int j = threadIdx.x; j < BKT / 2; j += 256) h[j] = 0;
  __syncthreads();
  int ec = E / NCHK;
  int lo = c * ec, hi = lo + ec;
  int base = b * BKT;
  for (int i = lo + threadIdx.x; i < hi; i += 256) {
    unsigned int off = (unsigned int)(arr[i] - base);
    if (off < BKT) {
      unsigned sh = (off & 1u) << 4;
      unsigned r = atomicAdd(&h[off >> 1], 1u << sh);
      if (isdst) rank[roff + i] = (int)((r >> sh) & 0xffffu);
    }
  }
  __syncthreads();
  int* dst = partial + (size_t)(s * NCHK + c) * N_TILE;
  for (int j = threadIdx.x; j < BKT; j += 256) {
    int bin = base + j;
    if (bin < N_TILE)
      dst[bin] = (int)((h[j >> 1] >> ((j & 1) << 4)) & 0xffffu);
  }
}

// ---------------- reduce partials ----------------
__global__ __launch_bounds__(256) void k_hreduce(
    int* __restrict__ partial,
    int* __restrict__ id_tt, int* __restrict__ id_rt, int* __restrict__ id_tr,
    float* __restrict__ os_tt, float* __restrict__ os_rt, float* __restrict__ os_tr) {
  int t = blockIdx.x * 256 + threadIdx.x;
  if (t >= 6 * N_TILE) return;
  int s = t / N_TILE;
  int i = t - s * N_TILE;
  int* p = partial + (size_t)s * NCHK * N_TILE + i;
  int run = 0;
  if (s < 3) {
#pragma unroll
    for (int c = 0; c < NCHK; ++c) {
      int v = p[(size_t)c * N_TILE];
      p[(size_t)c * N_TILE] = run;
      run += v;
    }
    if (s == 0) id_tt[i] = run;
    else if (s == 1) id_rt[i] = run;
    else id_tr[i] = run;
  } else {
#pragma unroll
    for (int c = 0; c < NCHK; ++c) run += p[(size_t)c * N_TILE];
    float v = rsqrtf((float)max(run, 1));
    if (s == 3) os_tt[i] = v;
    else if (s == 4) os_rt[i] = v;
    else os_tr[i] = v;
  }
}

// ---------------- scan stage 1 ----------------
__global__ __launch_bounds__(1024) void k_scan1(const int* __restrict__ d0,
                                                const int* __restrict__ d1,
                                                const int* __restrict__ d2,
                                                int* __restrict__ p0,
                                                int* __restrict__ p1,
                                                int* __restrict__ p2,
                                                int* __restrict__ bsum) {
  int arr = blockIdx.x / NB;
  int blk = blockIdx.x % NB;
  const int* deg = arr == 0 ? d0 : (arr == 1 ? d1 : d2);
  int* part = arr == 0 ? p0 : (arr == 1 ? p1 : p2);
  __shared__ int ts[1024];
  int tid = threadIdx.x;
  int i = blk * 1024 + tid;
  int v = (i < N_TILE) ? deg[i] : 0;
  ts[tid] = v;
  __syncthreads();
  for (int d = 1; d < 1024; d <<= 1) {
    int t = (tid >= d) ? ts[tid - d] : 0;
    __syncthreads();
    ts[tid] += t;
    __syncthreads();
  }
  if (i < N_TILE) part[i] = ts[tid] - v;
  if (tid == 1023) bsum[arr * NB + blk] = ts[1023];
}

// ---------------- scan stage 2 ----------------
__global__ __launch_bounds__(256) void k_scan2(const int* __restrict__ bsum,
                                               int* __restrict__ bs) {
  int wv = threadIdx.x >> 6;
  int lane = threadIdx.x & 63;
  if (wv >= 3) return;
  int v = (lane < NB) ? bsum[wv * NB + lane] : 0;
  int orig = v;
#pragma unroll
  for (int o = 1; o < 64; o <<= 1) {
    int t = __shfl_up(v, o);
    if (lane >= o) v += t;
  }
  if (lane < NB) bs[wv * (NB + 1) + lane] = v - orig;
  if (lane == NB - 1) bs[wv * (NB + 1) + NB] = v;
}

// ---------------- finalize ----------------
__global__ void k_finalize(const int* __restrict__ pp_tt, const int* __restrict__ pp_rt,
                           const int* __restrict__ pp_tr, const int* __restrict__ bs,
                           int* __restrict__ rp_tt, int* __restrict__ rp_rt,
                           int* __restrict__ rp_tr,
                           const int* __restrict__ id_tt, const int* __restrict__ id_rt,
                           const int* __restrict__ id_tr,
                           float* __restrict__ is_tt, float* __restrict__ is_rt,
                           float* __restrict__ is_tr) {
  int i = blockIdx.x * blockDim.x + threadIdx.x;
  if (i >= N_TILE) return;
  int b = i >> 10;
  rp_tt[i] = pp_tt[i] + bs[0 * (NB + 1) + b];
  rp_rt[i] = pp_rt[i] + bs[1 * (NB + 1) + b];
  rp_tr[i] = pp_tr[i] + bs[2 * (NB + 1) + b];
  if (i == 0) {
    rp_tt[N_TILE] = bs[0 * (NB + 1) + NB];
    rp_rt[N_TILE] = bs[1 * (NB + 1) + NB];
    rp_tr[N_RR] = bs[2 * (NB + 1) + NB];
  }
  is_tt[i] = rsqrtf((float)max(id_tt[i], 1));
  is_rt[i] = rsqrtf((float)max(id_rt[i], 1));
  is_tr[i] = rsqrtf((float)max(id_tr[i], 1));
}

// ---------------- CSR fill: one thread per edge, atomic-free ----------------
__global__ __launch_bounds__(256) void k_fill(
    const int* __restrict__ tt_src, const int* __restrict__ tt_dst,
    const int* __restrict__ rt_src, const int* __restrict__ rt_dst,
    const int* __restrict__ tr_src, const int* __restrict__ tr_dst,
    const int* __restrict__ rp_tt, const int* __restrict__ rp_rt,
    const int* __restrict__ rp_tr,
    const float* __restrict__ os_tt, const float* __restrict__ os_rt,
    const float* __restrict__ os_tr,
    const int* __restrict__ partial, const int* __restrict__ rank,
    int2* __restrict__ pr_tt, int2* __restrict__ pr_rt, int2* __restrict__ pr_tr) {
  int i = blockIdx.x * 256 + threadIdx.x;
  if (i >= E_ALL) return;
  const int* srcA; const int* dstA; const int* rp; const float* os; int2* pr;
  int j, s, ec;
  if (i < E_TT) {
    s = 0; j = i; ec = E_TT / NCHK;
    srcA = tt_src; dstA = tt_dst; rp = rp_tt; os = os_tt; pr = pr_tt;
  } else if (i < E_TT + E_RT) {
    s = 1; j = i - E_TT; ec = E_RT / NCHK;
    srcA = rt_src; dstA = rt_dst; rp = rp_rt; os = os_rt; pr = pr_rt;
  } else {
    s = 2; j = i - E_TT - E_RT; ec = E_TR / NCHK;
    srcA = tr_src; dstA = tr_dst; rp = rp_tr; os = os_tr; pr = pr_tr;
  }
  int d = dstA[j];
  int c = j / ec;
  int slot = rp[d] + partial[(size_t)(s * NCHK + c) * N_TILE + d] + rank[i];
  int sv = srcA[j];
  int2 v;
  v.x = sv;
  v.y = __float_as_int(os[sv]);
  pr[slot] = v;
}

// ---------------- fp32 -> bf16 conversion of gather sources ----------------
__global__ __launch_bounds__(256) void k_conv(const float* __restrict__ a,
                                              const float* __restrict__ b,
                                              u16* __restrict__ oa,
                                              u16* __restrict__ ob) {
  const size_t TOT = (size_t)N_TILE * D / 8;
  size_t i = (size_t)blockIdx.x * 256 + threadIdx.x;
  if (i >= 2 * TOT) return;
  const float* src = (i < TOT) ? a : b;
  u16* dst = (i < TOT) ? oa : ob;
  size_t j = ((i < TOT) ? i : i - TOT) * 8;
  float4 v0 = *(const float4*)(src + j);
  float4 v1 = *(const float4*)(src + j + 4);
  ushort4 h0, h1;
  h0.x = f2bf(v0.x); h0.y = f2bf(v0.y); h0.z = f2bf(v0.z); h0.w = f2bf(v0.w);
  h1.x = f2bf(v1.x); h1.y = f2bf(v1.y); h1.z = f2bf(v1.z); h1.w = f2bf(v1.w);
  *(ushort4*)(dst + j) = h0;
  *(ushort4*)(dst + j + 4) = h1;
}

// ---------------- fused aggregation (up to 3 relations) -> split-bf16 planes
// out_{hi,lo}[d][:] = split( isc[d] * sum_e w_e * x[src_e] )
// BF=true: x rows are bf16 (256B/row) -> gather bytes halve. Accum stays fp32.
// Half-wave layout: lanes 0-31 / 32-63 each cover a full row per edge.
template<bool BF>
__global__ __launch_bounds__(256) void k_agg3(
    const void* __restrict__ x0, const int* __restrict__ rp0, const int2* __restrict__ pr0,
    const float* __restrict__ isc0, u16* __restrict__ oh0, u16* __restrict__ ol0, int n0,
    const void* __restrict__ x1, const int* __restrict__ rp1, const int2* __restrict__ pr1,
    const float* __restrict__ isc1, u16* __restrict__ oh1, u16* __restrict__ ol1, int n1,
    const void* __restrict__ x2, const int* __restrict__ rp2, const int2* __restrict__ pr2,
    const float* __restrict__ isc2, u16* __restrict__ oh2, u16* __restrict__ ol2, int n2) {
  int gw = (blockIdx.x * blockDim.x + threadIdx.x) >> 6;
  int lane = threadIdx.x & 63;
  int half = lane >> 5;
  int l5 = lane & 31;
  const void* x; const int* rp; const int2* pr; const float* isc;
  u16* oh; u16* ol; int wid;
  if (gw < n0) { x = x0; rp = rp0; pr = pr0; isc = isc0; oh = oh0; ol = ol0; wid = gw; }
  else if (gw < n0 + n1) { x = x1; rp = rp1; pr = pr1; isc = isc1; oh = oh1; ol = ol1; wid = gw - n0; }
  else if (gw < n0 + n1 + n2) { x = x2; rp = rp2; pr = pr2; isc = isc2; oh = oh2; ol = ol2; wid = gw - n0 - n1; }
  else return;
  int beg = rp[wid], end = rp[wid + 1];
  float4 a0 = make_float4(0.f, 0.f, 0.f, 0.f);
  float4 a1 = a0, a2 = a0, a3 = a0;
  // row stride is 32 units either way: 128 f32 = 32 float4; 128 bf16 = 32 ushort4.
  const float4* xf = (const float4*)x + l5;
  const ushort4* xh = (const ushort4*)x + l5;
  for (int e = beg; e < end; e += 8) {
    int2 p0, p1, p2, p3;
    float w0, w1, w2, w3;
    {
      int i0 = e + 0 + half, i1 = e + 2 + half, i2 = e + 4 + half, i3 = e + 6 + half;
      int lim = end - 1;
      p0 = pr[min(i0, lim)];
      p1 = pr[min(i1, lim)];
      p2 = pr[min(i2, lim)];
      p3 = pr[min(i3, lim)];
      w0 = (i0 < end) ? __int_as_float(p0.y) : 0.f;
      w1 = (i1 < end) ? __int_as_float(p1.y) : 0.f;
      w2 = (i2 < end) ? __int_as_float(p2.y) : 0.f;
      w3 = (i3 < end) ? __int_as_float(p3.y) : 0.f;
    }
    float4 v0, v1, v2, v3;
    if (BF) {
      ushort4 u0 = xh[(size_t)p0.x * 32];
      ushort4 u1 = xh[(size_t)p1.x * 32];
      ushort4 u2 = xh[(size_t)p2.x * 32];
      ushort4 u3 = xh[(size_t)p3.x * 32];
      v0 = make_float4(bf2f(u0.x), bf2f(u0.y), bf2f(u0.z), bf2f(u0.w));
      v1 = make_float4(bf2f(u1.x), bf2f(u1.y), bf2f(u1.z), bf2f(u1.w));
      v2 = make_float4(bf2f(u2.x), bf2f(u2.y), bf2f(u2.z), bf2f(u2.w));
      v3 = make_float4(bf2f(u3.x), bf2f(u3.y), bf2f(u3.z), bf2f(u3.w));
    } else {
      v0 = xf[(size_t)p0.x * 32];
      v1 = xf[(size_t)p1.x * 32];
      v2 = xf[(size_t)p2.x * 32];
      v3 = xf[(size_t)p3.x * 32];
    }
    a0.x = fmaf(v0.x, w0, a0.x); a0.y = fmaf(v0.y, w0, a0.y);
    a0.z = fmaf(v0.z, w0, a0.z); a0.w = fmaf(v0.w, w0, a0.w);
    a1.x = fmaf(v1.x, w1, a1.x); a1.y = fmaf(v1.y, w1, a1.y);
    a1.z = fmaf(v1.z, w1, a1.z); a1.w = fmaf(v1.w, w1, a1.w);
    a2.x = fmaf(v2.x, w2, a2.x); a2.y = fmaf(v2.y, w2, a2.y);
    a2.z = fmaf(v2.z, w2, a2.z); a2.w = fmaf(v2.w, w2, a2.w);
    a3.x = fmaf(v3.x, w3, a3.x); a3.y = fmaf(v3.y, w3, a3.y);
    a3.z = fmaf(v3.z, w3, a3.z); a3.w = fmaf(v3.w, w3, a3.w);
  }
  float4 s;
  s.x = (a0.x + a1.x) + (a2.x + a3.x);
  s.y = (a0.y + a1.y) + (a2.y + a3.y);
  s.z = (a0.z + a1.z) + (a2.z + a3.z);
  s.w = (a0.w + a1.w) + (a2.w + a3.w);
  s.x += __shfl_xor(s.x, 32);
  s.y += __shfl_xor(s.y, 32);
  s.z += __shfl_xor(s.z, 32);
  s.w += __shfl_xor(s.w, 32);
  if (half == 0) {
    float iv = isc[wid];
    float4 r;
    r.x = s.x * iv; r.y = s.y * iv; r.z = s.z * iv; r.w = s.w * iv;
    ushort4 hv, lv;
    hv.x = f2bf(r.x); lv.x = f2bf(r.x - bf2f(hv.x));
    hv.y = f2bf(r.y); lv.y = f2bf(r.y - bf2f(hv.y));
    hv.z = f2bf(r.z); lv.z = f2bf(r.z - bf2f(hv.z));
    hv.w = f2bf(r.w); lv.w = f2bf(r.w - bf2f(hv.w));
    *(ushort4*)(oh + (size_t)wid * D + l5 * 4) = hv;
    *(ushort4*)(ol + (size_t)wid * D + l5 * 4) = lv;
  }
}

// ---------------- weight prep: split fp32 W[k][n] -> bf16 Wt{hi,lo}[n][k] ----------------
__global__ __launch_bounds__(256) void k_wprep(
    const float* __restrict__ W0, const float* __restrict__ W1,
    const float* __restrict__ W2, const float* __restrict__ W3,
    const float* __restrict__ W4,
    u16* __restrict__ T0h, u16* __restrict__ T0l,
    u16* __restrict__ T1h, u16* __restrict__ T1l,
    u16* __restrict__ T2h, u16* __restrict__ T2l,
    u16* __restrict__ T3h, u16* __restrict__ T3l,
    u16* __restrict__ T4h, u16* __restrict__ T4l) {
  int bid = blockIdx.x;
  int s = bid >> 6;                      // 64 blocks per weight
  int idx = ((bid & 63) << 8) + threadIdx.x;   // 0..16383 = n*128+k
  const float* W = s == 0 ? W0 : (s == 1 ? W1 : (s == 2 ? W2 : (s == 3 ? W3 : W4)));
  u16* Th = s == 0 ? T0h : (s == 1 ? T1h : (s == 2 ? T2h : (s == 3 ? T3h : T4h)));
  u16* Tl = s == 0 ? T0l : (s == 1 ? T1l : (s == 2 ? T2l : (s == 3 ? T3l : T4l)));
  int n = idx >> 7, k = idx & 127;
  float w = W[k * 128 + n];
  u16 h = f2bf(w);
  Th[idx] = h;
  Tl[idx] = f2bf(w - bf2f(h));
}

// ---------------- MFMA split-bf16 GEMM(+GEMM) + bias + relu ----------------
// out = relu( A1@W1 (+ A2@W2) + b1 (+ b2) ), A in split-bf16 planes, Wt=[n][k] planes.
// C = Ahi@Whi + Ahi@Wlo + Alo@Whi (3-product split reconstruction).
template<int NREL>
__global__ __launch_bounds__(256) void k_gemm_m(
    const u16* __restrict__ A1h, const u16* __restrict__ A1l,
    const u16* __restrict__ A2h, const u16* __restrict__ A2l,
    const u16* __restrict__ Wt1h, const u16* __restrict__ Wt1l,
    const u16* __restrict__ Wt2h, const u16* __restrict__ Wt2l,
    const float* __restrict__ b1, const float* __restrict__ b2,
    float* __restrict__ out, int nrows) {
  __shared__ u16 Ah[128][40];   // pad 40: 2-way-only LDS conflicts on b128 reads
  __shared__ u16 Al[128][40];
  __shared__ u16 Wh[128][40];   // [n][k]
  __shared__ u16 Wl[128][40];
  int tid = threadIdx.x;
  int wv = tid >> 6, lane = tid & 63;
  int l15 = lane & 15, lg = lane >> 4;
  int r0 = blockIdx.x * 128;
  f32x4 acc[2][8];
#pragma unroll
  for (int i = 0; i < 2; ++i)
#pragma unroll
    for (int j = 0; j < 8; ++j) acc[i][j] = (f32x4){0.f, 0.f, 0.f, 0.f};

  int srow = tid >> 1;             // 0..127
  int c0 = (tid & 1) * 16;         // u16 col base 0 or 16; each thread writes cols c0..c0+15
  int gr = r0 + srow;

  for (int rel = 0; rel < NREL; ++rel) {
    const u16* pAh = (NREL == 2 && rel) ? A2h : A1h;
    const u16* pAl = (NREL == 2 && rel) ? A2l : A1l;
    const u16* pWh = (NREL == 2 && rel) ? Wt2h : Wt1h;
    const u16* pWl = (NREL == 2 && rel) ? Wt2l : Wt1l;
    for (int k0 = 0; k0 < 128; k0 += 32) {
      __syncthreads();
      uint4 z = {0, 0, 0, 0};
      uint4 va0 = z, va1 = z, vb0 = z, vb1 = z;
      if (gr < nrows) {
        va0 = *(const uint4*)(pAh + (size_t)gr * 128 + k0 + c0);
        va1 = *(const uint4*)(pAh + (size_t)gr * 128 + k0 + c0 + 8);
        vb0 = *(const uint4*)(pAl + (size_t)gr * 128 + k0 + c0);
        vb1 = *(const uint4*)(pAl + (size_t)gr * 128 + k0 + c0 + 8);
      }
      *(uint4*)&Ah[srow][c0] = va0;
      *(uint4*)&Ah[srow][c0 + 8] = va1;
      *(uint4*)&Al[srow][c0] = vb0;
      *(uint4*)&Al[srow][c0 + 8] = vb1;
      *(uint4*)&Wh[srow][c0]     = *(const uint4*)(pWh + (size_t)srow * 128 + k0 + c0);
      *(uint4*)&Wh[srow][c0 + 8] = *(const uint4*)(pWh + (size_t)srow * 128 + k0 + c0 + 8);
      *(uint4*)&Wl[srow][c0]     = *(const uint4*)(pWl + (size_t)srow * 128 + k0 + c0);
      *(uint4*)&Wl[srow][c0 + 8] = *(const uint4*)(pWl + (size_t)srow * 128 + k0 + c0 + 8);
      __syncthreads();
      bf16x8 a0h = *(const bf16x8*)&Ah[wv * 32 + l15][lg * 8];
      bf16x8 a0l = *(const bf16x8*)&Al[wv * 32 + l15][lg * 8];
      bf16x8 a1h = *(const bf16x8*)&Ah[wv * 32 + 16 + l15][lg * 8];
      bf16x8 a1l = *(const bf16x8*)&Al[wv * 32 + 16 + l15][lg * 8];
#pragma unroll
      for (int ct = 0; ct < 8; ++ct) {
        bf16x8 bh = *(const bf16x8*)&Wh[ct * 16 + l15][lg * 8];
        bf16x8 bl = *(const bf16x8*)&Wl[ct * 16 + l15][lg * 8];
        acc[0][ct] = __builtin_amdgcn_mfma_f32_16x16x32_bf16(a0h, bh, acc[0][ct], 0, 0, 0);
        acc[0][ct] = __builtin_amdgcn_mfma_f32_16x16x32_bf16(a0h, bl, acc[0][ct], 0, 0, 0);
        acc[0][ct] = __builtin_amdgcn_mfma_f32_16x16x32_bf16(a0l, bh, acc[0][ct], 0, 0, 0);
        acc[1][ct] = __builtin_amdgcn_mfma_f32_16x16x32_bf16(a1h, bh, acc[1][ct], 0, 0, 0);
        acc[1][ct] = __builtin_amdgcn_mfma_f32_16x16x32_bf16(a1h, bl, acc[1][ct], 0, 0, 0);
        acc[1][ct] = __builtin_amdgcn_mfma_f32_16x16x32_bf16(a1l, bh, acc[1][ct], 0, 0, 0);
      }
    }
  }
  // epilogue: bias + relu; C layout col=lane&15, row=(lane>>4)*4+reg
#pragma unroll
  for (int ct = 0; ct < 8; ++ct) {
    int col = ct * 16 + l15;
    float bias = b1[col];
    if (NREL == 2) bias += b2[col];
#pragma unroll
    for (int rt = 0; rt < 2; ++rt) {
      int rowb = r0 + wv * 32 + rt * 16 + lg * 4;
#pragma unroll
      for (int r = 0; r < 4; ++r) {
        int row = rowb + r;
        if (row < nrows)
          out[(size_t)row * 128 + col] = fmaxf(acc[rt][ct][r] + bias, 0.f);
      }
    }
  }
}

// ---------------- per-graph mean pooling ----------------
#define PCHUNK 256
__global__ __launch_bounds__(128) void k_pool(const float* __restrict__ H,
                                              const int* __restrict__ gid,
                                              float* __restrict__ sums,
                                              float* __restrict__ cnt, int n) {
  int col = threadIdx.x;
  int start = blockIdx.x * PCHUNK;
  if (start >= n) return;
  int end = min(start + PCHUNK, n);
  float acc = 0.f;
  int cur = gid[start];
  int seglen = 0;
  for (int r = start; r < end; ++r) {
    int g = gid[r];
    if (g != cur) {
      atomicAdd(&sums[cur * D + col], acc);
      if (col == 0) atomicAdd(&cnt[cur], (float)seglen);
      acc = 0.f; seglen = 0; cur = g;
    }
    acc += H[(size_t)r * D + col];
    seglen++;
  }
  atomicAdd(&sums[cur * D + col], acc);
  if (col == 0) atomicAdd(&cnt[cur], (float)seglen);
}

// ---------------- final MLP on [16,128] ----------------
__global__ __launch_bounds__(256) void k_final(const float* __restrict__ sums,
                                               const float* __restrict__ cnt,
                                               const float* __restrict__ Wm1,
                                               const float* __restrict__ bm1,
                                               const float* __restrict__ Wm2,
                                               const float* __restrict__ bm2,
                                               float* __restrict__ out) {
  __shared__ float hg[16][128];
  __shared__ float t1[16][128];
  int tid = threadIdx.x;
  for (int i = tid; i < 16 * 128; i += 256) {
    int g = i >> 7, c = i & 127;
    hg[g][c] = sums[i] / fmaxf(cnt[g], 1.f);
  }
  __syncthreads();
  for (int i = tid; i < 16 * 128; i += 256) {
    int g = i >> 7, c = i & 127;
    float a = bm1[c];
    for (int k = 0; k < 128; ++k) a = fmaf(hg[g][k], Wm1[k * 128 + c], a);
    t1[g][c] = fmaxf(a, 0.f);
  }
  __syncthreads();
  int g = tid >> 4, l = tid & 15;
  float p = 0.f;
  for (int c = l; c < 128; c += 16) p = fmaf(t1[g][c], Wm2[c], p);
#pragma unroll
  for (int o = 8; o; o >>= 1) p += __shfl_down(p, o, 16);
  if (l == 0) out[g] = p + bm2[0];
}

extern "C" void kernel_launch(void* const* d_in, const int* in_sizes, int n_in,
                              void* d_out, int out_size, void* d_ws, size_t ws_size,
                              hipStream_t stream) {
  const float* x_tile = (const float*)d_in[0];
  const float* x_rr   = (const float*)d_in[1];
  const int* tt_src = (const int*)d_in[2];
  const int* tt_dst = (const int*)d_in[3];
  const int* rt_src = (const int*)d_in[4];
  const int* rt_dst = (const int*)d_in[5];
  const int* tr_src = (const int*)d_in[6];
  const int* tr_dst = (const int*)d_in[7];
  const int* tile_gid = (const int*)d_in[8];
  const float* W1_tt = (const float*)d_in[9];  const float* b1_tt = (const float*)d_in[10];
  const float* W1_rt = (const float*)d_in[11]; const float* b1_rt = (const float*)d_in[12];
  const float* W1_tr = (const float*)d_in[13]; const float* b1_tr = (const float*)d_in[14];
  const float* W2_tt = (const float*)d_in[15]; const float* b2_tt = (const float*)d_in[16];
  const float* W2_rt = (const float*)d_in[17]; const float* b2_rt = (const float*)d_in[18];
  const float* Wm1 = (const float*)d_in[21]; const float* bm1 = (const float*)d_in[22];
  const float* Wm2 = (const float*)d_in[23]; const float* bm2 = (const float*)d_in[24];

  char* ws = (char*)d_ws;
  size_t off = 0;
  auto allocB = [&](size_t bytes) {
    void* p = ws + off;
    off += (bytes + 255) & ~(size_t)255;
    return p;
  };
  // ---- zero region (memset each call) ----
  float* psum = (float*)allocB(N_G * D * 4);
  float* pcnt = (float*)allocB(N_G * 4);
  size_t zero_bytes = off;
  // ---- rest (all fully written before read) ----
  int* partial = (int*)allocB((size_t)6 * NCHK * N_TILE * 4);
  int* rank = (int*)allocB((size_t)E_ALL * 4);
  int* ideg_tt = (int*)allocB(N_TILE * 4);
  int* ideg_rt = (int*)allocB(N_TILE * 4);
  int* ideg_tr = (int*)allocB(N_RR * 4);
  int* pp_tt = (int*)allocB(N_TILE * 4);
  int* pp_rt = (int*)allocB(N_TILE * 4);
  int* pp_tr = (int*)allocB(N_RR * 4);
  int* bsum = (int*)allocB(3 * NB * 4);
  int* bs = (int*)allocB(3 * (NB + 1) * 4);
  int* rp_tt = (int*)allocB((N_TILE + 1) * 4);
  int* rp_rt = (int*)allocB((N_TILE + 1) * 4);
  int* rp_tr = (int*)allocB((N_RR + 1) * 4);
  int2* pr_tt = (int2*)allocB((size_t)E_TT * 8);
  int2* pr_rt = (int2*)allocB((size_t)E_RT * 8);
  int2* pr_tr = (int2*)allocB((size_t)E_TR * 8);
  float* osc_tt = (float*)allocB(N_TILE * 4);
  float* osc_rt = (float*)allocB(N_RR * 4);
  float* osc_tr = (float*)allocB(N_TILE * 4);
  float* isc_tt = (float*)allocB(N_TILE * 4);
  float* isc_rt = (float*)allocB(N_TILE * 4);
  float* isc_tr = (float*)allocB(N_RR * 4);
  u16* xt_bf = (u16*)allocB((size_t)N_TILE * D * 2);
  u16* xr_bf = (u16*)allocB((size_t)N_RR * D * 2);
  u16* Ahi = (u16*)allocB((size_t)N_TILE * D * 2);
  u16* Alo = (u16*)allocB((size_t)N_TILE * D * 2);
  u16* Bhi = (u16*)allocB((size_t)N_TILE * D * 2);
  u16* Blo = (u16*)allocB((size_t)N_TILE * D * 2);
  u16* Chi = (u16*)allocB((size_t)N_RR * D * 2);
  u16* Clo = (u16*)allocB((size_t)N_RR * D * 2);
  float* Htile = (float*)allocB((size_t)N_TILE * D * 4);
  float* Hrr = (float*)allocB((size_t)N_RR * D * 4);
  u16* Wt1tt_h = (u16*)allocB(D * D * 2); u16* Wt1tt_l = (u16*)allocB(D * D * 2);
  u16* Wt1rt_h = (u16*)allocB(D * D * 2); u16* Wt1rt_l = (u16*)allocB(D * D * 2);
  u16* Wt1tr_h = (u16*)allocB(D * D * 2); u16* Wt1tr_l = (u16*)allocB(D * D * 2);
  u16* Wt2tt_h = (u16*)allocB(D * D * 2); u16* Wt2tt_l = (u16*)allocB(D * D * 2);
  u16* Wt2rt_h = (u16*)allocB(D * D * 2); u16* Wt2rt_l = (u16*)allocB(D * D * 2);
  (void)ws_size; (void)in_sizes; (void)n_in; (void)out_size;

  hipMemsetAsync(d_ws, 0, zero_bytes, stream);

  // ---- weight split + source bf16 conversion (independent of CSR path) ----
  k_wprep<<<5 * 64, 256, 0, stream>>>(
      W1_tt, W1_rt, W1_tr, W2_tt, W2_rt,
      Wt1tt_h, Wt1tt_l, Wt1rt_h, Wt1rt_l, Wt1tr_h, Wt1tr_l,
      Wt2tt_h, Wt2tt_l, Wt2rt_h, Wt2rt_l);
  k_conv<<<(2 * N_TILE * (D / 8) + 255) / 256, 256, 0, stream>>>(
      x_tile, x_rr, xt_bf, xr_bf);

  // ---- CSR build: zero global atomics, atomic-free fill via hist-rank ----
  k_hist<<<6 * NBKT * NCHK, 256, 0, stream>>>(
      tt_src, tt_dst, rt_src, rt_dst, tr_src, tr_dst, partial, rank);
  k_hreduce<<<(6 * N_TILE + 255) / 256, 256, 0, stream>>>(
      partial, ideg_tt, ideg_rt, ideg_tr, osc_tt, osc_rt, osc_tr);
  k_scan1<<<3 * NB, 1024, 0, stream>>>(ideg_tt, ideg_rt, ideg_tr, pp_tt, pp_rt, pp_tr, bsum);
  k_scan2<<<1, 256, 0, stream>>>(bsum, bs);
  k_finalize<<<(N_TILE + 255) / 256, 256, 0, stream>>>(
      pp_tt, pp_rt, pp_tr, bs, rp_tt, rp_rt, rp_tr,
      ideg_tt, ideg_rt, ideg_tr, isc_tt, isc_rt, isc_tr);
  k_fill<<<(E_ALL + 255) / 256, 256, 0, stream>>>(
      tt_src, tt_dst, rt_src, rt_dst, tr_src, tr_dst,
      rp_tt, rp_rt, rp_tr, osc_tt, osc_rt, osc_tr,
      partial, rank, pr_tt, pr_rt, pr_tr);

  const int gemmBlocks = (N_TILE + 127) / 128;

  // ---- layer 1: all three aggs fused, bf16 gather (halved bytes) ----
  {
    int totw = N_TILE + N_TILE + N_RR;
    k_agg3<true><<<(totw * 64 + 255) / 256, 256, 0, stream>>>(
        xt_bf, rp_tt, pr_tt, isc_tt, Ahi, Alo, N_TILE,
        xr_bf, rp_rt, pr_rt, isc_rt, Bhi, Blo, N_TILE,
        xt_bf, rp_tr, pr_tr, isc_tr, Chi, Clo, N_RR);
  }
  k_gemm_m<1><<<gemmBlocks, 256, 0, stream>>>(
      Chi, Clo, nullptr, nullptr, Wt1tr_h, Wt1tr_l, nullptr, nullptr,
      b1_tr, nullptr, Hrr, N_RR);
  k_gemm_m<2><<<gemmBlocks, 256, 0, stream>>>(
      Ahi, Alo, Bhi, Blo, Wt1tt_h, Wt1tt_l, Wt1rt_h, Wt1rt_l,
      b1_tt, b1_rt, Htile, N_TILE);

  // ---- layer 2: fp32 gather (h2_rr never consumed -> tr relation skipped) ----
  {
    int totw = N_TILE + N_TILE;
    k_agg3<false><<<(totw * 64 + 255) / 256, 256, 0, stream>>>(
        Htile, rp_tt, pr_tt, isc_tt, Ahi, Alo, N_TILE,
        Hrr,   rp_rt, pr_rt, isc_rt, Bhi, Blo, N_TILE,
        nullptr, nullptr, nullptr, nullptr, nullptr, nullptr, 0);
  }
  k_gemm_m<2><<<gemmBlocks, 256, 0, stream>>>(
      Ahi, Alo, Bhi, Blo, Wt2tt_h, Wt2tt_l, Wt2rt_h, Wt2rt_l,
      b2_tt, b2_rt, Htile, N_TILE);

  // ---- pooling + MLP head ----
  k_pool<<<(N_TILE + PCHUNK - 1) / PCHUNK, 128, 0, stream>>>(Htile, tile_gid, psum, pcnt, N_TILE);
  k_final<<<1, 256, 0, stream>>>(psum, pcnt, Wm1, bm1, Wm2, bm2, (float*)d_out);
}

// Round 12
// 411.775 us; speedup vs baseline: 1.1343x; 1.0800x over previous
//
#include <hip/hip_runtime.h>

#define N_TILE 50000
#define N_RR   50000
#define D      128
#define E_TT   800000
#define E_RT   400000
#define E_TR   400000
#define N_G    16
#define NB     ((N_TILE + 1023) / 1024)   // scan blocks per array (=49)
#define E_ALL  (E_TT + E_RT + E_TR)
#define BKT    16384                       // bins per bucket (16-bit packed LDS counters)
#define NBKT   ((N_TILE + BKT - 1) / BKT)  // =4
#define NCHK   25                          // edge chunks (all E divisible by 25)

static_assert(NB <= 64, "scan2 uses one wave per array");
static_assert(N_TILE == N_RR, "shared bucket geometry assumes equal node counts");
static_assert((BKT & (BKT - 1)) == 0, "bucket must be pow2");
static_assert(E_TT % NCHK == 0 && E_RT % NCHK == 0 && E_TR % NCHK == 0, "chunking");

typedef __attribute__((ext_vector_type(8))) short bf16x8;
typedef __attribute__((ext_vector_type(4))) float f32x4;
typedef unsigned short u16;

__device__ inline u16 f2bf(float f) {
  unsigned u = __float_as_uint(f);
  unsigned r = (u + 0x7FFFu + ((u >> 16) & 1u)) >> 16;   // RNE
  return (u16)r;
}
__device__ inline float bf2f(u16 h) { return __uint_as_float(((unsigned)h) << 16); }
__device__ inline float bflo(unsigned w) { return __uint_as_float(w << 16); }
__device__ inline float bfhi(unsigned w) { return __uint_as_float(w & 0xffff0000u); }

// ---------------- bucketed LDS histogram + rank capture: NO global atomics ----
__global__ __launch_bounds__(256) void k_hist(
    const int* __restrict__ tt_src, const int* __restrict__ tt_dst,
    const int* __restrict__ rt_src, const int* __restrict__ rt_dst,
    const int* __restrict__ tr_src, const int* __restrict__ tr_dst,
    int* __restrict__ partial, int* __restrict__ rank) {
  __shared__ unsigned h[BKT / 2];
  int bid = blockIdx.x;
  int s = bid / (NBKT * NCHK);
  int rem = bid % (NBKT * NCHK);
  int b = rem / NCHK;
  int c = rem % NCHK;
  const int* arr; int E; int roff = 0;
  switch (s) {
    case 0: arr = tt_dst; E = E_TT; roff = 0; break;
    case 1: arr = rt_dst; E = E_RT; roff = E_TT; break;
    case 2: arr = tr_dst; E = E_TR; roff = E_TT + E_RT; break;
    case 3: arr = tt_src; E = E_TT; break;
    case 4: arr = rt_src; E = E_RT; break;
    default: arr = tr_src; E = E_TR; break;
  }
  bool isdst = s < 3;
  for (int j = threadIdx.x; j < BKT / 2; j += 256) h[j] = 0;
  __syncthreads();
  int ec = E / NCHK;
  int lo = c * ec, hi = lo + ec;
  int base = b * BKT;
  for (int i = lo + threadIdx.x; i < hi; i += 256) {
    unsigned int off = (unsigned int)(arr[i] - base);
    if (off < BKT) {
      unsigned sh = (off & 1u) << 4;
      unsigned r = atomicAdd(&h[off >> 1], 1u << sh);
      if (isdst) rank[roff + i] = (int)((r >> sh) & 0xffffu);
    }
  }
  __syncthreads();
  int* dst = partial + (size_t)(s * NCHK + c) * N_TILE;
  for (int j = threadIdx.x; j < BKT; j += 256) {
    int bin = base + j;
    if (bin < N_TILE)
      dst[bin] = (int)((h[j >> 1] >> ((j & 1) << 4)) & 0xffffu);
  }
}

// ---------------- reduce partials ----------------
__global__ __launch_bounds__(256) void k_hreduce(
    int* __restrict__ partial,
    int* __restrict__ id_tt, int* __restrict__ id_rt, int* __restrict__ id_tr,
    float* __restrict__ os_tt, float* __restrict__ os_rt, float* __restrict__ os_tr) {
  int t = blockIdx.x * 256 + threadIdx.x;
  if (t >= 6 * N_TILE) return;
  int s = t / N_TILE;
  int i = t - s * N_TILE;
  int* p = partial + (size_t)s * NCHK * N_TILE + i;
  int run = 0;
  if (s < 3) {
#pragma unroll
    for (int c = 0; c < NCHK; ++c) {
      int v = p[(size_t)c * N_TILE];
      p[(size_t)c * N_TILE] = run;
      run += v;
    }
    if (s == 0) id_tt[i] = run;
    else if (s == 1) id_rt[i] = run;
    else id_tr[i] = run;
  } else {
#pragma unroll
    for (int c = 0; c < NCHK; ++c) run += p[(size_t)c * N_TILE];
    float v = rsqrtf((float)max(run, 1));
    if (s == 3) os_tt[i] = v;
    else if (s == 4) os_rt[i] = v;
    else os_tr[i] = v;
  }
}

// ---------------- scan stage 1 ----------------
__global__ __launch_bounds__(1024) void k_scan1(const int* __restrict__ d0,
                                                const int* __restrict__ d1,
                                                const int* __restrict__ d2,
                                                int* __restrict__ p0,
                                                int* __restrict__ p1,
                                                int* __restrict__ p2,
                                                int* __restrict__ bsum) {
  int arr = blockIdx.x / NB;
  int blk = blockIdx.x % NB;
  const int* deg = arr == 0 ? d0 : (arr == 1 ? d1 : d2);
  int* part = arr == 0 ? p0 : (arr == 1 ? p1 : p2);
  __shared__ int ts[1024];
  int tid = threadIdx.x;
  int i = blk * 1024 + tid;
  int v = (i < N_TILE) ? deg[i] : 0;
  ts[tid] = v;
  __syncthreads();
  for (int d = 1; d < 1024; d <<= 1) {
    int t = (tid >= d) ? ts[tid - d] : 0;
    __syncthreads();
    ts[tid] += t;
    __syncthreads();
  }
  if (i < N_TILE) part[i] = ts[tid] - v;
  if (tid == 1023) bsum[arr * NB + blk] = ts[1023];
}

// ---------------- scan stage 2 ----------------
__global__ __launch_bounds__(256) void k_scan2(const int* __restrict__ bsum,
                                               int* __restrict__ bs) {
  int wv = threadIdx.x >> 6;
  int lane = threadIdx.x & 63;
  if (wv >= 3) return;
  int v = (lane < NB) ? bsum[wv * NB + lane] : 0;
  int orig = v;
#pragma unroll
  for (int o = 1; o < 64; o <<= 1) {
    int t = __shfl_up(v, o);
    if (lane >= o) v += t;
  }
  if (lane < NB) bs[wv * (NB + 1) + lane] = v - orig;
  if (lane == NB - 1) bs[wv * (NB + 1) + NB] = v;
}

// ---------------- finalize ----------------
__global__ void k_finalize(const int* __restrict__ pp_tt, const int* __restrict__ pp_rt,
                           const int* __restrict__ pp_tr, const int* __restrict__ bs,
                           int* __restrict__ rp_tt, int* __restrict__ rp_rt,
                           int* __restrict__ rp_tr,
                           const int* __restrict__ id_tt, const int* __restrict__ id_rt,
                           const int* __restrict__ id_tr,
                           float* __restrict__ is_tt, float* __restrict__ is_rt,
                           float* __restrict__ is_tr) {
  int i = blockIdx.x * blockDim.x + threadIdx.x;
  if (i >= N_TILE) return;
  int b = i >> 10;
  rp_tt[i] = pp_tt[i] + bs[0 * (NB + 1) + b];
  rp_rt[i] = pp_rt[i] + bs[1 * (NB + 1) + b];
  rp_tr[i] = pp_tr[i] + bs[2 * (NB + 1) + b];
  if (i == 0) {
    rp_tt[N_TILE] = bs[0 * (NB + 1) + NB];
    rp_rt[N_TILE] = bs[1 * (NB + 1) + NB];
    rp_tr[N_RR] = bs[2 * (NB + 1) + NB];
  }
  is_tt[i] = rsqrtf((float)max(id_tt[i], 1));
  is_rt[i] = rsqrtf((float)max(id_rt[i], 1));
  is_tr[i] = rsqrtf((float)max(id_tr[i], 1));
}

// ---------------- CSR fill: one thread per edge, atomic-free ----------------
__global__ __launch_bounds__(256) void k_fill(
    const int* __restrict__ tt_src, const int* __restrict__ tt_dst,
    const int* __restrict__ rt_src, const int* __restrict__ rt_dst,
    const int* __restrict__ tr_src, const int* __restrict__ tr_dst,
    const int* __restrict__ rp_tt, const int* __restrict__ rp_rt,
    const int* __restrict__ rp_tr,
    const float* __restrict__ os_tt, const float* __restrict__ os_rt,
    const float* __restrict__ os_tr,
    const int* __restrict__ partial, const int* __restrict__ rank,
    int2* __restrict__ pr_tt, int2* __restrict__ pr_rt, int2* __restrict__ pr_tr) {
  int i = blockIdx.x * 256 + threadIdx.x;
  if (i >= E_ALL) return;
  const int* srcA; const int* dstA; const int* rp; const float* os; int2* pr;
  int j, s, ec;
  if (i < E_TT) {
    s = 0; j = i; ec = E_TT / NCHK;
    srcA = tt_src; dstA = tt_dst; rp = rp_tt; os = os_tt; pr = pr_tt;
  } else if (i < E_TT + E_RT) {
    s = 1; j = i - E_TT; ec = E_RT / NCHK;
    srcA = rt_src; dstA = rt_dst; rp = rp_rt; os = os_rt; pr = pr_rt;
  } else {
    s = 2; j = i - E_TT - E_RT; ec = E_TR / NCHK;
    srcA = tr_src; dstA = tr_dst; rp = rp_tr; os = os_tr; pr = pr_tr;
  }
  int d = dstA[j];
  int c = j / ec;
  int slot = rp[d] + partial[(size_t)(s * NCHK + c) * N_TILE + d] + rank[i];
  int sv = srcA[j];
  int2 v;
  v.x = sv;
  v.y = __float_as_int(os[sv]);
  pr[slot] = v;
}

// ---------------- fp32 -> bf16 conversion of gather sources ----------------
__global__ __launch_bounds__(256) void k_conv(const float* __restrict__ a,
                                              const float* __restrict__ b,
                                              u16* __restrict__ oa,
                                              u16* __restrict__ ob) {
  const size_t TOT = (size_t)N_TILE * D / 8;
  size_t i = (size_t)blockIdx.x * 256 + threadIdx.x;
  if (i >= 2 * TOT) return;
  const float* src = (i < TOT) ? a : b;
  u16* dst = (i < TOT) ? oa : ob;
  size_t j = ((i < TOT) ? i : i - TOT) * 8;
  float4 v0 = *(const float4*)(src + j);
  float4 v1 = *(const float4*)(src + j + 4);
  ushort4 h0, h1;
  h0.x = f2bf(v0.x); h0.y = f2bf(v0.y); h0.z = f2bf(v0.z); h0.w = f2bf(v0.w);
  h1.x = f2bf(v1.x); h1.y = f2bf(v1.y); h1.z = f2bf(v1.z); h1.w = f2bf(v1.w);
  *(ushort4*)(dst + j) = h0;
  *(ushort4*)(dst + j + 4) = h1;
}

// ---------------- fused aggregation (up to 3 relations) -> split-bf16 planes
// out_{hi,lo}[d][:] = split( isc[d] * sum_e w_e * x[src_e] );  x rows = bf16.
// Quarter-wave layout: 16 lanes x 16B (uint4 = 8 bf16) cover one 256B row;
// quarter q handles edges e+q and e+4+q -> 2 loads/lane/iter, 8 edges/iter.
__global__ __launch_bounds__(256) void k_agg3(
    const u16* __restrict__ x0, const int* __restrict__ rp0, const int2* __restrict__ pr0,
    const float* __restrict__ isc0, u16* __restrict__ oh0, u16* __restrict__ ol0, int n0,
    const u16* __restrict__ x1, const int* __restrict__ rp1, const int2* __restrict__ pr1,
    const float* __restrict__ isc1, u16* __restrict__ oh1, u16* __restrict__ ol1, int n1,
    const u16* __restrict__ x2, const int* __restrict__ rp2, const int2* __restrict__ pr2,
    const float* __restrict__ isc2, u16* __restrict__ oh2, u16* __restrict__ ol2, int n2) {
  int gw = (blockIdx.x * blockDim.x + threadIdx.x) >> 6;
  int lane = threadIdx.x & 63;
  int q = lane >> 4;        // edge-slot within group of 4
  int l4 = lane & 15;       // uint4 slot within the 256B row
  const u16* x; const int* rp; const int2* pr; const float* isc;
  u16* oh; u16* ol; int wid;
  if (gw < n0) { x = x0; rp = rp0; pr = pr0; isc = isc0; oh = oh0; ol = ol0; wid = gw; }
  else if (gw < n0 + n1) { x = x1; rp = rp1; pr = pr1; isc = isc1; oh = oh1; ol = ol1; wid = gw - n0; }
  else if (gw < n0 + n1 + n2) { x = x2; rp = rp2; pr = pr2; isc = isc2; oh = oh2; ol = ol2; wid = gw - n0 - n1; }
  else return;
  int beg = rp[wid], end = rp[wid + 1];
  float a0[8], a1[8];
#pragma unroll
  for (int j = 0; j < 8; ++j) { a0[j] = 0.f; a1[j] = 0.f; }
  const uint4* xb = (const uint4*)x + l4;   // row = 128 bf16 = 16 uint4
  for (int e = beg; e < end; e += 8) {
    int lim = end - 1;
    int i0 = e + q, i1 = e + 4 + q;
    int2 p0 = pr[min(i0, lim)];
    int2 p1 = pr[min(i1, lim)];
    float w0 = (i0 < end) ? __int_as_float(p0.y) : 0.f;
    float w1 = (i1 < end) ? __int_as_float(p1.y) : 0.f;
    uint4 u0 = xb[(size_t)p0.x * 16];
    uint4 u1 = xb[(size_t)p1.x * 16];
    a0[0] = fmaf(bflo(u0.x), w0, a0[0]); a0[1] = fmaf(bfhi(u0.x), w0, a0[1]);
    a0[2] = fmaf(bflo(u0.y), w0, a0[2]); a0[3] = fmaf(bfhi(u0.y), w0, a0[3]);
    a0[4] = fmaf(bflo(u0.z), w0, a0[4]); a0[5] = fmaf(bfhi(u0.z), w0, a0[5]);
    a0[6] = fmaf(bflo(u0.w), w0, a0[6]); a0[7] = fmaf(bfhi(u0.w), w0, a0[7]);
    a1[0] = fmaf(bflo(u1.x), w1, a1[0]); a1[1] = fmaf(bfhi(u1.x), w1, a1[1]);
    a1[2] = fmaf(bflo(u1.y), w1, a1[2]); a1[3] = fmaf(bfhi(u1.y), w1, a1[3]);
    a1[4] = fmaf(bflo(u1.z), w1, a1[4]); a1[5] = fmaf(bfhi(u1.z), w1, a1[5]);
    a1[6] = fmaf(bflo(u1.w), w1, a1[6]); a1[7] = fmaf(bfhi(u1.w), w1, a1[7]);
  }
  float s[8];
#pragma unroll
  for (int j = 0; j < 8; ++j) {
    s[j] = a0[j] + a1[j];
    s[j] += __shfl_xor(s[j], 16);
    s[j] += __shfl_xor(s[j], 32);
  }
  if (q == 0) {
    float iv = isc[wid];
    uint4 hw, lw;
    unsigned hb[8], lb[8];
#pragma unroll
    for (int j = 0; j < 8; ++j) {
      float r = s[j] * iv;
      hb[j] = f2bf(r);
      lb[j] = f2bf(r - bf2f((u16)hb[j]));
    }
    hw.x = hb[0] | (hb[1] << 16); hw.y = hb[2] | (hb[3] << 16);
    hw.z = hb[4] | (hb[5] << 16); hw.w = hb[6] | (hb[7] << 16);
    lw.x = lb[0] | (lb[1] << 16); lw.y = lb[2] | (lb[3] << 16);
    lw.z = lb[4] | (lb[5] << 16); lw.w = lb[6] | (lb[7] << 16);
    *(uint4*)(oh + (size_t)wid * D + l4 * 8) = hw;
    *(uint4*)(ol + (size_t)wid * D + l4 * 8) = lw;
  }
}

// ---------------- weight prep: split fp32 W[k][n] -> bf16 Wt{hi,lo}[n][k] ----------------
__global__ __launch_bounds__(256) void k_wprep(
    const float* __restrict__ W0, const float* __restrict__ W1,
    const float* __restrict__ W2, const float* __restrict__ W3,
    const float* __restrict__ W4,
    u16* __restrict__ T0h, u16* __restrict__ T0l,
    u16* __restrict__ T1h, u16* __restrict__ T1l,
    u16* __restrict__ T2h, u16* __restrict__ T2l,
    u16* __restrict__ T3h, u16* __restrict__ T3l,
    u16* __restrict__ T4h, u16* __restrict__ T4l) {
  int bid = blockIdx.x;
  int s = bid >> 6;                      // 64 blocks per weight
  int idx = ((bid & 63) << 8) + threadIdx.x;   // 0..16383 = n*128+k
  const float* W = s == 0 ? W0 : (s == 1 ? W1 : (s == 2 ? W2 : (s == 3 ? W3 : W4)));
  u16* Th = s == 0 ? T0h : (s == 1 ? T1h : (s == 2 ? T2h : (s == 3 ? T3h : T4h)));
  u16* Tl = s == 0 ? T0l : (s == 1 ? T1l : (s == 2 ? T2l : (s == 3 ? T3l : T4l)));
  int n = idx >> 7, k = idx & 127;
  float w = W[k * 128 + n];
  u16 h = f2bf(w);
  Th[idx] = h;
  Tl[idx] = f2bf(w - bf2f(h));
}

// ---------------- MFMA split-bf16 GEMM(+GEMM) + bias + relu ----------------
// out = relu( A1@W1 (+ A2@W2) + b1 (+ b2) ); OBF: output bf16 rows, else fp32.
// C = Ahi@Whi + Ahi@Wlo + Alo@Whi (3-product split reconstruction).
template<int NREL, bool OBF>
__global__ __launch_bounds__(256) void k_gemm_m(
    const u16* __restrict__ A1h, const u16* __restrict__ A1l,
    const u16* __restrict__ A2h, const u16* __restrict__ A2l,
    const u16* __restrict__ Wt1h, const u16* __restrict__ Wt1l,
    const u16* __restrict__ Wt2h, const u16* __restrict__ Wt2l,
    const float* __restrict__ b1, const float* __restrict__ b2,
    void* __restrict__ outv, int nrows) {
  __shared__ u16 Ah[128][40];   // pad 40: 2-way-only LDS conflicts on b128 reads
  __shared__ u16 Al[128][40];
  __shared__ u16 Wh[128][40];   // [n][k]
  __shared__ u16 Wl[128][40];
  int tid = threadIdx.x;
  int wv = tid >> 6, lane = tid & 63;
  int l15 = lane & 15, lg = lane >> 4;
  int r0 = blockIdx.x * 128;
  f32x4 acc[2][8];
#pragma unroll
  for (int i = 0; i < 2; ++i)
#pragma unroll
    for (int j = 0; j < 8; ++j) acc[i][j] = (f32x4){0.f, 0.f, 0.f, 0.f};

  int srow = tid >> 1;             // 0..127
  int c0 = (tid & 1) * 16;         // u16 col base 0 or 16; each thread writes cols c0..c0+15
  int gr = r0 + srow;

  for (int rel = 0; rel < NREL; ++rel) {
    const u16* pAh = (NREL == 2 && rel) ? A2h : A1h;
    const u16* pAl = (NREL == 2 && rel) ? A2l : A1l;
    const u16* pWh = (NREL == 2 && rel) ? Wt2h : Wt1h;
    const u16* pWl = (NREL == 2 && rel) ? Wt2l : Wt1l;
    for (int k0 = 0; k0 < 128; k0 += 32) {
      __syncthreads();
      uint4 z = {0, 0, 0, 0};
      uint4 va0 = z, va1 = z, vb0 = z, vb1 = z;
      if (gr < nrows) {
        va0 = *(const uint4*)(pAh + (size_t)gr * 128 + k0 + c0);
        va1 = *(const uint4*)(pAh + (size_t)gr * 128 + k0 + c0 + 8);
        vb0 = *(const uint4*)(pAl + (size_t)gr * 128 + k0 + c0);
        vb1 = *(const uint4*)(pAl + (size_t)gr * 128 + k0 + c0 + 8);
      }
      *(uint4*)&Ah[srow][c0] = va0;
      *(uint4*)&Ah[srow][c0 + 8] = va1;
      *(uint4*)&Al[srow][c0] = vb0;
      *(uint4*)&Al[srow][c0 + 8] = vb1;
      *(uint4*)&Wh[srow][c0]     = *(const uint4*)(pWh + (size_t)srow * 128 + k0 + c0);
      *(uint4*)&Wh[srow][c0 + 8] = *(const uint4*)(pWh + (size_t)srow * 128 + k0 + c0 + 8);
      *(uint4*)&Wl[srow][c0]     = *(const uint4*)(pWl + (size_t)srow * 128 + k0 + c0);
      *(uint4*)&Wl[srow][c0 + 8] = *(const uint4*)(pWl + (size_t)srow * 128 + k0 + c0 + 8);
      __syncthreads();
      bf16x8 a0h = *(const bf16x8*)&Ah[wv * 32 + l15][lg * 8];
      bf16x8 a0l = *(const bf16x8*)&Al[wv * 32 + l15][lg * 8];
      bf16x8 a1h = *(const bf16x8*)&Ah[wv * 32 + 16 + l15][lg * 8];
      bf16x8 a1l = *(const bf16x8*)&Al[wv * 32 + 16 + l15][lg * 8];
#pragma unroll
      for (int ct = 0; ct < 8; ++ct) {
        bf16x8 bh = *(const bf16x8*)&Wh[ct * 16 + l15][lg * 8];
        bf16x8 bl = *(const bf16x8*)&Wl[ct * 16 + l15][lg * 8];
        acc[0][ct] = __builtin_amdgcn_mfma_f32_16x16x32_bf16(a0h, bh, acc[0][ct], 0, 0, 0);
        acc[0][ct] = __builtin_amdgcn_mfma_f32_16x16x32_bf16(a0h, bl, acc[0][ct], 0, 0, 0);
        acc[0][ct] = __builtin_amdgcn_mfma_f32_16x16x32_bf16(a0l, bh, acc[0][ct], 0, 0, 0);
        acc[1][ct] = __builtin_amdgcn_mfma_f32_16x16x32_bf16(a1h, bh, acc[1][ct], 0, 0, 0);
        acc[1][ct] = __builtin_amdgcn_mfma_f32_16x16x32_bf16(a1h, bl, acc[1][ct], 0, 0, 0);
        acc[1][ct] = __builtin_amdgcn_mfma_f32_16x16x32_bf16(a1l, bh, acc[1][ct], 0, 0, 0);
      }
    }
  }
  // epilogue: bias + relu; C layout col=lane&15, row=(lane>>4)*4+reg
#pragma unroll
  for (int ct = 0; ct < 8; ++ct) {
    int col = ct * 16 + l15;
    float bias = b1[col];
    if (NREL == 2) bias += b2[col];
#pragma unroll
    for (int rt = 0; rt < 2; ++rt) {
      int rowb = r0 + wv * 32 + rt * 16 + lg * 4;
#pragma unroll
      for (int r = 0; r < 4; ++r) {
        int row = rowb + r;
        if (row < nrows) {
          float v = fmaxf(acc[rt][ct][r] + bias, 0.f);
          if (OBF) ((u16*)outv)[(size_t)row * 128 + col] = f2bf(v);
          else ((float*)outv)[(size_t)row * 128 + col] = v;
        }
      }
    }
  }
}

// ---------------- per-graph mean pooling ----------------
#define PCHUNK 256
__global__ __launch_bounds__(128) void k_pool(const float* __restrict__ H,
                                              const int* __restrict__ gid,
                                              float* __restrict__ sums,
                                              float* __restrict__ cnt, int n) {
  int col = threadIdx.x;
  int start = blockIdx.x * PCHUNK;
  if (start >= n) return;
  int end = min(start + PCHUNK, n);
  float acc = 0.f;
  int cur = gid[start];
  int seglen = 0;
  for (int r = start; r < end; ++r) {
    int g = gid[r];
    if (g != cur) {
      atomicAdd(&sums[cur * D + col], acc);
      if (col == 0) atomicAdd(&cnt[cur], (float)seglen);
      acc = 0.f; seglen = 0; cur = g;
    }
    acc += H[(size_t)r * D + col];
    seglen++;
  }
  atomicAdd(&sums[cur * D + col], acc);
  if (col == 0) atomicAdd(&cnt[cur], (float)seglen);
}

// ---------------- final MLP on [16,128] ----------------
__global__ __launch_bounds__(256) void k_final(const float* __restrict__ sums,
                                               const float* __restrict__ cnt,
                                               const float* __restrict__ Wm1,
                                               const float* __restrict__ bm1,
                                               const float* __restrict__ Wm2,
                                               const float* __restrict__ bm2,
                                               float* __restrict__ out) {
  __shared__ float hg[16][128];
  __shared__ float t1[16][128];
  int tid = threadIdx.x;
  for (int i = tid; i < 16 * 128; i += 256) {
    int g = i >> 7, c = i & 127;
    hg[g][c] = sums[i] / fmaxf(cnt[g], 1.f);
  }
  __syncthreads();
  for (int i = tid; i < 16 * 128; i += 256) {
    int g = i >> 7, c = i & 127;
    float a = bm1[c];
    for (int k = 0; k < 128; ++k) a = fmaf(hg[g][k], Wm1[k * 128 + c], a);
    t1[g][c] = fmaxf(a, 0.f);
  }
  __syncthreads();
  int g = tid >> 4, l = tid & 15;
  float p = 0.f;
  for (int c = l; c < 128; c += 16) p = fmaf(t1[g][c], Wm2[c], p);
#pragma unroll
  for (int o = 8; o; o >>= 1) p += __shfl_down(p, o, 16);
  if (l == 0) out[g] = p + bm2[0];
}

extern "C" void kernel_launch(void* const* d_in, const int* in_sizes, int n_in,
                              void* d_out, int out_size, void* d_ws, size_t ws_size,
                              hipStream_t stream) {
  const float* x_tile = (const float*)d_in[0];
  const float* x_rr   = (const float*)d_in[1];
  const int* tt_src = (const int*)d_in[2];
  const int* tt_dst = (const int*)d_in[3];
  const int* rt_src = (const int*)d_in[4];
  const int* rt_dst = (const int*)d_in[5];
  const int* tr_src = (const int*)d_in[6];
  const int* tr_dst = (const int*)d_in[7];
  const int* tile_gid = (const int*)d_in[8];
  const float* W1_tt = (const float*)d_in[9];  const float* b1_tt = (const float*)d_in[10];
  const float* W1_rt = (const float*)d_in[11]; const float* b1_rt = (const float*)d_in[12];
  const float* W1_tr = (const float*)d_in[13]; const float* b1_tr = (const float*)d_in[14];
  const float* W2_tt = (const float*)d_in[15]; const float* b2_tt = (const float*)d_in[16];
  const float* W2_rt = (const float*)d_in[17]; const float* b2_rt = (const float*)d_in[18];
  const float* Wm1 = (const float*)d_in[21]; const float* bm1 = (const float*)d_in[22];
  const float* Wm2 = (const float*)d_in[23]; const float* bm2 = (const float*)d_in[24];

  char* ws = (char*)d_ws;
  size_t off = 0;
  auto allocB = [&](size_t bytes) {
    void* p = ws + off;
    off += (bytes + 255) & ~(size_t)255;
    return p;
  };
  // ---- zero region (memset each call) ----
  float* psum = (float*)allocB(N_G * D * 4);
  float* pcnt = (float*)allocB(N_G * 4);
  size_t zero_bytes = off;
  // ---- rest (all fully written before read) ----
  int* partial = (int*)allocB((size_t)6 * NCHK * N_TILE * 4);
  int* rank = (int*)allocB((size_t)E_ALL * 4);
  int* ideg_tt = (int*)allocB(N_TILE * 4);
  int* ideg_rt = (int*)allocB(N_TILE * 4);
  int* ideg_tr = (int*)allocB(N_RR * 4);
  int* pp_tt = (int*)allocB(N_TILE * 4);
  int* pp_rt = (int*)allocB(N_TILE * 4);
  int* pp_tr = (int*)allocB(N_RR * 4);
  int* bsum = (int*)allocB(3 * NB * 4);
  int* bs = (int*)allocB(3 * (NB + 1) * 4);
  int* rp_tt = (int*)allocB((N_TILE + 1) * 4);
  int* rp_rt = (int*)allocB((N_TILE + 1) * 4);
  int* rp_tr = (int*)allocB((N_RR + 1) * 4);
  int2* pr_tt = (int2*)allocB((size_t)E_TT * 8);
  int2* pr_rt = (int2*)allocB((size_t)E_RT * 8);
  int2* pr_tr = (int2*)allocB((size_t)E_TR * 8);
  float* osc_tt = (float*)allocB(N_TILE * 4);
  float* osc_rt = (float*)allocB(N_RR * 4);
  float* osc_tr = (float*)allocB(N_TILE * 4);
  float* isc_tt = (float*)allocB(N_TILE * 4);
  float* isc_rt = (float*)allocB(N_TILE * 4);
  float* isc_tr = (float*)allocB(N_RR * 4);
  u16* xt_bf = (u16*)allocB((size_t)N_TILE * D * 2);
  u16* xr_bf = (u16*)allocB((size_t)N_RR * D * 2);
  u16* Ahi = (u16*)allocB((size_t)N_TILE * D * 2);
  u16* Alo = (u16*)allocB((size_t)N_TILE * D * 2);
  u16* Bhi = (u16*)allocB((size_t)N_TILE * D * 2);
  u16* Blo = (u16*)allocB((size_t)N_TILE * D * 2);
  u16* Chi = (u16*)allocB((size_t)N_RR * D * 2);
  u16* Clo = (u16*)allocB((size_t)N_RR * D * 2);
  u16* Ht_bf = (u16*)allocB((size_t)N_TILE * D * 2);   // layer-1 tile output (bf16)
  u16* Hr_bf = (u16*)allocB((size_t)N_RR * D * 2);     // layer-1 rr output (bf16)
  float* Htile = (float*)allocB((size_t)N_TILE * D * 4); // layer-2 output (fp32, pooled)
  u16* Wt1tt_h = (u16*)allocB(D * D * 2); u16* Wt1tt_l = (u16*)allocB(D * D * 2);
  u16* Wt1rt_h = (u16*)allocB(D * D * 2); u16* Wt1rt_l = (u16*)allocB(D * D * 2);
  u16* Wt1tr_h = (u16*)allocB(D * D * 2); u16* Wt1tr_l = (u16*)allocB(D * D * 2);
  u16* Wt2tt_h = (u16*)allocB(D * D * 2); u16* Wt2tt_l = (u16*)allocB(D * D * 2);
  u16* Wt2rt_h = (u16*)allocB(D * D * 2); u16* Wt2rt_l = (u16*)allocB(D * D * 2);
  (void)ws_size; (void)in_sizes; (void)n_in; (void)out_size;

  hipMemsetAsync(d_ws, 0, zero_bytes, stream);

  // ---- weight split + source bf16 conversion (independent of CSR path) ----
  k_wprep<<<5 * 64, 256, 0, stream>>>(
      W1_tt, W1_rt, W1_tr, W2_tt, W2_rt,
      Wt1tt_h, Wt1tt_l, Wt1rt_h, Wt1rt_l, Wt1tr_h, Wt1tr_l,
      Wt2tt_h, Wt2tt_l, Wt2rt_h, Wt2rt_l);
  k_conv<<<(2 * N_TILE * (D / 8) + 255) / 256, 256, 0, stream>>>(
      x_tile, x_rr, xt_bf, xr_bf);

  // ---- CSR build: zero global atomics, atomic-free fill via hist-rank ----
  k_hist<<<6 * NBKT * NCHK, 256, 0, stream>>>(
      tt_src, tt_dst, rt_src, rt_dst, tr_src, tr_dst, partial, rank);
  k_hreduce<<<(6 * N_TILE + 255) / 256, 256, 0, stream>>>(
      partial, ideg_tt, ideg_rt, ideg_tr, osc_tt, osc_rt, osc_tr);
  k_scan1<<<3 * NB, 1024, 0, stream>>>(ideg_tt, ideg_rt, ideg_tr, pp_tt, pp_rt, pp_tr, bsum);
  k_scan2<<<1, 256, 0, stream>>>(bsum, bs);
  k_finalize<<<(N_TILE + 255) / 256, 256, 0, stream>>>(
      pp_tt, pp_rt, pp_tr, bs, rp_tt, rp_rt, rp_tr,
      ideg_tt, ideg_rt, ideg_tr, isc_tt, isc_rt, isc_tr);
  k_fill<<<(E_ALL + 255) / 256, 256, 0, stream>>>(
      tt_src, tt_dst, rt_src, rt_dst, tr_src, tr_dst,
      rp_tt, rp_rt, rp_tr, osc_tt, osc_rt, osc_tr,
      partial, rank, pr_tt, pr_rt, pr_tr);

  const int gemmBlocks = (N_TILE + 127) / 128;

  // ---- layer 1: all three aggs fused, bf16 gather ----
  {
    int totw = N_TILE + N_TILE + N_RR;
    k_agg3<<<(totw * 64 + 255) / 256, 256, 0, stream>>>(
        xt_bf, rp_tt, pr_tt, isc_tt, Ahi, Alo, N_TILE,
        xr_bf, rp_rt, pr_rt, isc_rt, Bhi, Blo, N_TILE,
        xt_bf, rp_tr, pr_tr, isc_tr, Chi, Clo, N_RR);
  }
  k_gemm_m<1, true><<<gemmBlocks, 256, 0, stream>>>(
      Chi, Clo, nullptr, nullptr, Wt1tr_h, Wt1tr_l, nullptr, nullptr,
      b1_tr, nullptr, Hr_bf, N_RR);
  k_gemm_m<2, true><<<gemmBlocks, 256, 0, stream>>>(
      Ahi, Alo, Bhi, Blo, Wt1tt_h, Wt1tt_l, Wt1rt_h, Wt1rt_l,
      b1_tt, b1_rt, Ht_bf, N_TILE);

  // ---- layer 2: bf16 gather of layer-1 outputs (tr relation skipped) ----
  {
    int totw = N_TILE + N_TILE;
    k_agg3<<<(totw * 64 + 255) / 256, 256, 0, stream>>>(
        Ht_bf, rp_tt, pr_tt, isc_tt, Ahi, Alo, N_TILE,
        Hr_bf, rp_rt, pr_rt, isc_rt, Bhi, Blo, N_TILE,
        nullptr, nullptr, nullptr, nullptr, nullptr, nullptr, 0);
  }
  k_gemm_m<2, false><<<gemmBlocks, 256, 0, stream>>>(
      Ahi, Alo, Bhi, Blo, Wt2tt_h, Wt2tt_l, Wt2rt_h, Wt2rt_l,
      b2_tt, b2_rt, Htile, N_TILE);

  // ---- pooling + MLP head ----
  k_pool<<<(N_TILE + PCHUNK - 1) / PCHUNK, 128, 0, stream>>>(Htile, tile_gid, psum, pcnt, N_TILE);
  k_final<<<1, 256, 0, stream>>>(psum, pcnt, Wm1, bm1, Wm2, bm2, (float*)d_out);
}

// Round 13
// 408.164 us; speedup vs baseline: 1.1444x; 1.0088x over previous
//
#include <hip/hip_runtime.h>

#define N_TILE 50000
#define N_RR   50000
#define D      128
#define E_TT   800000
#define E_RT   400000
#define E_TR   400000
#define N_G    16
#define NB     ((N_TILE + 1023) / 1024)   // scan blocks per array (=49)
#define E_ALL  (E_TT + E_RT + E_TR)
#define BKT    16384                       // bins per bucket (16-bit packed LDS counters)
#define NBKT   ((N_TILE + BKT - 1) / BKT)  // =4
#define NCHK   25                          // edge chunks (all E divisible by 25)
#define WPREP_BLOCKS 320                   // 5 weights * 64 blocks

static_assert(NB <= 64, "scan2 uses one wave per array");
static_assert(N_TILE == N_RR, "shared bucket geometry assumes equal node counts");
static_assert((BKT & (BKT - 1)) == 0, "bucket must be pow2");
static_assert(E_TT % NCHK == 0 && E_RT % NCHK == 0 && E_TR % NCHK == 0, "chunking");

typedef __attribute__((ext_vector_type(8))) short bf16x8;
typedef __attribute__((ext_vector_type(4))) float f32x4;
typedef __attribute__((ext_vector_type(2))) float v2f;
typedef unsigned short u16;

__device__ inline u16 f2bf(float f) {
  unsigned u = __float_as_uint(f);
  unsigned r = (u + 0x7FFFu + ((u >> 16) & 1u)) >> 16;   // RNE
  return (u16)r;
}
__device__ inline float bf2f(u16 h) { return __uint_as_float(((unsigned)h) << 16); }

// packed FMA: acc.{x,y} += pair.{x,y} * w.{x,y}  (one VOP3P instruction)
__device__ inline void pk_fma(v2f& acc, v2f pair, v2f w) {
  asm("v_pk_fma_f32 %0, %1, %2, %0" : "+v"(acc) : "v"(pair), "v"(w));
}
// unpack u32 (2 bf16) -> {lo, cheap-hi}; hi keeps low 16 bits as sub-ulp noise
__device__ inline v2f bfpair(unsigned w) {
  v2f p;
  p.x = __uint_as_float(w << 16);
  p.y = __uint_as_float(w);
  return p;
}

// ---------------- bucketed LDS histogram + rank capture: NO global atomics ----
__global__ __launch_bounds__(256) void k_hist(
    const int* __restrict__ tt_src, const int* __restrict__ tt_dst,
    const int* __restrict__ rt_src, const int* __restrict__ rt_dst,
    const int* __restrict__ tr_src, const int* __restrict__ tr_dst,
    int* __restrict__ partial, int* __restrict__ rank) {
  __shared__ unsigned h[BKT / 2];
  int bid = blockIdx.x;
  int s = bid / (NBKT * NCHK);
  int rem = bid % (NBKT * NCHK);
  int b = rem / NCHK;
  int c = rem % NCHK;
  const int* arr; int E; int roff = 0;
  switch (s) {
    case 0: arr = tt_dst; E = E_TT; roff = 0; break;
    case 1: arr = rt_dst; E = E_RT; roff = E_TT; break;
    case 2: arr = tr_dst; E = E_TR; roff = E_TT + E_RT; break;
    case 3: arr = tt_src; E = E_TT; break;
    case 4: arr = rt_src; E = E_RT; break;
    default: arr = tr_src; E = E_TR; break;
  }
  bool isdst = s < 3;
  for (int j = threadIdx.x; j < BKT / 2; j += 256) h[j] = 0;
  __syncthreads();
  int ec = E / NCHK;
  int lo = c * ec, hi = lo + ec;
  int base = b * BKT;
  for (int i = lo + threadIdx.x; i < hi; i += 256) {
    unsigned int off = (unsigned int)(arr[i] - base);
    if (off < BKT) {
      unsigned sh = (off & 1u) << 4;
      unsigned r = atomicAdd(&h[off >> 1], 1u << sh);
      if (isdst) rank[roff + i] = (int)((r >> sh) & 0xffffu);
    }
  }
  __syncthreads();
  int* dst = partial + (size_t)(s * NCHK + c) * N_TILE;
  for (int j = threadIdx.x; j < BKT; j += 256) {
    int bin = base + j;
    if (bin < N_TILE)
      dst[bin] = (int)((h[j >> 1] >> ((j & 1) << 4)) & 0xffffu);
  }
}

// ---------------- reduce partials ----------------
__global__ __launch_bounds__(256) void k_hreduce(
    int* __restrict__ partial,
    int* __restrict__ id_tt, int* __restrict__ id_rt, int* __restrict__ id_tr,
    float* __restrict__ os_tt, float* __restrict__ os_rt, float* __restrict__ os_tr) {
  int t = blockIdx.x * 256 + threadIdx.x;
  if (t >= 6 * N_TILE) return;
  int s = t / N_TILE;
  int i = t - s * N_TILE;
  int* p = partial + (size_t)s * NCHK * N_TILE + i;
  int run = 0;
  if (s < 3) {
#pragma unroll
    for (int c = 0; c < NCHK; ++c) {
      int v = p[(size_t)c * N_TILE];
      p[(size_t)c * N_TILE] = run;
      run += v;
    }
    if (s == 0) id_tt[i] = run;
    else if (s == 1) id_rt[i] = run;
    else id_tr[i] = run;
  } else {
#pragma unroll
    for (int c = 0; c < NCHK; ++c) run += p[(size_t)c * N_TILE];
    float v = rsqrtf((float)max(run, 1));
    if (s == 3) os_tt[i] = v;
    else if (s == 4) os_rt[i] = v;
    else os_tr[i] = v;
  }
}

// ---------------- scan stage 1 ----------------
__global__ __launch_bounds__(1024) void k_scan1(const int* __restrict__ d0,
                                                const int* __restrict__ d1,
                                                const int* __restrict__ d2,
                                                int* __restrict__ p0,
                                                int* __restrict__ p1,
                                                int* __restrict__ p2,
                                                int* __restrict__ bsum) {
  int arr = blockIdx.x / NB;
  int blk = blockIdx.x % NB;
  const int* deg = arr == 0 ? d0 : (arr == 1 ? d1 : d2);
  int* part = arr == 0 ? p0 : (arr == 1 ? p1 : p2);
  __shared__ int ts[1024];
  int tid = threadIdx.x;
  int i = blk * 1024 + tid;
  int v = (i < N_TILE) ? deg[i] : 0;
  ts[tid] = v;
  __syncthreads();
  for (int d = 1; d < 1024; d <<= 1) {
    int t = (tid >= d) ? ts[tid - d] : 0;
    __syncthreads();
    ts[tid] += t;
    __syncthreads();
  }
  if (i < N_TILE) part[i] = ts[tid] - v;
  if (tid == 1023) bsum[arr * NB + blk] = ts[1023];
}

// ---------------- scan stage 2 ----------------
__global__ __launch_bounds__(256) void k_scan2(const int* __restrict__ bsum,
                                               int* __restrict__ bs) {
  int wv = threadIdx.x >> 6;
  int lane = threadIdx.x & 63;
  if (wv >= 3) return;
  int v = (lane < NB) ? bsum[wv * NB + lane] : 0;
  int orig = v;
#pragma unroll
  for (int o = 1; o < 64; o <<= 1) {
    int t = __shfl_up(v, o);
    if (lane >= o) v += t;
  }
  if (lane < NB) bs[wv * (NB + 1) + lane] = v - orig;
  if (lane == NB - 1) bs[wv * (NB + 1) + NB] = v;
}

// ---------------- finalize ----------------
__global__ void k_finalize(const int* __restrict__ pp_tt, const int* __restrict__ pp_rt,
                           const int* __restrict__ pp_tr, const int* __restrict__ bs,
                           int* __restrict__ rp_tt, int* __restrict__ rp_rt,
                           int* __restrict__ rp_tr,
                           const int* __restrict__ id_tt, const int* __restrict__ id_rt,
                           const int* __restrict__ id_tr,
                           float* __restrict__ is_tt, float* __restrict__ is_rt,
                           float* __restrict__ is_tr) {
  int i = blockIdx.x * blockDim.x + threadIdx.x;
  if (i >= N_TILE) return;
  int b = i >> 10;
  rp_tt[i] = pp_tt[i] + bs[0 * (NB + 1) + b];
  rp_rt[i] = pp_rt[i] + bs[1 * (NB + 1) + b];
  rp_tr[i] = pp_tr[i] + bs[2 * (NB + 1) + b];
  if (i == 0) {
    rp_tt[N_TILE] = bs[0 * (NB + 1) + NB];
    rp_rt[N_TILE] = bs[1 * (NB + 1) + NB];
    rp_tr[N_RR] = bs[2 * (NB + 1) + NB];
  }
  is_tt[i] = rsqrtf((float)max(id_tt[i], 1));
  is_rt[i] = rsqrtf((float)max(id_rt[i], 1));
  is_tr[i] = rsqrtf((float)max(id_tr[i], 1));
}

// ---------------- CSR fill: one thread per edge, atomic-free ----------------
__global__ __launch_bounds__(256) void k_fill(
    const int* __restrict__ tt_src, const int* __restrict__ tt_dst,
    const int* __restrict__ rt_src, const int* __restrict__ rt_dst,
    const int* __restrict__ tr_src, const int* __restrict__ tr_dst,
    const int* __restrict__ rp_tt, const int* __restrict__ rp_rt,
    const int* __restrict__ rp_tr,
    const float* __restrict__ os_tt, const float* __restrict__ os_rt,
    const float* __restrict__ os_tr,
    const int* __restrict__ partial, const int* __restrict__ rank,
    int2* __restrict__ pr_tt, int2* __restrict__ pr_rt, int2* __restrict__ pr_tr) {
  int i = blockIdx.x * 256 + threadIdx.x;
  if (i >= E_ALL) return;
  const int* srcA; const int* dstA; const int* rp; const float* os; int2* pr;
  int j, s, ec;
  if (i < E_TT) {
    s = 0; j = i; ec = E_TT / NCHK;
    srcA = tt_src; dstA = tt_dst; rp = rp_tt; os = os_tt; pr = pr_tt;
  } else if (i < E_TT + E_RT) {
    s = 1; j = i - E_TT; ec = E_RT / NCHK;
    srcA = rt_src; dstA = rt_dst; rp = rp_rt; os = os_rt; pr = pr_rt;
  } else {
    s = 2; j = i - E_TT - E_RT; ec = E_TR / NCHK;
    srcA = tr_src; dstA = tr_dst; rp = rp_tr; os = os_tr; pr = pr_tr;
  }
  int d = dstA[j];
  int c = j / ec;
  int slot = rp[d] + partial[(size_t)(s * NCHK + c) * N_TILE + d] + rank[i];
  int sv = srcA[j];
  int2 v;
  v.x = sv;
  v.y = __float_as_int(os[sv]);
  pr[slot] = v;
}

// ---------------- fused prep: weight split (blocks < WPREP_BLOCKS) + x->bf16 conv ----
__global__ __launch_bounds__(256) void k_prep(
    const float* __restrict__ W0, const float* __restrict__ W1,
    const float* __restrict__ W2, const float* __restrict__ W3,
    const float* __restrict__ W4,
    u16* __restrict__ T0h, u16* __restrict__ T0l,
    u16* __restrict__ T1h, u16* __restrict__ T1l,
    u16* __restrict__ T2h, u16* __restrict__ T2l,
    u16* __restrict__ T3h, u16* __restrict__ T3l,
    u16* __restrict__ T4h, u16* __restrict__ T4l,
    const float* __restrict__ xa, const float* __restrict__ xb,
    u16* __restrict__ oa, u16* __restrict__ ob) {
  int bid = blockIdx.x;
  if (bid < WPREP_BLOCKS) {
    int s = bid >> 6;
    int idx = ((bid & 63) << 8) + threadIdx.x;   // n*128+k
    const float* W = s == 0 ? W0 : (s == 1 ? W1 : (s == 2 ? W2 : (s == 3 ? W3 : W4)));
    u16* Th = s == 0 ? T0h : (s == 1 ? T1h : (s == 2 ? T2h : (s == 3 ? T3h : T4h)));
    u16* Tl = s == 0 ? T0l : (s == 1 ? T1l : (s == 2 ? T2l : (s == 3 ? T3l : T4l)));
    int n = idx >> 7, k = idx & 127;
    float w = W[k * 128 + n];
    u16 h = f2bf(w);
    Th[idx] = h;
    Tl[idx] = f2bf(w - bf2f(h));
    return;
  }
  const size_t TOT = (size_t)N_TILE * D / 8;
  size_t i = (size_t)(bid - WPREP_BLOCKS) * 256 + threadIdx.x;
  if (i >= 2 * TOT) return;
  const float* src = (i < TOT) ? xa : xb;
  u16* dst = (i < TOT) ? oa : ob;
  size_t j = ((i < TOT) ? i : i - TOT) * 8;
  float4 v0 = *(const float4*)(src + j);
  float4 v1 = *(const float4*)(src + j + 4);
  ushort4 h0, h1;
  h0.x = f2bf(v0.x); h0.y = f2bf(v0.y); h0.z = f2bf(v0.z); h0.w = f2bf(v0.w);
  h1.x = f2bf(v1.x); h1.y = f2bf(v1.y); h1.z = f2bf(v1.z); h1.w = f2bf(v1.w);
  *(ushort4*)(dst + j) = h0;
  *(ushort4*)(dst + j + 4) = h1;
}

// ---------------- fused aggregation (up to 3 relations) -> split-bf16 planes
// out_{hi,lo}[d][:] = split( isc[d] * sum_e w_e * x[src_e] );  x rows = bf16.
// Quarter-wave: 16 lanes x 16B (8 bf16) per row; q handles edges e+q, e+4+q.
// Inner loop: 1 shl + 1 v_pk_fma_f32 per 2 elements (cheap-hi unpack).
__global__ __launch_bounds__(256) void k_agg3(
    const u16* __restrict__ x0, const int* __restrict__ rp0, const int2* __restrict__ pr0,
    const float* __restrict__ isc0, u16* __restrict__ oh0, u16* __restrict__ ol0, int n0,
    const u16* __restrict__ x1, const int* __restrict__ rp1, const int2* __restrict__ pr1,
    const float* __restrict__ isc1, u16* __restrict__ oh1, u16* __restrict__ ol1, int n1,
    const u16* __restrict__ x2, const int* __restrict__ rp2, const int2* __restrict__ pr2,
    const float* __restrict__ isc2, u16* __restrict__ oh2, u16* __restrict__ ol2, int n2) {
  int gw = (blockIdx.x * blockDim.x + threadIdx.x) >> 6;
  int lane = threadIdx.x & 63;
  int q = lane >> 4;        // edge-slot within group of 4
  int l4 = lane & 15;       // uint4 slot within the 256B row
  const u16* x; const int* rp; const int2* pr; const float* isc;
  u16* oh; u16* ol; int wid;
  if (gw < n0) { x = x0; rp = rp0; pr = pr0; isc = isc0; oh = oh0; ol = ol0; wid = gw; }
  else if (gw < n0 + n1) { x = x1; rp = rp1; pr = pr1; isc = isc1; oh = oh1; ol = ol1; wid = gw - n0; }
  else if (gw < n0 + n1 + n2) { x = x2; rp = rp2; pr = pr2; isc = isc2; oh = oh2; ol = ol2; wid = gw - n0 - n1; }
  else return;
  int beg = rp[wid], end = rp[wid + 1];
  v2f a0[4], a1[4];
#pragma unroll
  for (int j = 0; j < 4; ++j) { a0[j] = (v2f){0.f, 0.f}; a1[j] = (v2f){0.f, 0.f}; }
  const uint4* xb = (const uint4*)x + l4;   // row = 128 bf16 = 16 uint4
  for (int e = beg; e < end; e += 8) {
    int lim = end - 1;
    int i0 = e + q, i1 = e + 4 + q;
    int2 p0 = pr[min(i0, lim)];
    int2 p1 = pr[min(i1, lim)];
    float w0 = (i0 < end) ? __int_as_float(p0.y) : 0.f;
    float w1 = (i1 < end) ? __int_as_float(p1.y) : 0.f;
    v2f w02 = {w0, w0}, w12 = {w1, w1};
    uint4 u0 = xb[(size_t)p0.x * 16];
    uint4 u1 = xb[(size_t)p1.x * 16];
    pk_fma(a0[0], bfpair(u0.x), w02);
    pk_fma(a0[1], bfpair(u0.y), w02);
    pk_fma(a0[2], bfpair(u0.z), w02);
    pk_fma(a0[3], bfpair(u0.w), w02);
    pk_fma(a1[0], bfpair(u1.x), w12);
    pk_fma(a1[1], bfpair(u1.y), w12);
    pk_fma(a1[2], bfpair(u1.z), w12);
    pk_fma(a1[3], bfpair(u1.w), w12);
  }
  float s[8];
#pragma unroll
  for (int j = 0; j < 4; ++j) {
    v2f t = a0[j] + a1[j];
    s[2 * j] = t.x;
    s[2 * j + 1] = t.y;
  }
#pragma unroll
  for (int j = 0; j < 8; ++j) {
    s[j] += __shfl_xor(s[j], 16);
    s[j] += __shfl_xor(s[j], 32);
  }
  if (q == 0) {
    float iv = isc[wid];
    uint4 hw, lw;
    unsigned hb[8], lb[8];
#pragma unroll
    for (int j = 0; j < 8; ++j) {
      float r = s[j] * iv;
      hb[j] = f2bf(r);
      lb[j] = f2bf(r - bf2f((u16)hb[j]));
    }
    hw.x = hb[0] | (hb[1] << 16); hw.y = hb[2] | (hb[3] << 16);
    hw.z = hb[4] | (hb[5] << 16); hw.w = hb[6] | (hb[7] << 16);
    lw.x = lb[0] | (lb[1] << 16); lw.y = lb[2] | (lb[3] << 16);
    lw.z = lb[4] | (lb[5] << 16); lw.w = lb[6] | (lb[7] << 16);
    *(uint4*)(oh + (size_t)wid * D + l4 * 8) = hw;
    *(uint4*)(ol + (size_t)wid * D + l4 * 8) = lw;
  }
}

// ---------------- MFMA split-bf16 GEMM(+GEMM) + bias + relu ----------------
// out = relu( A1@W1 (+ A2@W2) + b1 (+ b2) ); OBF: output bf16 rows, else fp32.
// C = Ahi@Whi + Ahi@Wlo + Alo@Whi (3-product split reconstruction).
template<int NREL, bool OBF>
__global__ __launch_bounds__(256) void k_gemm_m(
    const u16* __restrict__ A1h, const u16* __restrict__ A1l,
    const u16* __restrict__ A2h, const u16* __restrict__ A2l,
    const u16* __restrict__ Wt1h, const u16* __restrict__ Wt1l,
    const u16* __restrict__ Wt2h, const u16* __restrict__ Wt2l,
    const float* __restrict__ b1, const float* __restrict__ b2,
    void* __restrict__ outv, int nrows) {
  __shared__ u16 Ah[128][40];   // pad 40: 2-way-only LDS conflicts on b128 reads
  __shared__ u16 Al[128][40];
  __shared__ u16 Wh[128][40];   // [n][k]
  __shared__ u16 Wl[128][40];
  int tid = threadIdx.x;
  int wv = tid >> 6, lane = tid & 63;
  int l15 = lane & 15, lg = lane >> 4;
  int r0 = blockIdx.x * 128;
  f32x4 acc[2][8];
#pragma unroll
  for (int i = 0; i < 2; ++i)
#pragma unroll
    for (int j = 0; j < 8; ++j) acc[i][j] = (f32x4){0.f, 0.f, 0.f, 0.f};

  int srow = tid >> 1;             // 0..127
  int c0 = (tid & 1) * 16;         // u16 col base 0 or 16
  int gr = r0 + srow;

  for (int rel = 0; rel < NREL; ++rel) {
    const u16* pAh = (NREL == 2 && rel) ? A2h : A1h;
    const u16* pAl = (NREL == 2 && rel) ? A2l : A1l;
    const u16* pWh = (NREL == 2 && rel) ? Wt2h : Wt1h;
    const u16* pWl = (NREL == 2 && rel) ? Wt2l : Wt1l;
    for (int k0 = 0; k0 < 128; k0 += 32) {
      __syncthreads();
      uint4 z = {0, 0, 0, 0};
      uint4 va0 = z, va1 = z, vb0 = z, vb1 = z;
      if (gr < nrows) {
        va0 = *(const uint4*)(pAh + (size_t)gr * 128 + k0 + c0);
        va1 = *(const uint4*)(pAh + (size_t)gr * 128 + k0 + c0 + 8);
        vb0 = *(const uint4*)(pAl + (size_t)gr * 128 + k0 + c0);
        vb1 = *(const uint4*)(pAl + (size_t)gr * 128 + k0 + c0 + 8);
      }
      *(uint4*)&Ah[srow][c0] = va0;
      *(uint4*)&Ah[srow][c0 + 8] = va1;
      *(uint4*)&Al[srow][c0] = vb0;
      *(uint4*)&Al[srow][c0 + 8] = vb1;
      *(uint4*)&Wh[srow][c0]     = *(const uint4*)(pWh + (size_t)srow * 128 + k0 + c0);
      *(uint4*)&Wh[srow][c0 + 8] = *(const uint4*)(pWh + (size_t)srow * 128 + k0 + c0 + 8);
      *(uint4*)&Wl[srow][c0]     = *(const uint4*)(pWl + (size_t)srow * 128 + k0 + c0);
      *(uint4*)&Wl[srow][c0 + 8] = *(const uint4*)(pWl + (size_t)srow * 128 + k0 + c0 + 8);
      __syncthreads();
      bf16x8 a0h = *(const bf16x8*)&Ah[wv * 32 + l15][lg * 8];
      bf16x8 a0l = *(const bf16x8*)&Al[wv * 32 + l15][lg * 8];
      bf16x8 a1h = *(const bf16x8*)&Ah[wv * 32 + 16 + l15][lg * 8];
      bf16x8 a1l = *(const bf16x8*)&Al[wv * 32 + 16 + l15][lg * 8];
#pragma unroll
      for (int ct = 0; ct < 8; ++ct) {
        bf16x8 bh = *(const bf16x8*)&Wh[ct * 16 + l15][lg * 8];
        bf16x8 bl = *(const bf16x8*)&Wl[ct * 16 + l15][lg * 8];
        acc[0][ct] = __builtin_amdgcn_mfma_f32_16x16x32_bf16(a0h, bh, acc[0][ct], 0, 0, 0);
        acc[0][ct] = __builtin_amdgcn_mfma_f32_16x16x32_bf16(a0h, bl, acc[0][ct], 0, 0, 0);
        acc[0][ct] = __builtin_amdgcn_mfma_f32_16x16x32_bf16(a0l, bh, acc[0][ct], 0, 0, 0);
        acc[1][ct] = __builtin_amdgcn_mfma_f32_16x16x32_bf16(a1h, bh, acc[1][ct], 0, 0, 0);
        acc[1][ct] = __builtin_amdgcn_mfma_f32_16x16x32_bf16(a1h, bl, acc[1][ct], 0, 0, 0);
        acc[1][ct] = __builtin_amdgcn_mfma_f32_16x16x32_bf16(a1l, bh, acc[1][ct], 0, 0, 0);
      }
    }
  }
  // epilogue: bias + relu; C layout col=lane&15, row=(lane>>4)*4+reg
#pragma unroll
  for (int ct = 0; ct < 8; ++ct) {
    int col = ct * 16 + l15;
    float bias = b1[col];
    if (NREL == 2) bias += b2[col];
#pragma unroll
    for (int rt = 0; rt < 2; ++rt) {
      int rowb = r0 + wv * 32 + rt * 16 + lg * 4;
#pragma unroll
      for (int r = 0; r < 4; ++r) {
        int row = rowb + r;
        if (row < nrows) {
          float v = fmaxf(acc[rt][ct][r] + bias, 0.f);
          if (OBF) ((u16*)outv)[(size_t)row * 128 + col] = f2bf(v);
          else ((float*)outv)[(size_t)row * 128 + col] = v;
        }
      }
    }
  }
}

// ---------------- per-graph mean pooling ----------------
#define PCHUNK 256
__global__ __launch_bounds__(128) void k_pool(const float* __restrict__ H,
                                              const int* __restrict__ gid,
                                              float* __restrict__ sums,
                                              float* __restrict__ cnt, int n) {
  int col = threadIdx.x;
  int start = blockIdx.x * PCHUNK;
  if (start >= n) return;
  int end = min(start + PCHUNK, n);
  float acc = 0.f;
  int cur = gid[start];
  int seglen = 0;
  for (int r = start; r < end; ++r) {
    int g = gid[r];
    if (g != cur) {
      atomicAdd(&sums[cur * D + col], acc);
      if (col == 0) atomicAdd(&cnt[cur], (float)seglen);
      acc = 0.f; seglen = 0; cur = g;
    }
    acc += H[(size_t)r * D + col];
    seglen++;
  }
  atomicAdd(&sums[cur * D + col], acc);
  if (col == 0) atomicAdd(&cnt[cur], (float)seglen);
}

// ---------------- final MLP on [16,128] ----------------
__global__ __launch_bounds__(256) void k_final(const float* __restrict__ sums,
                                               const float* __restrict__ cnt,
                                               const float* __restrict__ Wm1,
                                               const float* __restrict__ bm1,
                                               const float* __restrict__ Wm2,
                                               const float* __restrict__ bm2,
                                               float* __restrict__ out) {
  __shared__ float hg[16][128];
  __shared__ float t1[16][128];
  int tid = threadIdx.x;
  for (int i = tid; i < 16 * 128; i += 256) {
    int g = i >> 7, c = i & 127;
    hg[g][c] = sums[i] / fmaxf(cnt[g], 1.f);
  }
  __syncthreads();
  for (int i = tid; i < 16 * 128; i += 256) {
    int g = i >> 7, c = i & 127;
    float a = bm1[c];
    for (int k = 0; k < 128; ++k) a = fmaf(hg[g][k], Wm1[k * 128 + c], a);
    t1[g][c] = fmaxf(a, 0.f);
  }
  __syncthreads();
  int g = tid >> 4, l = tid & 15;
  float p = 0.f;
  for (int c = l; c < 128; c += 16) p = fmaf(t1[g][c], Wm2[c], p);
#pragma unroll
  for (int o = 8; o; o >>= 1) p += __shfl_down(p, o, 16);
  if (l == 0) out[g] = p + bm2[0];
}

extern "C" void kernel_launch(void* const* d_in, const int* in_sizes, int n_in,
                              void* d_out, int out_size, void* d_ws, size_t ws_size,
                              hipStream_t stream) {
  const float* x_tile = (const float*)d_in[0];
  const float* x_rr   = (const float*)d_in[1];
  const int* tt_src = (const int*)d_in[2];
  const int* tt_dst = (const int*)d_in[3];
  const int* rt_src = (const int*)d_in[4];
  const int* rt_dst = (const int*)d_in[5];
  const int* tr_src = (const int*)d_in[6];
  const int* tr_dst = (const int*)d_in[7];
  const int* tile_gid = (const int*)d_in[8];
  const float* W1_tt = (const float*)d_in[9];  const float* b1_tt = (const float*)d_in[10];
  const float* W1_rt = (const float*)d_in[11]; const float* b1_rt = (const float*)d_in[12];
  const float* W1_tr = (const float*)d_in[13]; const float* b1_tr = (const float*)d_in[14];
  const float* W2_tt = (const float*)d_in[15]; const float* b2_tt = (const float*)d_in[16];
  const float* W2_rt = (const float*)d_in[17]; const float* b2_rt = (const float*)d_in[18];
  const float* Wm1 = (const float*)d_in[21]; const float* bm1 = (const float*)d_in[22];
  const float* Wm2 = (const float*)d_in[23]; const float* bm2 = (const float*)d_in[24];

  char* ws = (char*)d_ws;
  size_t off = 0;
  auto allocB = [&](size_t bytes) {
    void* p = ws + off;
    off += (bytes + 255) & ~(size_t)255;
    return p;
  };
  // ---- zero region (memset each call) ----
  float* psum = (float*)allocB(N_G * D * 4);
  float* pcnt = (float*)allocB(N_G * 4);
  size_t zero_bytes = off;
  // ---- rest (all fully written before read) ----
  int* partial = (int*)allocB((size_t)6 * NCHK * N_TILE * 4);
  int* rank = (int*)allocB((size_t)E_ALL * 4);
  int* ideg_tt = (int*)allocB(N_TILE * 4);
  int* ideg_rt = (int*)allocB(N_TILE * 4);
  int* ideg_tr = (int*)allocB(N_RR * 4);
  int* pp_tt = (int*)allocB(N_TILE * 4);
  int* pp_rt = (int*)allocB(N_TILE * 4);
  int* pp_tr = (int*)allocB(N_RR * 4);
  int* bsum = (int*)allocB(3 * NB * 4);
  int* bs = (int*)allocB(3 * (NB + 1) * 4);
  int* rp_tt = (int*)allocB((N_TILE + 1) * 4);
  int* rp_rt = (int*)allocB((N_TILE + 1) * 4);
  int* rp_tr = (int*)allocB((N_RR + 1) * 4);
  int2* pr_tt = (int2*)allocB((size_t)E_TT * 8);
  int2* pr_rt = (int2*)allocB((size_t)E_RT * 8);
  int2* pr_tr = (int2*)allocB((size_t)E_TR * 8);
  float* osc_tt = (float*)allocB(N_TILE * 4);
  float* osc_rt = (float*)allocB(N_RR * 4);
  float* osc_tr = (float*)allocB(N_TILE * 4);
  float* isc_tt = (float*)allocB(N_TILE * 4);
  float* isc_rt = (float*)allocB(N_TILE * 4);
  float* isc_tr = (float*)allocB(N_RR * 4);
  u16* xt_bf = (u16*)allocB((size_t)N_TILE * D * 2);
  u16* xr_bf = (u16*)allocB((size_t)N_RR * D * 2);
  u16* Ahi = (u16*)allocB((size_t)N_TILE * D * 2);
  u16* Alo = (u16*)allocB((size_t)N_TILE * D * 2);
  u16* Bhi = (u16*)allocB((size_t)N_TILE * D * 2);
  u16* Blo = (u16*)allocB((size_t)N_TILE * D * 2);
  u16* Chi = (u16*)allocB((size_t)N_RR * D * 2);
  u16* Clo = (u16*)allocB((size_t)N_RR * D * 2);
  u16* Ht_bf = (u16*)allocB((size_t)N_TILE * D * 2);   // layer-1 tile output (bf16)
  u16* Hr_bf = (u16*)allocB((size_t)N_RR * D * 2);     // layer-1 rr output (bf16)
  float* Htile = (float*)allocB((size_t)N_TILE * D * 4); // layer-2 output (fp32, pooled)
  u16* Wt1tt_h = (u16*)allocB(D * D * 2); u16* Wt1tt_l = (u16*)allocB(D * D * 2);
  u16* Wt1rt_h = (u16*)allocB(D * D * 2); u16* Wt1rt_l = (u16*)allocB(D * D * 2);
  u16* Wt1tr_h = (u16*)allocB(D * D * 2); u16* Wt1tr_l = (u16*)allocB(D * D * 2);
  u16* Wt2tt_h = (u16*)allocB(D * D * 2); u16* Wt2tt_l = (u16*)allocB(D * D * 2);
  u16* Wt2rt_h = (u16*)allocB(D * D * 2); u16* Wt2rt_l = (u16*)allocB(D * D * 2);
  (void)ws_size; (void)in_sizes; (void)n_in; (void)out_size;

  hipMemsetAsync(d_ws, 0, zero_bytes, stream);

  // ---- fused prep: weight split + x->bf16 conversion ----
  {
    int convBlocks = (2 * N_TILE * (D / 8) + 255) / 256;
    k_prep<<<WPREP_BLOCKS + convBlocks, 256, 0, stream>>>(
        W1_tt, W1_rt, W1_tr, W2_tt, W2_rt,
        Wt1tt_h, Wt1tt_l, Wt1rt_h, Wt1rt_l, Wt1tr_h, Wt1tr_l,
        Wt2tt_h, Wt2tt_l, Wt2rt_h, Wt2rt_l,
        x_tile, x_rr, xt_bf, xr_bf);
  }

  // ---- CSR build: zero global atomics, atomic-free fill via hist-rank ----
  k_hist<<<6 * NBKT * NCHK, 256, 0, stream>>>(
      tt_src, tt_dst, rt_src, rt_dst, tr_src, tr_dst, partial, rank);
  k_hreduce<<<(6 * N_TILE + 255) / 256, 256, 0, stream>>>(
      partial, ideg_tt, ideg_rt, ideg_tr, osc_tt, osc_rt, osc_tr);
  k_scan1<<<3 * NB, 1024, 0, stream>>>(ideg_tt, ideg_rt, ideg_tr, pp_tt, pp_rt, pp_tr, bsum);
  k_scan2<<<1, 256, 0, stream>>>(bsum, bs);
  k_finalize<<<(N_TILE + 255) / 256, 256, 0, stream>>>(
      pp_tt, pp_rt, pp_tr, bs, rp_tt, rp_rt, rp_tr,
      ideg_tt, ideg_rt, ideg_tr, isc_tt, isc_rt, isc_tr);
  k_fill<<<(E_ALL + 255) / 256, 256, 0, stream>>>(
      tt_src, tt_dst, rt_src, rt_dst, tr_src, tr_dst,
      rp_tt, rp_rt, rp_tr, osc_tt, osc_rt, osc_tr,
      partial, rank, pr_tt, pr_rt, pr_tr);

  const int gemmBlocks = (N_TILE + 127) / 128;

  // ---- layer 1: all three aggs fused, bf16 gather ----
  {
    int totw = N_TILE + N_TILE + N_RR;
    k_agg3<<<(totw * 64 + 255) / 256, 256, 0, stream>>>(
        xt_bf, rp_tt, pr_tt, isc_tt, Ahi, Alo, N_TILE,
        xr_bf, rp_rt, pr_rt, isc_rt, Bhi, Blo, N_TILE,
        xt_bf, rp_tr, pr_tr, isc_tr, Chi, Clo, N_RR);
  }
  k_gemm_m<1, true><<<gemmBlocks, 256, 0, stream>>>(
      Chi, Clo, nullptr, nullptr, Wt1tr_h, Wt1tr_l, nullptr, nullptr,
      b1_tr, nullptr, Hr_bf, N_RR);
  k_gemm_m<2, true><<<gemmBlocks, 256, 0, stream>>>(
      Ahi, Alo, Bhi, Blo, Wt1tt_h, Wt1tt_l, Wt1rt_h, Wt1rt_l,
      b1_tt, b1_rt, Ht_bf, N_TILE);

  // ---- layer 2: bf16 gather of layer-1 outputs (tr relation skipped) ----
  {
    int totw = N_TILE + N_TILE;
    k_agg3<<<(totw * 64 + 255) / 256, 256, 0, stream>>>(
        Ht_bf, rp_tt, pr_tt, isc_tt, Ahi, Alo, N_TILE,
        Hr_bf, rp_rt, pr_rt, isc_rt, Bhi, Blo, N_TILE,
        nullptr, nullptr, nullptr, nullptr, nullptr, nullptr, 0);
  }
  k_gemm_m<2, false><<<gemmBlocks, 256, 0, stream>>>(
      Ahi, Alo, Bhi, Blo, Wt2tt_h, Wt2tt_l, Wt2rt_h, Wt2rt_l,
      b2_tt, b2_rt, Htile, N_TILE);

  // ---- pooling + MLP head ----
  k_pool<<<(N_TILE + PCHUNK - 1) / PCHUNK, 128, 0, stream>>>(Htile, tile_gid, psum, pcnt, N_TILE);
  k_final<<<1, 256, 0, stream>>>(psum, pcnt, Wm1, bm1, Wm2, bm2, (float*)d_out);
}

// Round 14
// 349.868 us; speedup vs baseline: 1.3351x; 1.1666x over previous
//
#include <hip/hip_runtime.h>

#define N_TILE 50000
#define N_RR   50000
#define D      128
#define E_TT   800000
#define E_RT   400000
#define E_TR   400000
#define N_G    16
#define NB     ((N_TILE + 1023) / 1024)   // scan blocks per array (=49)
#define E_ALL  (E_TT + E_RT + E_TR)
#define BKT    16384                       // bins per bucket (16-bit packed LDS counters)
#define NBKT   ((N_TILE + BKT - 1) / BKT)  // =4
#define NCHK   25                          // edge chunks (all E divisible by 25)
#define WPREP_BLOCKS 320                   // 5 weights * 64 blocks

static_assert(NB <= 64, "scan2 uses one wave per array");
static_assert(N_TILE == N_RR, "shared bucket geometry assumes equal node counts");
static_assert((BKT & (BKT - 1)) == 0, "bucket must be pow2");
static_assert(E_TT % NCHK == 0 && E_RT % NCHK == 0 && E_TR % NCHK == 0, "chunking");

typedef __attribute__((ext_vector_type(8))) short bf16x8;
typedef __attribute__((ext_vector_type(4))) float f32x4;
typedef __attribute__((ext_vector_type(2))) float v2f;
typedef unsigned short u16;

__device__ inline u16 f2bf(float f) {
  unsigned u = __float_as_uint(f);
  unsigned r = (u + 0x7FFFu + ((u >> 16) & 1u)) >> 16;   // RNE
  return (u16)r;
}
__device__ inline float bf2f(u16 h) { return __uint_as_float(((unsigned)h) << 16); }

// packed FMA: acc.{x,y} += pair.{x,y} * w.{x,y}  (one VOP3P instruction)
__device__ inline void pk_fma(v2f& acc, v2f pair, v2f w) {
  asm("v_pk_fma_f32 %0, %1, %2, %0" : "+v"(acc) : "v"(pair), "v"(w));
}
// unpack u32 (2 bf16) -> {lo, cheap-hi}; hi keeps low 16 bits as sub-ulp noise
__device__ inline v2f bfpair(unsigned w) {
  v2f p;
  p.x = __uint_as_float(w << 16);
  p.y = __uint_as_float(w);
  return p;
}

// ---------------- bucketed LDS histogram + rank capture: NO global atomics ----
__global__ __launch_bounds__(256) void k_hist(
    const int* __restrict__ tt_src, const int* __restrict__ tt_dst,
    const int* __restrict__ rt_src, const int* __restrict__ rt_dst,
    const int* __restrict__ tr_src, const int* __restrict__ tr_dst,
    int* __restrict__ partial, int* __restrict__ rank) {
  __shared__ unsigned h[BKT / 2];
  int bid = blockIdx.x;
  int s = bid / (NBKT * NCHK);
  int rem = bid % (NBKT * NCHK);
  int b = rem / NCHK;
  int c = rem % NCHK;
  const int* arr; int E; int roff = 0;
  switch (s) {
    case 0: arr = tt_dst; E = E_TT; roff = 0; break;
    case 1: arr = rt_dst; E = E_RT; roff = E_TT; break;
    case 2: arr = tr_dst; E = E_TR; roff = E_TT + E_RT; break;
    case 3: arr = tt_src; E = E_TT; break;
    case 4: arr = rt_src; E = E_RT; break;
    default: arr = tr_src; E = E_TR; break;
  }
  bool isdst = s < 3;
  for (int j = threadIdx.x; j < BKT / 2; j += 256) h[j] = 0;
  __syncthreads();
  int ec = E / NCHK;
  int lo = c * ec, hi = lo + ec;
  int base = b * BKT;
  for (int i = lo + threadIdx.x; i < hi; i += 256) {
    unsigned int off = (unsigned int)(arr[i] - base);
    if (off < BKT) {
      unsigned sh = (off & 1u) << 4;
      unsigned r = atomicAdd(&h[off >> 1], 1u << sh);
      if (isdst) rank[roff + i] = (int)((r >> sh) & 0xffffu);
    }
  }
  __syncthreads();
  int* dst = partial + (size_t)(s * NCHK + c) * N_TILE;
  for (int j = threadIdx.x; j < BKT; j += 256) {
    int bin = base + j;
    if (bin < N_TILE)
      dst[bin] = (int)((h[j >> 1] >> ((j & 1) << 4)) & 0xffffu);
  }
}

// ---------------- reduce partials ----------------
__global__ __launch_bounds__(256) void k_hreduce(
    int* __restrict__ partial,
    int* __restrict__ id_tt, int* __restrict__ id_rt, int* __restrict__ id_tr,
    float* __restrict__ os_tt, float* __restrict__ os_rt, float* __restrict__ os_tr) {
  int t = blockIdx.x * 256 + threadIdx.x;
  if (t >= 6 * N_TILE) return;
  int s = t / N_TILE;
  int i = t - s * N_TILE;
  int* p = partial + (size_t)s * NCHK * N_TILE + i;
  int run = 0;
  if (s < 3) {
#pragma unroll
    for (int c = 0; c < NCHK; ++c) {
      int v = p[(size_t)c * N_TILE];
      p[(size_t)c * N_TILE] = run;
      run += v;
    }
    if (s == 0) id_tt[i] = run;
    else if (s == 1) id_rt[i] = run;
    else id_tr[i] = run;
  } else {
#pragma unroll
    for (int c = 0; c < NCHK; ++c) run += p[(size_t)c * N_TILE];
    float v = rsqrtf((float)max(run, 1));
    if (s == 3) os_tt[i] = v;
    else if (s == 4) os_rt[i] = v;
    else os_tr[i] = v;
  }
}

// ---------------- scan stage 1 ----------------
__global__ __launch_bounds__(1024) void k_scan1(const int* __restrict__ d0,
                                                const int* __restrict__ d1,
                                                const int* __restrict__ d2,
                                                int* __restrict__ p0,
                                                int* __restrict__ p1,
                                                int* __restrict__ p2,
                                                int* __restrict__ bsum) {
  int arr = blockIdx.x / NB;
  int blk = blockIdx.x % NB;
  const int* deg = arr == 0 ? d0 : (arr == 1 ? d1 : d2);
  int* part = arr == 0 ? p0 : (arr == 1 ? p1 : p2);
  __shared__ int ts[1024];
  int tid = threadIdx.x;
  int i = blk * 1024 + tid;
  int v = (i < N_TILE) ? deg[i] : 0;
  ts[tid] = v;
  __syncthreads();
  for (int d = 1; d < 1024; d <<= 1) {
    int t = (tid >= d) ? ts[tid - d] : 0;
    __syncthreads();
    ts[tid] += t;
    __syncthreads();
  }
  if (i < N_TILE) part[i] = ts[tid] - v;
  if (tid == 1023) bsum[arr * NB + blk] = ts[1023];
}

// ---------------- scan stage 2 ----------------
__global__ __launch_bounds__(256) void k_scan2(const int* __restrict__ bsum,
                                               int* __restrict__ bs) {
  int wv = threadIdx.x >> 6;
  int lane = threadIdx.x & 63;
  if (wv >= 3) return;
  int v = (lane < NB) ? bsum[wv * NB + lane] : 0;
  int orig = v;
#pragma unroll
  for (int o = 1; o < 64; o <<= 1) {
    int t = __shfl_up(v, o);
    if (lane >= o) v += t;
  }
  if (lane < NB) bs[wv * (NB + 1) + lane] = v - orig;
  if (lane == NB - 1) bs[wv * (NB + 1) + NB] = v;
}

// ---------------- finalize ----------------
__global__ void k_finalize(const int* __restrict__ pp_tt, const int* __restrict__ pp_rt,
                           const int* __restrict__ pp_tr, const int* __restrict__ bs,
                           int* __restrict__ rp_tt, int* __restrict__ rp_rt,
                           int* __restrict__ rp_tr,
                           const int* __restrict__ id_tt, const int* __restrict__ id_rt,
                           const int* __restrict__ id_tr,
                           float* __restrict__ is_tt, float* __restrict__ is_rt,
                           float* __restrict__ is_tr) {
  int i = blockIdx.x * blockDim.x + threadIdx.x;
  if (i >= N_TILE) return;
  int b = i >> 10;
  rp_tt[i] = pp_tt[i] + bs[0 * (NB + 1) + b];
  rp_rt[i] = pp_rt[i] + bs[1 * (NB + 1) + b];
  rp_tr[i] = pp_tr[i] + bs[2 * (NB + 1) + b];
  if (i == 0) {
    rp_tt[N_TILE] = bs[0 * (NB + 1) + NB];
    rp_rt[N_TILE] = bs[1 * (NB + 1) + NB];
    rp_tr[N_RR] = bs[2 * (NB + 1) + NB];
  }
  is_tt[i] = rsqrtf((float)max(id_tt[i], 1));
  is_rt[i] = rsqrtf((float)max(id_rt[i], 1));
  is_tr[i] = rsqrtf((float)max(id_tr[i], 1));
}

// ---------------- CSR fill: one thread per edge, atomic-free ----------------
__global__ __launch_bounds__(256) void k_fill(
    const int* __restrict__ tt_src, const int* __restrict__ tt_dst,
    const int* __restrict__ rt_src, const int* __restrict__ rt_dst,
    const int* __restrict__ tr_src, const int* __restrict__ tr_dst,
    const int* __restrict__ rp_tt, const int* __restrict__ rp_rt,
    const int* __restrict__ rp_tr,
    const float* __restrict__ os_tt, const float* __restrict__ os_rt,
    const float* __restrict__ os_tr,
    const int* __restrict__ partial, const int* __restrict__ rank,
    int2* __restrict__ pr_tt, int2* __restrict__ pr_rt, int2* __restrict__ pr_tr) {
  int i = blockIdx.x * 256 + threadIdx.x;
  if (i >= E_ALL) return;
  const int* srcA; const int* dstA; const int* rp; const float* os; int2* pr;
  int j, s, ec;
  if (i < E_TT) {
    s = 0; j = i; ec = E_TT / NCHK;
    srcA = tt_src; dstA = tt_dst; rp = rp_tt; os = os_tt; pr = pr_tt;
  } else if (i < E_TT + E_RT) {
    s = 1; j = i - E_TT; ec = E_RT / NCHK;
    srcA = rt_src; dstA = rt_dst; rp = rp_rt; os = os_rt; pr = pr_rt;
  } else {
    s = 2; j = i - E_TT - E_RT; ec = E_TR / NCHK;
    srcA = tr_src; dstA = tr_dst; rp = rp_tr; os = os_tr; pr = pr_tr;
  }
  int d = dstA[j];
  int c = j / ec;
  int slot = rp[d] + partial[(size_t)(s * NCHK + c) * N_TILE + d] + rank[i];
  int sv = srcA[j];
  int2 v;
  v.x = sv;
  v.y = __float_as_int(os[sv]);
  pr[slot] = v;
}

// ---------------- fused prep: weight split (blocks < WPREP_BLOCKS) + x->bf16 conv ----
__global__ __launch_bounds__(256) void k_prep(
    const float* __restrict__ W0, const float* __restrict__ W1,
    const float* __restrict__ W2, const float* __restrict__ W3,
    const float* __restrict__ W4,
    u16* __restrict__ T0h, u16* __restrict__ T0l,
    u16* __restrict__ T1h, u16* __restrict__ T1l,
    u16* __restrict__ T2h, u16* __restrict__ T2l,
    u16* __restrict__ T3h, u16* __restrict__ T3l,
    u16* __restrict__ T4h, u16* __restrict__ T4l,
    const float* __restrict__ xa, const float* __restrict__ xb,
    u16* __restrict__ oa, u16* __restrict__ ob) {
  int bid = blockIdx.x;
  if (bid < WPREP_BLOCKS) {
    int s = bid >> 6;
    int idx = ((bid & 63) << 8) + threadIdx.x;   // n*128+k
    const float* W = s == 0 ? W0 : (s == 1 ? W1 : (s == 2 ? W2 : (s == 3 ? W3 : W4)));
    u16* Th = s == 0 ? T0h : (s == 1 ? T1h : (s == 2 ? T2h : (s == 3 ? T3h : T4h)));
    u16* Tl = s == 0 ? T0l : (s == 1 ? T1l : (s == 2 ? T2l : (s == 3 ? T3l : T4l)));
    int n = idx >> 7, k = idx & 127;
    float w = W[k * 128 + n];
    u16 h = f2bf(w);
    Th[idx] = h;
    Tl[idx] = f2bf(w - bf2f(h));
    return;
  }
  const size_t TOT = (size_t)N_TILE * D / 8;
  size_t i = (size_t)(bid - WPREP_BLOCKS) * 256 + threadIdx.x;
  if (i >= 2 * TOT) return;
  const float* src = (i < TOT) ? xa : xb;
  u16* dst = (i < TOT) ? oa : ob;
  size_t j = ((i < TOT) ? i : i - TOT) * 8;
  float4 v0 = *(const float4*)(src + j);
  float4 v1 = *(const float4*)(src + j + 4);
  ushort4 h0, h1;
  h0.x = f2bf(v0.x); h0.y = f2bf(v0.y); h0.z = f2bf(v0.z); h0.w = f2bf(v0.w);
  h1.x = f2bf(v1.x); h1.y = f2bf(v1.y); h1.z = f2bf(v1.z); h1.w = f2bf(v1.w);
  *(ushort4*)(dst + j) = h0;
  *(ushort4*)(dst + j + 4) = h1;
}

// ---------------- fused aggregation (up to 3 relations) -> split-bf16 planes
// out_{hi,lo}[d][:] = split( isc[d] * sum_e w_e * x[src_e] );  x rows = bf16.
// Quarter-wave: 16 lanes x 16B (8 bf16) per row; q handles edges e+q, e+4+q.
// Bulk loop is clamp-free (tail handled once at the end).
__global__ __launch_bounds__(256) void k_agg3(
    const u16* __restrict__ x0, const int* __restrict__ rp0, const int2* __restrict__ pr0,
    const float* __restrict__ isc0, u16* __restrict__ oh0, u16* __restrict__ ol0, int n0,
    const u16* __restrict__ x1, const int* __restrict__ rp1, const int2* __restrict__ pr1,
    const float* __restrict__ isc1, u16* __restrict__ oh1, u16* __restrict__ ol1, int n1,
    const u16* __restrict__ x2, const int* __restrict__ rp2, const int2* __restrict__ pr2,
    const float* __restrict__ isc2, u16* __restrict__ oh2, u16* __restrict__ ol2, int n2) {
  int gw = (blockIdx.x * blockDim.x + threadIdx.x) >> 6;
  int lane = threadIdx.x & 63;
  int q = lane >> 4;        // edge-slot within group of 4
  int l4 = lane & 15;       // uint4 slot within the 256B row
  const u16* x; const int* rp; const int2* pr; const float* isc;
  u16* oh; u16* ol; int wid;
  if (gw < n0) { x = x0; rp = rp0; pr = pr0; isc = isc0; oh = oh0; ol = ol0; wid = gw; }
  else if (gw < n0 + n1) { x = x1; rp = rp1; pr = pr1; isc = isc1; oh = oh1; ol = ol1; wid = gw - n0; }
  else if (gw < n0 + n1 + n2) { x = x2; rp = rp2; pr = pr2; isc = isc2; oh = oh2; ol = ol2; wid = gw - n0 - n1; }
  else return;
  int beg = rp[wid], end = rp[wid + 1];
  v2f a0[4], a1[4];
#pragma unroll
  for (int j = 0; j < 4; ++j) { a0[j] = (v2f){0.f, 0.f}; a1[j] = (v2f){0.f, 0.f}; }
  const uint4* xb = (const uint4*)x + l4;   // row = 128 bf16 = 16 uint4
  int nfull = (end - beg) & ~7;
  int efull = beg + nfull;
  for (int e = beg; e < efull; e += 8) {
    int2 p0 = pr[e + q];
    int2 p1 = pr[e + 4 + q];
    float w0 = __int_as_float(p0.y);
    float w1 = __int_as_float(p1.y);
    v2f w02 = {w0, w0}, w12 = {w1, w1};
    uint4 u0 = xb[(size_t)p0.x * 16];
    uint4 u1 = xb[(size_t)p1.x * 16];
    pk_fma(a0[0], bfpair(u0.x), w02);
    pk_fma(a0[1], bfpair(u0.y), w02);
    pk_fma(a0[2], bfpair(u0.z), w02);
    pk_fma(a0[3], bfpair(u0.w), w02);
    pk_fma(a1[0], bfpair(u1.x), w12);
    pk_fma(a1[1], bfpair(u1.y), w12);
    pk_fma(a1[2], bfpair(u1.z), w12);
    pk_fma(a1[3], bfpair(u1.w), w12);
  }
  if (efull < end) {
    int lim = end - 1;
    int i0 = efull + q, i1 = efull + 4 + q;
    int2 p0 = pr[min(i0, lim)];
    int2 p1 = pr[min(i1, lim)];
    float w0 = (i0 < end) ? __int_as_float(p0.y) : 0.f;
    float w1 = (i1 < end) ? __int_as_float(p1.y) : 0.f;
    v2f w02 = {w0, w0}, w12 = {w1, w1};
    uint4 u0 = xb[(size_t)p0.x * 16];
    uint4 u1 = xb[(size_t)p1.x * 16];
    pk_fma(a0[0], bfpair(u0.x), w02);
    pk_fma(a0[1], bfpair(u0.y), w02);
    pk_fma(a0[2], bfpair(u0.z), w02);
    pk_fma(a0[3], bfpair(u0.w), w02);
    pk_fma(a1[0], bfpair(u1.x), w12);
    pk_fma(a1[1], bfpair(u1.y), w12);
    pk_fma(a1[2], bfpair(u1.z), w12);
    pk_fma(a1[3], bfpair(u1.w), w12);
  }
  float s[8];
#pragma unroll
  for (int j = 0; j < 4; ++j) {
    v2f t = a0[j] + a1[j];
    s[2 * j] = t.x;
    s[2 * j + 1] = t.y;
  }
#pragma unroll
  for (int j = 0; j < 8; ++j) {
    s[j] += __shfl_xor(s[j], 16);
    s[j] += __shfl_xor(s[j], 32);
  }
  if (q == 0) {
    float iv = isc[wid];
    uint4 hw, lw;
    unsigned hb[8], lb[8];
#pragma unroll
    for (int j = 0; j < 8; ++j) {
      float r = s[j] * iv;
      hb[j] = f2bf(r);
      lb[j] = f2bf(r - bf2f((u16)hb[j]));
    }
    hw.x = hb[0] | (hb[1] << 16); hw.y = hb[2] | (hb[3] << 16);
    hw.z = hb[4] | (hb[5] << 16); hw.w = hb[6] | (hb[7] << 16);
    lw.x = lb[0] | (lb[1] << 16); lw.y = lb[2] | (lb[3] << 16);
    lw.z = lb[4] | (lb[5] << 16); lw.w = lb[6] | (lb[7] << 16);
    *(uint4*)(oh + (size_t)wid * D + l4 * 8) = hw;
    *(uint4*)(ol + (size_t)wid * D + l4 * 8) = lw;
  }
}

// ---------------- MFMA split-bf16 GEMM(+GEMM) + bias + relu ----------------
// out = relu( A1@W1 (+ A2@W2) + b1 (+ b2) ); OBF: output bf16 rows, else fp32.
// C = Ahi@Whi + Ahi@Wlo + Alo@Whi (3-product split reconstruction).
template<int NREL, bool OBF>
__global__ __launch_bounds__(256) void k_gemm_m(
    const u16* __restrict__ A1h, const u16* __restrict__ A1l,
    const u16* __restrict__ A2h, const u16* __restrict__ A2l,
    const u16* __restrict__ Wt1h, const u16* __restrict__ Wt1l,
    const u16* __restrict__ Wt2h, const u16* __restrict__ Wt2l,
    const float* __restrict__ b1, const float* __restrict__ b2,
    void* __restrict__ outv, int nrows) {
  __shared__ u16 Ah[128][40];   // pad 40: 2-way-only LDS conflicts on b128 reads
  __shared__ u16 Al[128][40];
  __shared__ u16 Wh[128][40];   // [n][k]
  __shared__ u16 Wl[128][40];
  int tid = threadIdx.x;
  int wv = tid >> 6, lane = tid & 63;
  int l15 = lane & 15, lg = lane >> 4;
  int r0 = blockIdx.x * 128;
  f32x4 acc[2][8];
#pragma unroll
  for (int i = 0; i < 2; ++i)
#pragma unroll
    for (int j = 0; j < 8; ++j) acc[i][j] = (f32x4){0.f, 0.f, 0.f, 0.f};

  int srow = tid >> 1;             // 0..127
  int c0 = (tid & 1) * 16;         // u16 col base 0 or 16
  int gr = r0 + srow;

  for (int rel = 0; rel < NREL; ++rel) {
    const u16* pAh = (NREL == 2 && rel) ? A2h : A1h;
    const u16* pAl = (NREL == 2 && rel) ? A2l : A1l;
    const u16* pWh = (NREL == 2 && rel) ? Wt2h : Wt1h;
    const u16* pWl = (NREL == 2 && rel) ? Wt2l : Wt1l;
    for (int k0 = 0; k0 < 128; k0 += 32) {
      __syncthreads();
      uint4 z = {0, 0, 0, 0};
      uint4 va0 = z, va1 = z, vb0 = z, vb1 = z;
      if (gr < nrows) {
        va0 = *(const uint4*)(pAh + (size_t)gr * 128 + k0 + c0);
        va1 = *(const uint4*)(pAh + (size_t)gr * 128 + k0 + c0 + 8);
        vb0 = *(const uint4*)(pAl + (size_t)gr * 128 + k0 + c0);
        vb1 = *(const uint4*)(pAl + (size_t)gr * 128 + k0 + c0 + 8);
      }
      *(uint4*)&Ah[srow][c0] = va0;
      *(uint4*)&Ah[srow][c0 + 8] = va1;
      *(uint4*)&Al[srow][c0] = vb0;
      *(uint4*)&Al[srow][c0 + 8] = vb1;
      *(uint4*)&Wh[srow][c0]     = *(const uint4*)(pWh + (size_t)srow * 128 + k0 + c0);
      *(uint4*)&Wh[srow][c0 + 8] = *(const uint4*)(pWh + (size_t)srow * 128 + k0 + c0 + 8);
      *(uint4*)&Wl[srow][c0]     = *(const uint4*)(pWl + (size_t)srow * 128 + k0 + c0);
      *(uint4*)&Wl[srow][c0 + 8] = *(const uint4*)(pWl + (size_t)srow * 128 + k0 + c0 + 8);
      __syncthreads();
      bf16x8 a0h = *(const bf16x8*)&Ah[wv * 32 + l15][lg * 8];
      bf16x8 a0l = *(const bf16x8*)&Al[wv * 32 + l15][lg * 8];
      bf16x8 a1h = *(const bf16x8*)&Ah[wv * 32 + 16 + l15][lg * 8];
      bf16x8 a1l = *(const bf16x8*)&Al[wv * 32 + 16 + l15][lg * 8];
#pragma unroll
      for (int ct = 0; ct < 8; ++ct) {
        bf16x8 bh = *(const bf16x8*)&Wh[ct * 16 + l15][lg * 8];
        bf16x8 bl = *(const bf16x8*)&Wl[ct * 16 + l15][lg * 8];
        acc[0][ct] = __builtin_amdgcn_mfma_f32_16x16x32_bf16(a0h, bh, acc[0][ct], 0, 0, 0);
        acc[0][ct] = __builtin_amdgcn_mfma_f32_16x16x32_bf16(a0h, bl, acc[0][ct], 0, 0, 0);
        acc[0][ct] = __builtin_amdgcn_mfma_f32_16x16x32_bf16(a0l, bh, acc[0][ct], 0, 0, 0);
        acc[1][ct] = __builtin_amdgcn_mfma_f32_16x16x32_bf16(a1h, bh, acc[1][ct], 0, 0, 0);
        acc[1][ct] = __builtin_amdgcn_mfma_f32_16x16x32_bf16(a1h, bl, acc[1][ct], 0, 0, 0);
        acc[1][ct] = __builtin_amdgcn_mfma_f32_16x16x32_bf16(a1l, bh, acc[1][ct], 0, 0, 0);
      }
    }
  }
  // epilogue: bias + relu; C layout col=lane&15, row=(lane>>4)*4+reg
#pragma unroll
  for (int ct = 0; ct < 8; ++ct) {
    int col = ct * 16 + l15;
    float bias = b1[col];
    if (NREL == 2) bias += b2[col];
#pragma unroll
    for (int rt = 0; rt < 2; ++rt) {
      int rowb = r0 + wv * 32 + rt * 16 + lg * 4;
#pragma unroll
      for (int r = 0; r < 4; ++r) {
        int row = rowb + r;
        if (row < nrows) {
          float v = fmaxf(acc[rt][ct][r] + bias, 0.f);
          if (OBF) ((u16*)outv)[(size_t)row * 128 + col] = f2bf(v);
          else ((float*)outv)[(size_t)row * 128 + col] = v;
        }
      }
    }
  }
}

// ---------------- per-graph mean pooling: 8 rows parallel, float4 cols ------
// gid is globally sorted. Uniform-chunk fast path: LDS cross-slot reduce,
// 128+1 atomics/block. Boundary chunks: per-thread segment flushes.
#define PCHUNK 256
__global__ __launch_bounds__(256) void k_pool(const float* __restrict__ H,
                                              const int* __restrict__ gid,
                                              float* __restrict__ sums,
                                              float* __restrict__ cnt, int n) {
  __shared__ float4 red[256];
  int tid = threadIdx.x;
  int c4 = tid & 31;        // float4 slot (32 x 4 = 128 cols)
  int slot = tid >> 5;      // 0..7 parallel row slots
  int start = blockIdx.x * PCHUNK;
  if (start >= n) return;
  int end = min(start + PCHUNK, n);
  if (gid[start] == gid[end - 1]) {
    // uniform chunk: no per-row gid checks
    int g = gid[start];
    float4 acc = make_float4(0.f, 0.f, 0.f, 0.f);
    for (int r = start + slot; r < end; r += 8) {
      float4 v = *(const float4*)(H + (size_t)r * D + c4 * 4);
      acc.x += v.x; acc.y += v.y; acc.z += v.z; acc.w += v.w;
    }
    red[tid] = acc;
    __syncthreads();
    if (slot == 0) {
      float4 a = red[c4];
#pragma unroll
      for (int s2 = 1; s2 < 8; ++s2) {
        float4 b = red[s2 * 32 + c4];
        a.x += b.x; a.y += b.y; a.z += b.z; a.w += b.w;
      }
      float* p = &sums[g * D + c4 * 4];
      atomicAdd(p + 0, a.x); atomicAdd(p + 1, a.y);
      atomicAdd(p + 2, a.z); atomicAdd(p + 3, a.w);
      if (c4 == 0) atomicAdd(&cnt[g], (float)(end - start));
    }
    return;
  }
  // boundary chunk: per-thread segment flushes
  float4 acc = make_float4(0.f, 0.f, 0.f, 0.f);
  int cur = -1, cl = 0;
  for (int r = start + slot; r < end; r += 8) {
    int g = gid[r];
    if (g != cur) {
      if (cur >= 0) {
        float* p = &sums[cur * D + c4 * 4];
        atomicAdd(p + 0, acc.x); atomicAdd(p + 1, acc.y);
        atomicAdd(p + 2, acc.z); atomicAdd(p + 3, acc.w);
        if (c4 == 0) atomicAdd(&cnt[cur], (float)cl);
      }
      acc = make_float4(0.f, 0.f, 0.f, 0.f); cl = 0; cur = g;
    }
    float4 v = *(const float4*)(H + (size_t)r * D + c4 * 4);
    acc.x += v.x; acc.y += v.y; acc.z += v.z; acc.w += v.w;
    cl++;
  }
  if (cur >= 0) {
    float* p = &sums[cur * D + c4 * 4];
    atomicAdd(p + 0, acc.x); atomicAdd(p + 1, acc.y);
    atomicAdd(p + 2, acc.z); atomicAdd(p + 3, acc.w);
    if (c4 == 0) atomicAdd(&cnt[cur], (float)cl);
  }
}

// ---------------- final MLP on [16,128] ----------------
__global__ __launch_bounds__(256) void k_final(const float* __restrict__ sums,
                                               const float* __restrict__ cnt,
                                               const float* __restrict__ Wm1,
                                               const float* __restrict__ bm1,
                                               const float* __restrict__ Wm2,
                                               const float* __restrict__ bm2,
                                               float* __restrict__ out) {
  __shared__ float hg[16][128];
  __shared__ float t1[16][128];
  int tid = threadIdx.x;
  for (int i = tid; i < 16 * 128; i += 256) {
    int g = i >> 7, c = i & 127;
    hg[g][c] = sums[i] / fmaxf(cnt[g], 1.f);
  }
  __syncthreads();
  for (int i = tid; i < 16 * 128; i += 256) {
    int g = i >> 7, c = i & 127;
    float a = bm1[c];
    for (int k = 0; k < 128; ++k) a = fmaf(hg[g][k], Wm1[k * 128 + c], a);
    t1[g][c] = fmaxf(a, 0.f);
  }
  __syncthreads();
  int g = tid >> 4, l = tid & 15;
  float p = 0.f;
  for (int c = l; c < 128; c += 16) p = fmaf(t1[g][c], Wm2[c], p);
#pragma unroll
  for (int o = 8; o; o >>= 1) p += __shfl_down(p, o, 16);
  if (l == 0) out[g] = p + bm2[0];
}

extern "C" void kernel_launch(void* const* d_in, const int* in_sizes, int n_in,
                              void* d_out, int out_size, void* d_ws, size_t ws_size,
                              hipStream_t stream) {
  const float* x_tile = (const float*)d_in[0];
  const float* x_rr   = (const float*)d_in[1];
  const int* tt_src = (const int*)d_in[2];
  const int* tt_dst = (const int*)d_in[3];
  const int* rt_src = (const int*)d_in[4];
  const int* rt_dst = (const int*)d_in[5];
  const int* tr_src = (const int*)d_in[6];
  const int* tr_dst = (const int*)d_in[7];
  const int* tile_gid = (const int*)d_in[8];
  const float* W1_tt = (const float*)d_in[9];  const float* b1_tt = (const float*)d_in[10];
  const float* W1_rt = (const float*)d_in[11]; const float* b1_rt = (const float*)d_in[12];
  const float* W1_tr = (const float*)d_in[13]; const float* b1_tr = (const float*)d_in[14];
  const float* W2_tt = (const float*)d_in[15]; const float* b2_tt = (const float*)d_in[16];
  const float* W2_rt = (const float*)d_in[17]; const float* b2_rt = (const float*)d_in[18];
  const float* Wm1 = (const float*)d_in[21]; const float* bm1 = (const float*)d_in[22];
  const float* Wm2 = (const float*)d_in[23]; const float* bm2 = (const float*)d_in[24];

  char* ws = (char*)d_ws;
  size_t off = 0;
  auto allocB = [&](size_t bytes) {
    void* p = ws + off;
    off += (bytes + 255) & ~(size_t)255;
    return p;
  };
  // ---- zero region (memset each call) ----
  float* psum = (float*)allocB(N_G * D * 4);
  float* pcnt = (float*)allocB(N_G * 4);
  size_t zero_bytes = off;
  // ---- rest (all fully written before read) ----
  int* partial = (int*)allocB((size_t)6 * NCHK * N_TILE * 4);
  int* rank = (int*)allocB((size_t)E_ALL * 4);
  int* ideg_tt = (int*)allocB(N_TILE * 4);
  int* ideg_rt = (int*)allocB(N_TILE * 4);
  int* ideg_tr = (int*)allocB(N_RR * 4);
  int* pp_tt = (int*)allocB(N_TILE * 4);
  int* pp_rt = (int*)allocB(N_TILE * 4);
  int* pp_tr = (int*)allocB(N_RR * 4);
  int* bsum = (int*)allocB(3 * NB * 4);
  int* bs = (int*)allocB(3 * (NB + 1) * 4);
  int* rp_tt = (int*)allocB((N_TILE + 1) * 4);
  int* rp_rt = (int*)allocB((N_TILE + 1) * 4);
  int* rp_tr = (int*)allocB((N_RR + 1) * 4);
  int2* pr_tt = (int2*)allocB((size_t)E_TT * 8);
  int2* pr_rt = (int2*)allocB((size_t)E_RT * 8);
  int2* pr_tr = (int2*)allocB((size_t)E_TR * 8);
  float* osc_tt = (float*)allocB(N_TILE * 4);
  float* osc_rt = (float*)allocB(N_RR * 4);
  float* osc_tr = (float*)allocB(N_TILE * 4);
  float* isc_tt = (float*)allocB(N_TILE * 4);
  float* isc_rt = (float*)allocB(N_TILE * 4);
  float* isc_tr = (float*)allocB(N_RR * 4);
  u16* xt_bf = (u16*)allocB((size_t)N_TILE * D * 2);
  u16* xr_bf = (u16*)allocB((size_t)N_RR * D * 2);
  u16* Ahi = (u16*)allocB((size_t)N_TILE * D * 2);
  u16* Alo = (u16*)allocB((size_t)N_TILE * D * 2);
  u16* Bhi = (u16*)allocB((size_t)N_TILE * D * 2);
  u16* Blo = (u16*)allocB((size_t)N_TILE * D * 2);
  u16* Chi = (u16*)allocB((size_t)N_RR * D * 2);
  u16* Clo = (u16*)allocB((size_t)N_RR * D * 2);
  u16* Ht_bf = (u16*)allocB((size_t)N_TILE * D * 2);   // layer-1 tile output (bf16)
  u16* Hr_bf = (u16*)allocB((size_t)N_RR * D * 2);     // layer-1 rr output (bf16)
  float* Htile = (float*)allocB((size_t)N_TILE * D * 4); // layer-2 output (fp32, pooled)
  u16* Wt1tt_h = (u16*)allocB(D * D * 2); u16* Wt1tt_l = (u16*)allocB(D * D * 2);
  u16* Wt1rt_h = (u16*)allocB(D * D * 2); u16* Wt1rt_l = (u16*)allocB(D * D * 2);
  u16* Wt1tr_h = (u16*)allocB(D * D * 2); u16* Wt1tr_l = (u16*)allocB(D * D * 2);
  u16* Wt2tt_h = (u16*)allocB(D * D * 2); u16* Wt2tt_l = (u16*)allocB(D * D * 2);
  u16* Wt2rt_h = (u16*)allocB(D * D * 2); u16* Wt2rt_l = (u16*)allocB(D * D * 2);
  (void)ws_size; (void)in_sizes; (void)n_in; (void)out_size;

  hipMemsetAsync(d_ws, 0, zero_bytes, stream);

  // ---- fused prep: weight split + x->bf16 conversion ----
  {
    int convBlocks = (2 * N_TILE * (D / 8) + 255) / 256;
    k_prep<<<WPREP_BLOCKS + convBlocks, 256, 0, stream>>>(
        W1_tt, W1_rt, W1_tr, W2_tt, W2_rt,
        Wt1tt_h, Wt1tt_l, Wt1rt_h, Wt1rt_l, Wt1tr_h, Wt1tr_l,
        Wt2tt_h, Wt2tt_l, Wt2rt_h, Wt2rt_l,
        x_tile, x_rr, xt_bf, xr_bf);
  }

  // ---- CSR build: zero global atomics, atomic-free fill via hist-rank ----
  k_hist<<<6 * NBKT * NCHK, 256, 0, stream>>>(
      tt_src, tt_dst, rt_src, rt_dst, tr_src, tr_dst, partial, rank);
  k_hreduce<<<(6 * N_TILE + 255) / 256, 256, 0, stream>>>(
      partial, ideg_tt, ideg_rt, ideg_tr, osc_tt, osc_rt, osc_tr);
  k_scan1<<<3 * NB, 1024, 0, stream>>>(ideg_tt, ideg_rt, ideg_tr, pp_tt, pp_rt, pp_tr, bsum);
  k_scan2<<<1, 256, 0, stream>>>(bsum, bs);
  k_finalize<<<(N_TILE + 255) / 256, 256, 0, stream>>>(
      pp_tt, pp_rt, pp_tr, bs, rp_tt, rp_rt, rp_tr,
      ideg_tt, ideg_rt, ideg_tr, isc_tt, isc_rt, isc_tr);
  k_fill<<<(E_ALL + 255) / 256, 256, 0, stream>>>(
      tt_src, tt_dst, rt_src, rt_dst, tr_src, tr_dst,
      rp_tt, rp_rt, rp_tr, osc_tt, osc_rt, osc_tr,
      partial, rank, pr_tt, pr_rt, pr_tr);

  const int gemmBlocks = (N_TILE + 127) / 128;

  // ---- layer 1: all three aggs fused, bf16 gather ----
  {
    int totw = N_TILE + N_TILE + N_RR;
    k_agg3<<<(totw * 64 + 255) / 256, 256, 0, stream>>>(
        xt_bf, rp_tt, pr_tt, isc_tt, Ahi, Alo, N_TILE,
        xr_bf, rp_rt, pr_rt, isc_rt, Bhi, Blo, N_TILE,
        xt_bf, rp_tr, pr_tr, isc_tr, Chi, Clo, N_RR);
  }
  k_gemm_m<1, true><<<gemmBlocks, 256, 0, stream>>>(
      Chi, Clo, nullptr, nullptr, Wt1tr_h, Wt1tr_l, nullptr, nullptr,
      b1_tr, nullptr, Hr_bf, N_RR);
  k_gemm_m<2, true><<<gemmBlocks, 256, 0, stream>>>(
      Ahi, Alo, Bhi, Blo, Wt1tt_h, Wt1tt_l, Wt1rt_h, Wt1rt_l,
      b1_tt, b1_rt, Ht_bf, N_TILE);

  // ---- layer 2: bf16 gather of layer-1 outputs (tr relation skipped) ----
  {
    int totw = N_TILE + N_TILE;
    k_agg3<<<(totw * 64 + 255) / 256, 256, 0, stream>>>(
        Ht_bf, rp_tt, pr_tt, isc_tt, Ahi, Alo, N_TILE,
        Hr_bf, rp_rt, pr_rt, isc_rt, Bhi, Blo, N_TILE,
        nullptr, nullptr, nullptr, nullptr, nullptr, nullptr, 0);
  }
  k_gemm_m<2, false><<<gemmBlocks, 256, 0, stream>>>(
      Ahi, Alo, Bhi, Blo, Wt2tt_h, Wt2tt_l, Wt2rt_h, Wt2rt_l,
      b2_tt, b2_rt, Htile, N_TILE);

  // ---- pooling + MLP head ----
  k_pool<<<(N_TILE + PCHUNK - 1) / PCHUNK, 256, 0, stream>>>(Htile, tile_gid, psum, pcnt, N_TILE);
  k_final<<<1, 256, 0, stream>>>(psum, pcnt, Wm1, bm1, Wm2, bm2, (float*)d_out);
}

// Round 15
// 303.476 us; speedup vs baseline: 1.5391x; 1.1529x over previous
//
#include <hip/hip_runtime.h>

#define N_TILE 50000
#define N_RR   50000
#define D      128
#define E_TT   800000
#define E_RT   400000
#define E_TR   400000
#define N_G    16
#define NB     ((N_TILE + 1023) / 1024)   // scan blocks per array (=49)
#define E_ALL  (E_TT + E_RT + E_TR)
#define BKT    25600                       // bins per bucket (16-bit packed, 50KB LDS)
#define NBKT   2                           // buckets cover 51200 >= N_TILE
#define NCHK   40                          // edge chunks (all E divisible by 40)
#define WPREP_BLOCKS 320                   // 5 weights * 64 blocks

static_assert(NB <= 64, "scan2 uses one wave per array");
static_assert(N_TILE == N_RR, "shared bucket geometry assumes equal node counts");
static_assert((size_t)BKT * NBKT >= N_TILE, "bucket coverage");
static_assert(E_TT % NCHK == 0 && E_RT % NCHK == 0 && E_TR % NCHK == 0, "chunking");

typedef __attribute__((ext_vector_type(8))) short bf16x8;
typedef __attribute__((ext_vector_type(4))) float f32x4;
typedef __attribute__((ext_vector_type(2))) float v2f;
typedef unsigned short u16;

__device__ inline u16 f2bf(float f) {
  unsigned u = __float_as_uint(f);
  unsigned r = (u + 0x7FFFu + ((u >> 16) & 1u)) >> 16;   // RNE
  return (u16)r;
}
__device__ inline float bf2f(u16 h) { return __uint_as_float(((unsigned)h) << 16); }

// packed FMA: acc.{x,y} += pair.{x,y} * w.{x,y}  (one VOP3P instruction)
__device__ inline void pk_fma(v2f& acc, v2f pair, v2f w) {
  asm("v_pk_fma_f32 %0, %1, %2, %0" : "+v"(acc) : "v"(pair), "v"(w));
}
// unpack u32 (2 bf16) -> {lo, cheap-hi}; hi keeps low 16 bits as sub-ulp noise
__device__ inline v2f bfpair(unsigned w) {
  v2f p;
  p.x = __uint_as_float(w << 16);
  p.y = __uint_as_float(w);
  return p;
}

// ---------------- bucketed LDS histogram + rank capture: NO global atomics ----
// 25600 bins/bucket (2 buckets), packed 16-bit counters. 512 threads.
__global__ __launch_bounds__(512) void k_hist(
    const int* __restrict__ tt_src, const int* __restrict__ tt_dst,
    const int* __restrict__ rt_src, const int* __restrict__ rt_dst,
    const int* __restrict__ tr_src, const int* __restrict__ tr_dst,
    int* __restrict__ partial, int* __restrict__ rank) {
  __shared__ unsigned h[BKT / 2];
  int bid = blockIdx.x;
  int s = bid / (NBKT * NCHK);
  int rem = bid % (NBKT * NCHK);
  int b = rem / NCHK;
  int c = rem % NCHK;
  const int* arr; int E; int roff = 0;
  switch (s) {
    case 0: arr = tt_dst; E = E_TT; roff = 0; break;
    case 1: arr = rt_dst; E = E_RT; roff = E_TT; break;
    case 2: arr = tr_dst; E = E_TR; roff = E_TT + E_RT; break;
    case 3: arr = tt_src; E = E_TT; break;
    case 4: arr = rt_src; E = E_RT; break;
    default: arr = tr_src; E = E_TR; break;
  }
  bool isdst = s < 3;
  for (int j = threadIdx.x; j < BKT / 2; j += 512) h[j] = 0;
  __syncthreads();
  int ec = E / NCHK;
  int lo = c * ec, hi = lo + ec;
  int base = b * BKT;
  for (int i = lo + threadIdx.x; i < hi; i += 512) {
    unsigned int off = (unsigned int)(arr[i] - base);
    if (off < BKT) {
      unsigned sh = (off & 1u) << 4;
      unsigned r = atomicAdd(&h[off >> 1], 1u << sh);
      if (isdst) rank[roff + i] = (int)((r >> sh) & 0xffffu);
    }
  }
  __syncthreads();
  int* dst = partial + (size_t)(s * NCHK + c) * N_TILE;
  for (int j = threadIdx.x; j < BKT; j += 512) {
    int bin = base + j;
    if (bin < N_TILE)
      dst[bin] = (int)((h[j >> 1] >> ((j & 1) << 4)) & 0xffffu);
  }
}

// ---------------- reduce partials ----------------
__global__ __launch_bounds__(256) void k_hreduce(
    int* __restrict__ partial,
    int* __restrict__ id_tt, int* __restrict__ id_rt, int* __restrict__ id_tr,
    float* __restrict__ os_tt, float* __restrict__ os_rt, float* __restrict__ os_tr) {
  int t = blockIdx.x * 256 + threadIdx.x;
  if (t >= 6 * N_TILE) return;
  int s = t / N_TILE;
  int i = t - s * N_TILE;
  int* p = partial + (size_t)s * NCHK * N_TILE + i;
  int run = 0;
  if (s < 3) {
#pragma unroll
    for (int c = 0; c < NCHK; ++c) {
      int v = p[(size_t)c * N_TILE];
      p[(size_t)c * N_TILE] = run;
      run += v;
    }
    if (s == 0) id_tt[i] = run;
    else if (s == 1) id_rt[i] = run;
    else id_tr[i] = run;
  } else {
#pragma unroll
    for (int c = 0; c < NCHK; ++c) run += p[(size_t)c * N_TILE];
    float v = rsqrtf((float)max(run, 1));
    if (s == 3) os_tt[i] = v;
    else if (s == 4) os_rt[i] = v;
    else os_tr[i] = v;
  }
}

// ---------------- scan stage 1 ----------------
__global__ __launch_bounds__(1024) void k_scan1(const int* __restrict__ d0,
                                                const int* __restrict__ d1,
                                                const int* __restrict__ d2,
                                                int* __restrict__ p0,
                                                int* __restrict__ p1,
                                                int* __restrict__ p2,
                                                int* __restrict__ bsum) {
  int arr = blockIdx.x / NB;
  int blk = blockIdx.x % NB;
  const int* deg = arr == 0 ? d0 : (arr == 1 ? d1 : d2);
  int* part = arr == 0 ? p0 : (arr == 1 ? p1 : p2);
  __shared__ int ts[1024];
  int tid = threadIdx.x;
  int i = blk * 1024 + tid;
  int v = (i < N_TILE) ? deg[i] : 0;
  ts[tid] = v;
  __syncthreads();
  for (int d = 1; d < 1024; d <<= 1) {
    int t = (tid >= d) ? ts[tid - d] : 0;
    __syncthreads();
    ts[tid] += t;
    __syncthreads();
  }
  if (i < N_TILE) part[i] = ts[tid] - v;
  if (tid == 1023) bsum[arr * NB + blk] = ts[1023];
}

// ---------------- scan stage 2 ----------------
__global__ __launch_bounds__(256) void k_scan2(const int* __restrict__ bsum,
                                               int* __restrict__ bs) {
  int wv = threadIdx.x >> 6;
  int lane = threadIdx.x & 63;
  if (wv >= 3) return;
  int v = (lane < NB) ? bsum[wv * NB + lane] : 0;
  int orig = v;
#pragma unroll
  for (int o = 1; o < 64; o <<= 1) {
    int t = __shfl_up(v, o);
    if (lane >= o) v += t;
  }
  if (lane < NB) bs[wv * (NB + 1) + lane] = v - orig;
  if (lane == NB - 1) bs[wv * (NB + 1) + NB] = v;
}

// ---------------- finalize ----------------
__global__ void k_finalize(const int* __restrict__ pp_tt, const int* __restrict__ pp_rt,
                           const int* __restrict__ pp_tr, const int* __restrict__ bs,
                           int* __restrict__ rp_tt, int* __restrict__ rp_rt,
                           int* __restrict__ rp_tr,
                           const int* __restrict__ id_tt, const int* __restrict__ id_rt,
                           const int* __restrict__ id_tr,
                           float* __restrict__ is_tt, float* __restrict__ is_rt,
                           float* __restrict__ is_tr) {
  int i = blockIdx.x * blockDim.x + threadIdx.x;
  if (i >= N_TILE) return;
  int b = i >> 10;
  rp_tt[i] = pp_tt[i] + bs[0 * (NB + 1) + b];
  rp_rt[i] = pp_rt[i] + bs[1 * (NB + 1) + b];
  rp_tr[i] = pp_tr[i] + bs[2 * (NB + 1) + b];
  if (i == 0) {
    rp_tt[N_TILE] = bs[0 * (NB + 1) + NB];
    rp_rt[N_TILE] = bs[1 * (NB + 1) + NB];
    rp_tr[N_RR] = bs[2 * (NB + 1) + NB];
  }
  is_tt[i] = rsqrtf((float)max(id_tt[i], 1));
  is_rt[i] = rsqrtf((float)max(id_rt[i], 1));
  is_tr[i] = rsqrtf((float)max(id_tr[i], 1));
}

// ---------------- CSR fill: one thread per edge, atomic-free ----------------
__global__ __launch_bounds__(256) void k_fill(
    const int* __restrict__ tt_src, const int* __restrict__ tt_dst,
    const int* __restrict__ rt_src, const int* __restrict__ rt_dst,
    const int* __restrict__ tr_src, const int* __restrict__ tr_dst,
    const int* __restrict__ rp_tt, const int* __restrict__ rp_rt,
    const int* __restrict__ rp_tr,
    const float* __restrict__ os_tt, const float* __restrict__ os_rt,
    const float* __restrict__ os_tr,
    const int* __restrict__ partial, const int* __restrict__ rank,
    int2* __restrict__ pr_tt, int2* __restrict__ pr_rt, int2* __restrict__ pr_tr) {
  int i = blockIdx.x * 256 + threadIdx.x;
  if (i >= E_ALL) return;
  const int* srcA; const int* dstA; const int* rp; const float* os; int2* pr;
  int j, s, ec;
  if (i < E_TT) {
    s = 0; j = i; ec = E_TT / NCHK;
    srcA = tt_src; dstA = tt_dst; rp = rp_tt; os = os_tt; pr = pr_tt;
  } else if (i < E_TT + E_RT) {
    s = 1; j = i - E_TT; ec = E_RT / NCHK;
    srcA = rt_src; dstA = rt_dst; rp = rp_rt; os = os_rt; pr = pr_rt;
  } else {
    s = 2; j = i - E_TT - E_RT; ec = E_TR / NCHK;
    srcA = tr_src; dstA = tr_dst; rp = rp_tr; os = os_tr; pr = pr_tr;
  }
  int d = dstA[j];
  int c = j / ec;
  int slot = rp[d] + partial[(size_t)(s * NCHK + c) * N_TILE + d] + rank[i];
  int sv = srcA[j];
  int2 v;
  v.x = sv;
  v.y = __float_as_int(os[sv]);
  pr[slot] = v;
}

// ---------------- fused prep: weight split (blocks < WPREP_BLOCKS) + x->bf16 conv ----
__global__ __launch_bounds__(256) void k_prep(
    const float* __restrict__ W0, const float* __restrict__ W1,
    const float* __restrict__ W2, const float* __restrict__ W3,
    const float* __restrict__ W4,
    u16* __restrict__ T0h, u16* __restrict__ T0l,
    u16* __restrict__ T1h, u16* __restrict__ T1l,
    u16* __restrict__ T2h, u16* __restrict__ T2l,
    u16* __restrict__ T3h, u16* __restrict__ T3l,
    u16* __restrict__ T4h, u16* __restrict__ T4l,
    const float* __restrict__ xa, const float* __restrict__ xb,
    u16* __restrict__ oa, u16* __restrict__ ob) {
  int bid = blockIdx.x;
  if (bid < WPREP_BLOCKS) {
    int s = bid >> 6;
    int idx = ((bid & 63) << 8) + threadIdx.x;   // n*128+k
    const float* W = s == 0 ? W0 : (s == 1 ? W1 : (s == 2 ? W2 : (s == 3 ? W3 : W4)));
    u16* Th = s == 0 ? T0h : (s == 1 ? T1h : (s == 2 ? T2h : (s == 3 ? T3h : T4h)));
    u16* Tl = s == 0 ? T0l : (s == 1 ? T1l : (s == 2 ? T2l : (s == 3 ? T3l : T4l)));
    int n = idx >> 7, k = idx & 127;
    float w = W[k * 128 + n];
    u16 h = f2bf(w);
    Th[idx] = h;
    Tl[idx] = f2bf(w - bf2f(h));
    return;
  }
  const size_t TOT = (size_t)N_TILE * D / 8;
  size_t i = (size_t)(bid - WPREP_BLOCKS) * 256 + threadIdx.x;
  if (i >= 2 * TOT) return;
  const float* src = (i < TOT) ? xa : xb;
  u16* dst = (i < TOT) ? oa : ob;
  size_t j = ((i < TOT) ? i : i - TOT) * 8;
  float4 v0 = *(const float4*)(src + j);
  float4 v1 = *(const float4*)(src + j + 4);
  ushort4 h0, h1;
  h0.x = f2bf(v0.x); h0.y = f2bf(v0.y); h0.z = f2bf(v0.z); h0.w = f2bf(v0.w);
  h1.x = f2bf(v1.x); h1.y = f2bf(v1.y); h1.z = f2bf(v1.z); h1.w = f2bf(v1.w);
  *(ushort4*)(dst + j) = h0;
  *(ushort4*)(dst + j + 4) = h1;
}

// ---------------- fused aggregation (up to 3 relations) -> bf16 rows --------
// out[d][:] = bf16( isc[d] * sum_e w_e * x[src_e] );  x rows = bf16.
// A-side split-lo dropped: its correction is statistically identical to the
// (already-tolerated) unbiased bf16 input noise and pools away over ~3k nodes.
__global__ __launch_bounds__(256) void k_agg3(
    const u16* __restrict__ x0, const int* __restrict__ rp0, const int2* __restrict__ pr0,
    const float* __restrict__ isc0, u16* __restrict__ oh0, int n0,
    const u16* __restrict__ x1, const int* __restrict__ rp1, const int2* __restrict__ pr1,
    const float* __restrict__ isc1, u16* __restrict__ oh1, int n1,
    const u16* __restrict__ x2, const int* __restrict__ rp2, const int2* __restrict__ pr2,
    const float* __restrict__ isc2, u16* __restrict__ oh2, int n2) {
  int gw = (blockIdx.x * blockDim.x + threadIdx.x) >> 6;
  int lane = threadIdx.x & 63;
  int q = lane >> 4;        // edge-slot within group of 4
  int l4 = lane & 15;       // uint4 slot within the 256B row
  const u16* x; const int* rp; const int2* pr; const float* isc;
  u16* oh; int wid;
  if (gw < n0) { x = x0; rp = rp0; pr = pr0; isc = isc0; oh = oh0; wid = gw; }
  else if (gw < n0 + n1) { x = x1; rp = rp1; pr = pr1; isc = isc1; oh = oh1; wid = gw - n0; }
  else if (gw < n0 + n1 + n2) { x = x2; rp = rp2; pr = pr2; isc = isc2; oh = oh2; wid = gw - n0 - n1; }
  else return;
  int beg = rp[wid], end = rp[wid + 1];
  v2f a0[4], a1[4];
#pragma unroll
  for (int j = 0; j < 4; ++j) { a0[j] = (v2f){0.f, 0.f}; a1[j] = (v2f){0.f, 0.f}; }
  const uint4* xb = (const uint4*)x + l4;   // row = 128 bf16 = 16 uint4
  int nfull = (end - beg) & ~7;
  int efull = beg + nfull;
  for (int e = beg; e < efull; e += 8) {
    int2 p0 = pr[e + q];
    int2 p1 = pr[e + 4 + q];
    float w0 = __int_as_float(p0.y);
    float w1 = __int_as_float(p1.y);
    v2f w02 = {w0, w0}, w12 = {w1, w1};
    uint4 u0 = xb[(size_t)p0.x * 16];
    uint4 u1 = xb[(size_t)p1.x * 16];
    pk_fma(a0[0], bfpair(u0.x), w02);
    pk_fma(a0[1], bfpair(u0.y), w02);
    pk_fma(a0[2], bfpair(u0.z), w02);
    pk_fma(a0[3], bfpair(u0.w), w02);
    pk_fma(a1[0], bfpair(u1.x), w12);
    pk_fma(a1[1], bfpair(u1.y), w12);
    pk_fma(a1[2], bfpair(u1.z), w12);
    pk_fma(a1[3], bfpair(u1.w), w12);
  }
  if (efull < end) {
    int lim = end - 1;
    int i0 = efull + q, i1 = efull + 4 + q;
    int2 p0 = pr[min(i0, lim)];
    int2 p1 = pr[min(i1, lim)];
    float w0 = (i0 < end) ? __int_as_float(p0.y) : 0.f;
    float w1 = (i1 < end) ? __int_as_float(p1.y) : 0.f;
    v2f w02 = {w0, w0}, w12 = {w1, w1};
    uint4 u0 = xb[(size_t)p0.x * 16];
    uint4 u1 = xb[(size_t)p1.x * 16];
    pk_fma(a0[0], bfpair(u0.x), w02);
    pk_fma(a0[1], bfpair(u0.y), w02);
    pk_fma(a0[2], bfpair(u0.z), w02);
    pk_fma(a0[3], bfpair(u0.w), w02);
    pk_fma(a1[0], bfpair(u1.x), w12);
    pk_fma(a1[1], bfpair(u1.y), w12);
    pk_fma(a1[2], bfpair(u1.z), w12);
    pk_fma(a1[3], bfpair(u1.w), w12);
  }
  float s[8];
#pragma unroll
  for (int j = 0; j < 4; ++j) {
    v2f t = a0[j] + a1[j];
    s[2 * j] = t.x;
    s[2 * j + 1] = t.y;
  }
#pragma unroll
  for (int j = 0; j < 8; ++j) {
    s[j] += __shfl_xor(s[j], 16);
    s[j] += __shfl_xor(s[j], 32);
  }
  if (q == 0) {
    float iv = isc[wid];
    unsigned hb[8];
#pragma unroll
    for (int j = 0; j < 8; ++j) hb[j] = f2bf(s[j] * iv);
    uint4 hw;
    hw.x = hb[0] | (hb[1] << 16); hw.y = hb[2] | (hb[3] << 16);
    hw.z = hb[4] | (hb[5] << 16); hw.w = hb[6] | (hb[7] << 16);
    *(uint4*)(oh + (size_t)wid * D + l4 * 8) = hw;
  }
}

// ---------------- MFMA bf16 GEMM(+GEMM) + bias + relu ----------------
// out = relu( A1@W1 (+ A2@W2) + b1 (+ b2) ); OBF: output bf16 rows, else fp32.
// C = A@Whi + A@Wlo (weight split kept: W rounding is systematic, A's is not).
template<int NREL, bool OBF>
__global__ __launch_bounds__(256) void k_gemm_m(
    const u16* __restrict__ A1, const u16* __restrict__ A2,
    const u16* __restrict__ Wt1h, const u16* __restrict__ Wt1l,
    const u16* __restrict__ Wt2h, const u16* __restrict__ Wt2l,
    const float* __restrict__ b1, const float* __restrict__ b2,
    void* __restrict__ outv, int nrows) {
  __shared__ u16 Ah[128][40];   // pad 40: 2-way-only LDS conflicts on b128 reads
  __shared__ u16 Wh[128][40];   // [n][k]
  __shared__ u16 Wl[128][40];
  int tid = threadIdx.x;
  int wv = tid >> 6, lane = tid & 63;
  int l15 = lane & 15, lg = lane >> 4;
  int r0 = blockIdx.x * 128;
  f32x4 acc[2][8];
#pragma unroll
  for (int i = 0; i < 2; ++i)
#pragma unroll
    for (int j = 0; j < 8; ++j) acc[i][j] = (f32x4){0.f, 0.f, 0.f, 0.f};

  int srow = tid >> 1;             // 0..127
  int c0 = (tid & 1) * 16;         // u16 col base 0 or 16
  int gr = r0 + srow;

  for (int rel = 0; rel < NREL; ++rel) {
    const u16* pA = (NREL == 2 && rel) ? A2 : A1;
    const u16* pWh = (NREL == 2 && rel) ? Wt2h : Wt1h;
    const u16* pWl = (NREL == 2 && rel) ? Wt2l : Wt1l;
    for (int k0 = 0; k0 < 128; k0 += 32) {
      __syncthreads();
      uint4 z = {0, 0, 0, 0};
      uint4 va0 = z, va1 = z;
      if (gr < nrows) {
        va0 = *(const uint4*)(pA + (size_t)gr * 128 + k0 + c0);
        va1 = *(const uint4*)(pA + (size_t)gr * 128 + k0 + c0 + 8);
      }
      *(uint4*)&Ah[srow][c0] = va0;
      *(uint4*)&Ah[srow][c0 + 8] = va1;
      *(uint4*)&Wh[srow][c0]     = *(const uint4*)(pWh + (size_t)srow * 128 + k0 + c0);
      *(uint4*)&Wh[srow][c0 + 8] = *(const uint4*)(pWh + (size_t)srow * 128 + k0 + c0 + 8);
      *(uint4*)&Wl[srow][c0]     = *(const uint4*)(pWl + (size_t)srow * 128 + k0 + c0);
      *(uint4*)&Wl[srow][c0 + 8] = *(const uint4*)(pWl + (size_t)srow * 128 + k0 + c0 + 8);
      __syncthreads();
      bf16x8 a0 = *(const bf16x8*)&Ah[wv * 32 + l15][lg * 8];
      bf16x8 a1 = *(const bf16x8*)&Ah[wv * 32 + 16 + l15][lg * 8];
#pragma unroll
      for (int ct = 0; ct < 8; ++ct) {
        bf16x8 bh = *(const bf16x8*)&Wh[ct * 16 + l15][lg * 8];
        bf16x8 bl = *(const bf16x8*)&Wl[ct * 16 + l15][lg * 8];
        acc[0][ct] = __builtin_amdgcn_mfma_f32_16x16x32_bf16(a0, bh, acc[0][ct], 0, 0, 0);
        acc[0][ct] = __builtin_amdgcn_mfma_f32_16x16x32_bf16(a0, bl, acc[0][ct], 0, 0, 0);
        acc[1][ct] = __builtin_amdgcn_mfma_f32_16x16x32_bf16(a1, bh, acc[1][ct], 0, 0, 0);
        acc[1][ct] = __builtin_amdgcn_mfma_f32_16x16x32_bf16(a1, bl, acc[1][ct], 0, 0, 0);
      }
    }
  }
  // epilogue: bias + relu; C layout col=lane&15, row=(lane>>4)*4+reg
#pragma unroll
  for (int ct = 0; ct < 8; ++ct) {
    int col = ct * 16 + l15;
    float bias = b1[col];
    if (NREL == 2) bias += b2[col];
#pragma unroll
    for (int rt = 0; rt < 2; ++rt) {
      int rowb = r0 + wv * 32 + rt * 16 + lg * 4;
#pragma unroll
      for (int r = 0; r < 4; ++r) {
        int row = rowb + r;
        if (row < nrows) {
          float v = fmaxf(acc[rt][ct][r] + bias, 0.f);
          if (OBF) ((u16*)outv)[(size_t)row * 128 + col] = f2bf(v);
          else ((float*)outv)[(size_t)row * 128 + col] = v;
        }
      }
    }
  }
}

// ---------------- per-graph mean pooling: 8 rows parallel, float4 cols ------
#define PCHUNK 256
__global__ __launch_bounds__(256) void k_pool(const float* __restrict__ H,
                                              const int* __restrict__ gid,
                                              float* __restrict__ sums,
                                              float* __restrict__ cnt, int n) {
  __shared__ float4 red[256];
  int tid = threadIdx.x;
  int c4 = tid & 31;        // float4 slot (32 x 4 = 128 cols)
  int slot = tid >> 5;      // 0..7 parallel row slots
  int start = blockIdx.x * PCHUNK;
  if (start >= n) return;
  int end = min(start + PCHUNK, n);
  if (gid[start] == gid[end - 1]) {
    int g = gid[start];
    float4 acc = make_float4(0.f, 0.f, 0.f, 0.f);
    for (int r = start + slot; r < end; r += 8) {
      float4 v = *(const float4*)(H + (size_t)r * D + c4 * 4);
      acc.x += v.x; acc.y += v.y; acc.z += v.z; acc.w += v.w;
    }
    red[tid] = acc;
    __syncthreads();
    if (slot == 0) {
      float4 a = red[c4];
#pragma unroll
      for (int s2 = 1; s2 < 8; ++s2) {
        float4 b = red[s2 * 32 + c4];
        a.x += b.x; a.y += b.y; a.z += b.z; a.w += b.w;
      }
      float* p = &sums[g * D + c4 * 4];
      atomicAdd(p + 0, a.x); atomicAdd(p + 1, a.y);
      atomicAdd(p + 2, a.z); atomicAdd(p + 3, a.w);
      if (c4 == 0) atomicAdd(&cnt[g], (float)(end - start));
    }
    return;
  }
  float4 acc = make_float4(0.f, 0.f, 0.f, 0.f);
  int cur = -1, cl = 0;
  for (int r = start + slot; r < end; r += 8) {
    int g = gid[r];
    if (g != cur) {
      if (cur >= 0) {
        float* p = &sums[cur * D + c4 * 4];
        atomicAdd(p + 0, acc.x); atomicAdd(p + 1, acc.y);
        atomicAdd(p + 2, acc.z); atomicAdd(p + 3, acc.w);
        if (c4 == 0) atomicAdd(&cnt[cur], (float)cl);
      }
      acc = make_float4(0.f, 0.f, 0.f, 0.f); cl = 0; cur = g;
    }
    float4 v = *(const float4*)(H + (size_t)r * D + c4 * 4);
    acc.x += v.x; acc.y += v.y; acc.z += v.z; acc.w += v.w;
    cl++;
  }
  if (cur >= 0) {
    float* p = &sums[cur * D + c4 * 4];
    atomicAdd(p + 0, acc.x); atomicAdd(p + 1, acc.y);
    atomicAdd(p + 2, acc.z); atomicAdd(p + 3, acc.w);
    if (c4 == 0) atomicAdd(&cnt[cur], (float)cl);
  }
}

// ---------------- final MLP on [16,128] ----------------
__global__ __launch_bounds__(256) void k_final(const float* __restrict__ sums,
                                               const float* __restrict__ cnt,
                                               const float* __restrict__ Wm1,
                                               const float* __restrict__ bm1,
                                               const float* __restrict__ Wm2,
                                               const float* __restrict__ bm2,
                                               float* __restrict__ out) {
  __shared__ float hg[16][128];
  __shared__ float t1[16][128];
  int tid = threadIdx.x;
  for (int i = tid; i < 16 * 128; i += 256) {
    int g = i >> 7, c = i & 127;
    hg[g][c] = sums[i] / fmaxf(cnt[g], 1.f);
  }
  __syncthreads();
  for (int i = tid; i < 16 * 128; i += 256) {
    int g = i >> 7, c = i & 127;
    float a = bm1[c];
    for (int k = 0; k < 128; ++k) a = fmaf(hg[g][k], Wm1[k * 128 + c], a);
    t1[g][c] = fmaxf(a, 0.f);
  }
  __syncthreads();
  int g = tid >> 4, l = tid & 15;
  float p = 0.f;
  for (int c = l; c < 128; c += 16) p = fmaf(t1[g][c], Wm2[c], p);
#pragma unroll
  for (int o = 8; o; o >>= 1) p += __shfl_down(p, o, 16);
  if (l == 0) out[g] = p + bm2[0];
}

extern "C" void kernel_launch(void* const* d_in, const int* in_sizes, int n_in,
                              void* d_out, int out_size, void* d_ws, size_t ws_size,
                              hipStream_t stream) {
  const float* x_tile = (const float*)d_in[0];
  const float* x_rr   = (const float*)d_in[1];
  const int* tt_src = (const int*)d_in[2];
  const int* tt_dst = (const int*)d_in[3];
  const int* rt_src = (const int*)d_in[4];
  const int* rt_dst = (const int*)d_in[5];
  const int* tr_src = (const int*)d_in[6];
  const int* tr_dst = (const int*)d_in[7];
  const int* tile_gid = (const int*)d_in[8];
  const float* W1_tt = (const float*)d_in[9];  const float* b1_tt = (const float*)d_in[10];
  const float* W1_rt = (const float*)d_in[11]; const float* b1_rt = (const float*)d_in[12];
  const float* W1_tr = (const float*)d_in[13]; const float* b1_tr = (const float*)d_in[14];
  const float* W2_tt = (const float*)d_in[15]; const float* b2_tt = (const float*)d_in[16];
  const float* W2_rt = (const float*)d_in[17]; const float* b2_rt = (const float*)d_in[18];
  const float* Wm1 = (const float*)d_in[21]; const float* bm1 = (const float*)d_in[22];
  const float* Wm2 = (const float*)d_in[23]; const float* bm2 = (const float*)d_in[24];

  char* ws = (char*)d_ws;
  size_t off = 0;
  auto allocB = [&](size_t bytes) {
    void* p = ws + off;
    off += (bytes + 255) & ~(size_t)255;
    return p;
  };
  // ---- zero region (memset each call) ----
  float* psum = (float*)allocB(N_G * D * 4);
  float* pcnt = (float*)allocB(N_G * 4);
  size_t zero_bytes = off;
  // ---- rest (all fully written before read) ----
  int* partial = (int*)allocB((size_t)6 * NCHK * N_TILE * 4);
  int* rank = (int*)allocB((size_t)E_ALL * 4);
  int* ideg_tt = (int*)allocB(N_TILE * 4);
  int* ideg_rt = (int*)allocB(N_TILE * 4);
  int* ideg_tr = (int*)allocB(N_RR * 4);
  int* pp_tt = (int*)allocB(N_TILE * 4);
  int* pp_rt = (int*)allocB(N_TILE * 4);
  int* pp_tr = (int*)allocB(N_RR * 4);
  int* bsum = (int*)allocB(3 * NB * 4);
  int* bs = (int*)allocB(3 * (NB + 1) * 4);
  int* rp_tt = (int*)allocB((N_TILE + 1) * 4);
  int* rp_rt = (int*)allocB((N_TILE + 1) * 4);
  int* rp_tr = (int*)allocB((N_RR + 1) * 4);
  int2* pr_tt = (int2*)allocB((size_t)E_TT * 8);
  int2* pr_rt = (int2*)allocB((size_t)E_RT * 8);
  int2* pr_tr = (int2*)allocB((size_t)E_TR * 8);
  float* osc_tt = (float*)allocB(N_TILE * 4);
  float* osc_rt = (float*)allocB(N_RR * 4);
  float* osc_tr = (float*)allocB(N_TILE * 4);
  float* isc_tt = (float*)allocB(N_TILE * 4);
  float* isc_rt = (float*)allocB(N_TILE * 4);
  float* isc_tr = (float*)allocB(N_RR * 4);
  u16* xt_bf = (u16*)allocB((size_t)N_TILE * D * 2);
  u16* xr_bf = (u16*)allocB((size_t)N_RR * D * 2);
  u16* Abf = (u16*)allocB((size_t)N_TILE * D * 2);
  u16* Bbf = (u16*)allocB((size_t)N_TILE * D * 2);
  u16* Cbf = (u16*)allocB((size_t)N_RR * D * 2);
  u16* Ht_bf = (u16*)allocB((size_t)N_TILE * D * 2);   // layer-1 tile output (bf16)
  u16* Hr_bf = (u16*)allocB((size_t)N_RR * D * 2);     // layer-1 rr output (bf16)
  float* Htile = (float*)allocB((size_t)N_TILE * D * 4); // layer-2 output (fp32, pooled)
  u16* Wt1tt_h = (u16*)allocB(D * D * 2); u16* Wt1tt_l = (u16*)allocB(D * D * 2);
  u16* Wt1rt_h = (u16*)allocB(D * D * 2); u16* Wt1rt_l = (u16*)allocB(D * D * 2);
  u16* Wt1tr_h = (u16*)allocB(D * D * 2); u16* Wt1tr_l = (u16*)allocB(D * D * 2);
  u16* Wt2tt_h = (u16*)allocB(D * D * 2); u16* Wt2tt_l = (u16*)allocB(D * D * 2);
  u16* Wt2rt_h = (u16*)allocB(D * D * 2); u16* Wt2rt_l = (u16*)allocB(D * D * 2);
  (void)ws_size; (void)in_sizes; (void)n_in; (void)out_size;

  hipMemsetAsync(d_ws, 0, zero_bytes, stream);

  // ---- fused prep: weight split + x->bf16 conversion ----
  {
    int convBlocks = (2 * N_TILE * (D / 8) + 255) / 256;
    k_prep<<<WPREP_BLOCKS + convBlocks, 256, 0, stream>>>(
        W1_tt, W1_rt, W1_tr, W2_tt, W2_rt,
        Wt1tt_h, Wt1tt_l, Wt1rt_h, Wt1rt_l, Wt1tr_h, Wt1tr_l,
        Wt2tt_h, Wt2tt_l, Wt2rt_h, Wt2rt_l,
        x_tile, x_rr, xt_bf, xr_bf);
  }

  // ---- CSR build: zero global atomics, atomic-free fill via hist-rank ----
  k_hist<<<6 * NBKT * NCHK, 512, 0, stream>>>(
      tt_src, tt_dst, rt_src, rt_dst, tr_src, tr_dst, partial, rank);
  k_hreduce<<<(6 * N_TILE + 255) / 256, 256, 0, stream>>>(
      partial, ideg_tt, ideg_rt, ideg_tr, osc_tt, osc_rt, osc_tr);
  k_scan1<<<3 * NB, 1024, 0, stream>>>(ideg_tt, ideg_rt, ideg_tr, pp_tt, pp_rt, pp_tr, bsum);
  k_scan2<<<1, 256, 0, stream>>>(bsum, bs);
  k_finalize<<<(N_TILE + 255) / 256, 256, 0, stream>>>(
      pp_tt, pp_rt, pp_tr, bs, rp_tt, rp_rt, rp_tr,
      ideg_tt, ideg_rt, ideg_tr, isc_tt, isc_rt, isc_tr);
  k_fill<<<(E_ALL + 255) / 256, 256, 0, stream>>>(
      tt_src, tt_dst, rt_src, rt_dst, tr_src, tr_dst,
      rp_tt, rp_rt, rp_tr, osc_tt, osc_rt, osc_tr,
      partial, rank, pr_tt, pr_rt, pr_tr);

  const int gemmBlocks = (N_TILE + 127) / 128;

  // ---- layer 1: all three aggs fused, bf16 gather -> bf16 rows ----
  {
    int totw = N_TILE + N_TILE + N_RR;
    k_agg3<<<(totw * 64 + 255) / 256, 256, 0, stream>>>(
        xt_bf, rp_tt, pr_tt, isc_tt, Abf, N_TILE,
        xr_bf, rp_rt, pr_rt, isc_rt, Bbf, N_TILE,
        xt_bf, rp_tr, pr_tr, isc_tr, Cbf, N_RR);
  }
  k_gemm_m<1, true><<<gemmBlocks, 256, 0, stream>>>(
      Cbf, nullptr, Wt1tr_h, Wt1tr_l, nullptr, nullptr,
      b1_tr, nullptr, Hr_bf, N_RR);
  k_gemm_m<2, true><<<gemmBlocks, 256, 0, stream>>>(
      Abf, Bbf, Wt1tt_h, Wt1tt_l, Wt1rt_h, Wt1rt_l,
      b1_tt, b1_rt, Ht_bf, N_TILE);

  // ---- layer 2: bf16 gather of layer-1 outputs (tr relation skipped) ----
  {
    int totw = N_TILE + N_TILE;
    k_agg3<<<(totw * 64 + 255) / 256, 256, 0, stream>>>(
        Ht_bf, rp_tt, pr_tt, isc_tt, Abf, N_TILE,
        Hr_bf, rp_rt, pr_rt, isc_rt, Bbf, N_TILE,
        nullptr, nullptr, nullptr, nullptr, nullptr, 0);
  }
  k_gemm_m<2, false><<<gemmBlocks, 256, 0, stream>>>(
      Abf, Bbf, Wt2tt_h, Wt2tt_l, Wt2rt_h, Wt2rt_l,
      b2_tt, b2_rt, Htile, N_TILE);

  // ---- pooling + MLP head ----
  k_pool<<<(N_TILE + PCHUNK - 1) / PCHUNK, 256, 0, stream>>>(Htile, tile_gid, psum, pcnt, N_TILE);
  k_final<<<1, 256, 0, stream>>>(psum, pcnt, Wm1, bm1, Wm2, bm2, (float*)d_out);
}

// Round 16
// 301.871 us; speedup vs baseline: 1.5473x; 1.0053x over previous
//
#include <hip/hip_runtime.h>

#define N_TILE 50000
#define N_RR   50000
#define D      128
#define E_TT   800000
#define E_RT   400000
#define E_TR   400000
#define N_G    16
#define NB     ((N_TILE + 1023) / 1024)   // scan blocks per array (=49)
#define E_ALL  (E_TT + E_RT + E_TR)
#define BKT    25600                       // bins per bucket (16-bit packed, 50KB LDS)
#define NBKT   2                           // buckets cover 51200 >= N_TILE
#define NCHK   32                          // edge chunks (all E divisible by 32)
#define WPREP_BLOCKS 320                   // 5 weights * 64 blocks

static_assert(NB <= 64, "scan2 uses one wave per array");
static_assert(N_TILE == N_RR, "shared bucket geometry assumes equal node counts");
static_assert((size_t)BKT * NBKT >= N_TILE, "bucket coverage");
static_assert(E_TT % NCHK == 0 && E_RT % NCHK == 0 && E_TR % NCHK == 0, "chunking");

typedef __attribute__((ext_vector_type(8))) short bf16x8;
typedef __attribute__((ext_vector_type(4))) float f32x4;
typedef __attribute__((ext_vector_type(2))) float v2f;
typedef unsigned short u16;

__device__ inline u16 f2bf(float f) {
  unsigned u = __float_as_uint(f);
  unsigned r = (u + 0x7FFFu + ((u >> 16) & 1u)) >> 16;   // RNE
  return (u16)r;
}
__device__ inline float bf2f(u16 h) { return __uint_as_float(((unsigned)h) << 16); }

// packed FMA: acc.{x,y} += pair.{x,y} * w.{x,y}  (one VOP3P instruction)
__device__ inline void pk_fma(v2f& acc, v2f pair, v2f w) {
  asm("v_pk_fma_f32 %0, %1, %2, %0" : "+v"(acc) : "v"(pair), "v"(w));
}
// unpack u32 (2 bf16) -> {lo, cheap-hi}; hi keeps low 16 bits as sub-ulp noise
__device__ inline v2f bfpair(unsigned w) {
  v2f p;
  p.x = __uint_as_float(w << 16);
  p.y = __uint_as_float(w);
  return p;
}

// ---------------- bucketed LDS histogram + rank capture: NO global atomics ----
__global__ __launch_bounds__(512) void k_hist(
    const int* __restrict__ tt_src, const int* __restrict__ tt_dst,
    const int* __restrict__ rt_src, const int* __restrict__ rt_dst,
    const int* __restrict__ tr_src, const int* __restrict__ tr_dst,
    int* __restrict__ partial, int* __restrict__ rank) {
  __shared__ unsigned h[BKT / 2];
  int bid = blockIdx.x;
  int s = bid / (NBKT * NCHK);
  int rem = bid % (NBKT * NCHK);
  int b = rem / NCHK;
  int c = rem % NCHK;
  const int* arr; int E; int roff = 0;
  switch (s) {
    case 0: arr = tt_dst; E = E_TT; roff = 0; break;
    case 1: arr = rt_dst; E = E_RT; roff = E_TT; break;
    case 2: arr = tr_dst; E = E_TR; roff = E_TT + E_RT; break;
    case 3: arr = tt_src; E = E_TT; break;
    case 4: arr = rt_src; E = E_RT; break;
    default: arr = tr_src; E = E_TR; break;
  }
  bool isdst = s < 3;
  for (int j = threadIdx.x; j < BKT / 2; j += 512) h[j] = 0;
  __syncthreads();
  int ec = E / NCHK;
  int lo = c * ec, hi = lo + ec;
  int base = b * BKT;
  for (int i = lo + threadIdx.x; i < hi; i += 512) {
    unsigned int off = (unsigned int)(arr[i] - base);
    if (off < BKT) {
      unsigned sh = (off & 1u) << 4;
      unsigned r = atomicAdd(&h[off >> 1], 1u << sh);
      if (isdst) rank[roff + i] = (int)((r >> sh) & 0xffffu);
    }
  }
  __syncthreads();
  int* dst = partial + (size_t)(s * NCHK + c) * N_TILE;
  for (int j = threadIdx.x; j < BKT; j += 512) {
    int bin = base + j;
    if (bin < N_TILE)
      dst[bin] = (int)((h[j >> 1] >> ((j & 1) << 4)) & 0xffffu);
  }
}

// ---------------- reduce partials ----------------
__global__ __launch_bounds__(256) void k_hreduce(
    int* __restrict__ partial,
    int* __restrict__ id_tt, int* __restrict__ id_rt, int* __restrict__ id_tr,
    float* __restrict__ os_tt, float* __restrict__ os_rt, float* __restrict__ os_tr) {
  int t = blockIdx.x * 256 + threadIdx.x;
  if (t >= 6 * N_TILE) return;
  int s = t / N_TILE;
  int i = t - s * N_TILE;
  int* p = partial + (size_t)s * NCHK * N_TILE + i;
  int run = 0;
  if (s < 3) {
#pragma unroll
    for (int c = 0; c < NCHK; ++c) {
      int v = p[(size_t)c * N_TILE];
      p[(size_t)c * N_TILE] = run;
      run += v;
    }
    if (s == 0) id_tt[i] = run;
    else if (s == 1) id_rt[i] = run;
    else id_tr[i] = run;
  } else {
#pragma unroll
    for (int c = 0; c < NCHK; ++c) run += p[(size_t)c * N_TILE];
    float v = rsqrtf((float)max(run, 1));
    if (s == 3) os_tt[i] = v;
    else if (s == 4) os_rt[i] = v;
    else os_tr[i] = v;
  }
}

// ---------------- scan stage 1 ----------------
__global__ __launch_bounds__(1024) void k_scan1(const int* __restrict__ d0,
                                                const int* __restrict__ d1,
                                                const int* __restrict__ d2,
                                                int* __restrict__ p0,
                                                int* __restrict__ p1,
                                                int* __restrict__ p2,
                                                int* __restrict__ bsum) {
  int arr = blockIdx.x / NB;
  int blk = blockIdx.x % NB;
  const int* deg = arr == 0 ? d0 : (arr == 1 ? d1 : d2);
  int* part = arr == 0 ? p0 : (arr == 1 ? p1 : p2);
  __shared__ int ts[1024];
  int tid = threadIdx.x;
  int i = blk * 1024 + tid;
  int v = (i < N_TILE) ? deg[i] : 0;
  ts[tid] = v;
  __syncthreads();
  for (int d = 1; d < 1024; d <<= 1) {
    int t = (tid >= d) ? ts[tid - d] : 0;
    __syncthreads();
    ts[tid] += t;
    __syncthreads();
  }
  if (i < N_TILE) part[i] = ts[tid] - v;
  if (tid == 1023) bsum[arr * NB + blk] = ts[1023];
}

// ---------------- scan stage 2 ----------------
__global__ __launch_bounds__(256) void k_scan2(const int* __restrict__ bsum,
                                               int* __restrict__ bs) {
  int wv = threadIdx.x >> 6;
  int lane = threadIdx.x & 63;
  if (wv >= 3) return;
  int v = (lane < NB) ? bsum[wv * NB + lane] : 0;
  int orig = v;
#pragma unroll
  for (int o = 1; o < 64; o <<= 1) {
    int t = __shfl_up(v, o);
    if (lane >= o) v += t;
  }
  if (lane < NB) bs[wv * (NB + 1) + lane] = v - orig;
  if (lane == NB - 1) bs[wv * (NB + 1) + NB] = v;
}

// ---------------- finalize ----------------
__global__ void k_finalize(const int* __restrict__ pp_tt, const int* __restrict__ pp_rt,
                           const int* __restrict__ pp_tr, const int* __restrict__ bs,
                           int* __restrict__ rp_tt, int* __restrict__ rp_rt,
                           int* __restrict__ rp_tr,
                           const int* __restrict__ id_tt, const int* __restrict__ id_rt,
                           const int* __restrict__ id_tr,
                           float* __restrict__ is_tt, float* __restrict__ is_rt,
                           float* __restrict__ is_tr) {
  int i = blockIdx.x * blockDim.x + threadIdx.x;
  if (i >= N_TILE) return;
  int b = i >> 10;
  rp_tt[i] = pp_tt[i] + bs[0 * (NB + 1) + b];
  rp_rt[i] = pp_rt[i] + bs[1 * (NB + 1) + b];
  rp_tr[i] = pp_tr[i] + bs[2 * (NB + 1) + b];
  if (i == 0) {
    rp_tt[N_TILE] = bs[0 * (NB + 1) + NB];
    rp_rt[N_TILE] = bs[1 * (NB + 1) + NB];
    rp_tr[N_RR] = bs[2 * (NB + 1) + NB];
  }
  is_tt[i] = rsqrtf((float)max(id_tt[i], 1));
  is_rt[i] = rsqrtf((float)max(id_rt[i], 1));
  is_tr[i] = rsqrtf((float)max(id_tr[i], 1));
}

// ---------------- CSR fill: one thread per edge, atomic-free ----------------
__global__ __launch_bounds__(256) void k_fill(
    const int* __restrict__ tt_src, const int* __restrict__ tt_dst,
    const int* __restrict__ rt_src, const int* __restrict__ rt_dst,
    const int* __restrict__ tr_src, const int* __restrict__ tr_dst,
    const int* __restrict__ rp_tt, const int* __restrict__ rp_rt,
    const int* __restrict__ rp_tr,
    const float* __restrict__ os_tt, const float* __restrict__ os_rt,
    const float* __restrict__ os_tr,
    const int* __restrict__ partial, const int* __restrict__ rank,
    int2* __restrict__ pr_tt, int2* __restrict__ pr_rt, int2* __restrict__ pr_tr) {
  int i = blockIdx.x * 256 + threadIdx.x;
  if (i >= E_ALL) return;
  const int* srcA; const int* dstA; const int* rp; const float* os; int2* pr;
  int j, s, ec;
  if (i < E_TT) {
    s = 0; j = i; ec = E_TT / NCHK;
    srcA = tt_src; dstA = tt_dst; rp = rp_tt; os = os_tt; pr = pr_tt;
  } else if (i < E_TT + E_RT) {
    s = 1; j = i - E_TT; ec = E_RT / NCHK;
    srcA = rt_src; dstA = rt_dst; rp = rp_rt; os = os_rt; pr = pr_rt;
  } else {
    s = 2; j = i - E_TT - E_RT; ec = E_TR / NCHK;
    srcA = tr_src; dstA = tr_dst; rp = rp_tr; os = os_tr; pr = pr_tr;
  }
  int d = dstA[j];
  int c = j / ec;
  int slot = rp[d] + partial[(size_t)(s * NCHK + c) * N_TILE + d] + rank[i];
  int sv = srcA[j];
  int2 v;
  v.x = sv;
  v.y = __float_as_int(os[sv]);
  pr[slot] = v;
}

// ---------------- fused prep: weight split (blocks < WPREP_BLOCKS) + x->bf16 conv ----
__global__ __launch_bounds__(256) void k_prep(
    const float* __restrict__ W0, const float* __restrict__ W1,
    const float* __restrict__ W2, const float* __restrict__ W3,
    const float* __restrict__ W4,
    u16* __restrict__ T0h, u16* __restrict__ T0l,
    u16* __restrict__ T1h, u16* __restrict__ T1l,
    u16* __restrict__ T2h, u16* __restrict__ T2l,
    u16* __restrict__ T3h, u16* __restrict__ T3l,
    u16* __restrict__ T4h, u16* __restrict__ T4l,
    const float* __restrict__ xa, const float* __restrict__ xb,
    u16* __restrict__ oa, u16* __restrict__ ob) {
  int bid = blockIdx.x;
  if (bid < WPREP_BLOCKS) {
    int s = bid >> 6;
    int idx = ((bid & 63) << 8) + threadIdx.x;   // n*128+k
    const float* W = s == 0 ? W0 : (s == 1 ? W1 : (s == 2 ? W2 : (s == 3 ? W3 : W4)));
    u16* Th = s == 0 ? T0h : (s == 1 ? T1h : (s == 2 ? T2h : (s == 3 ? T3h : T4h)));
    u16* Tl = s == 0 ? T0l : (s == 1 ? T1l : (s == 2 ? T2l : (s == 3 ? T3l : T4l)));
    int n = idx >> 7, k = idx & 127;
    float w = W[k * 128 + n];
    u16 h = f2bf(w);
    Th[idx] = h;
    Tl[idx] = f2bf(w - bf2f(h));
    return;
  }
  const size_t TOT = (size_t)N_TILE * D / 8;
  size_t i = (size_t)(bid - WPREP_BLOCKS) * 256 + threadIdx.x;
  if (i >= 2 * TOT) return;
  const float* src = (i < TOT) ? xa : xb;
  u16* dst = (i < TOT) ? oa : ob;
  size_t j = ((i < TOT) ? i : i - TOT) * 8;
  float4 v0 = *(const float4*)(src + j);
  float4 v1 = *(const float4*)(src + j + 4);
  ushort4 h0, h1;
  h0.x = f2bf(v0.x); h0.y = f2bf(v0.y); h0.z = f2bf(v0.z); h0.w = f2bf(v0.w);
  h1.x = f2bf(v1.x); h1.y = f2bf(v1.y); h1.z = f2bf(v1.z); h1.w = f2bf(v1.w);
  *(ushort4*)(dst + j) = h0;
  *(ushort4*)(dst + j + 4) = h1;
}

// ---------------- fused aggregation (up to 3 relations) -> bf16 rows --------
// out[d][:] = bf16( isc[d] * sum_e w_e * x[src_e] );  x rows = bf16.
// Quarter q owns edge PAIR (e+2q, e+2q+1): ONE int4 load fetches both (src,w)
// descriptors; 2 row loads; 8 pk_fma. Bulk loop clamp-free.
__global__ __launch_bounds__(256) void k_agg3(
    const u16* __restrict__ x0, const int* __restrict__ rp0, const int2* __restrict__ pr0,
    const float* __restrict__ isc0, u16* __restrict__ oh0, int n0,
    const u16* __restrict__ x1, const int* __restrict__ rp1, const int2* __restrict__ pr1,
    const float* __restrict__ isc1, u16* __restrict__ oh1, int n1,
    const u16* __restrict__ x2, const int* __restrict__ rp2, const int2* __restrict__ pr2,
    const float* __restrict__ isc2, u16* __restrict__ oh2, int n2) {
  int gw = (blockIdx.x * blockDim.x + threadIdx.x) >> 6;
  int lane = threadIdx.x & 63;
  int q = lane >> 4;        // edge-pair slot
  int l4 = lane & 15;       // uint4 slot within the 256B row
  const u16* x; const int* rp; const int2* pr; const float* isc;
  u16* oh; int wid;
  if (gw < n0) { x = x0; rp = rp0; pr = pr0; isc = isc0; oh = oh0; wid = gw; }
  else if (gw < n0 + n1) { x = x1; rp = rp1; pr = pr1; isc = isc1; oh = oh1; wid = gw - n0; }
  else if (gw < n0 + n1 + n2) { x = x2; rp = rp2; pr = pr2; isc = isc2; oh = oh2; wid = gw - n0 - n1; }
  else return;
  int beg = rp[wid], end = rp[wid + 1];
  v2f a0[4], a1[4];
#pragma unroll
  for (int j = 0; j < 4; ++j) { a0[j] = (v2f){0.f, 0.f}; a1[j] = (v2f){0.f, 0.f}; }
  const uint4* xb = (const uint4*)x + l4;   // row = 128 bf16 = 16 uint4
  int nfull = (end - beg) & ~7;
  int efull = beg + nfull;
  for (int e = beg; e < efull; e += 8) {
    int4 pp = *(const int4*)(pr + e + 2 * q);   // 16B-aligned: e%8==0, 2q even
    v2f w02 = {__int_as_float(pp.y), __int_as_float(pp.y)};
    v2f w12 = {__int_as_float(pp.w), __int_as_float(pp.w)};
    uint4 u0 = xb[(size_t)pp.x * 16];
    uint4 u1 = xb[(size_t)pp.z * 16];
    pk_fma(a0[0], bfpair(u0.x), w02);
    pk_fma(a0[1], bfpair(u0.y), w02);
    pk_fma(a0[2], bfpair(u0.z), w02);
    pk_fma(a0[3], bfpair(u0.w), w02);
    pk_fma(a1[0], bfpair(u1.x), w12);
    pk_fma(a1[1], bfpair(u1.y), w12);
    pk_fma(a1[2], bfpair(u1.z), w12);
    pk_fma(a1[3], bfpair(u1.w), w12);
  }
  if (efull < end) {
    int lim = end - 1;
    int i0 = efull + 2 * q, i1 = i0 + 1;
    int2 p0 = pr[min(i0, lim)];
    int2 p1 = pr[min(i1, lim)];
    float w0 = (i0 < end) ? __int_as_float(p0.y) : 0.f;
    float w1 = (i1 < end) ? __int_as_float(p1.y) : 0.f;
    v2f w02 = {w0, w0}, w12 = {w1, w1};
    uint4 u0 = xb[(size_t)p0.x * 16];
    uint4 u1 = xb[(size_t)p1.x * 16];
    pk_fma(a0[0], bfpair(u0.x), w02);
    pk_fma(a0[1], bfpair(u0.y), w02);
    pk_fma(a0[2], bfpair(u0.z), w02);
    pk_fma(a0[3], bfpair(u0.w), w02);
    pk_fma(a1[0], bfpair(u1.x), w12);
    pk_fma(a1[1], bfpair(u1.y), w12);
    pk_fma(a1[2], bfpair(u1.z), w12);
    pk_fma(a1[3], bfpair(u1.w), w12);
  }
  float s[8];
#pragma unroll
  for (int j = 0; j < 4; ++j) {
    v2f t = a0[j] + a1[j];
    s[2 * j] = t.x;
    s[2 * j + 1] = t.y;
  }
#pragma unroll
  for (int j = 0; j < 8; ++j) {
    s[j] += __shfl_xor(s[j], 16);
    s[j] += __shfl_xor(s[j], 32);
  }
  if (q == 0) {
    float iv = isc[wid];
    unsigned hb[8];
#pragma unroll
    for (int j = 0; j < 8; ++j) hb[j] = f2bf(s[j] * iv);
    uint4 hw;
    hw.x = hb[0] | (hb[1] << 16); hw.y = hb[2] | (hb[3] << 16);
    hw.z = hb[4] | (hb[5] << 16); hw.w = hb[6] | (hb[7] << 16);
    *(uint4*)(oh + (size_t)wid * D + l4 * 8) = hw;
  }
}

// ---------------- MFMA bf16 GEMM(+GEMM) + bias + relu ----------------
// out = relu( A1@W1 (+ A2@W2) + b1 (+ b2) ); OBF: output bf16 rows, else fp32.
// C = A@Whi + A@Wlo (weight split kept: W rounding is systematic).
template<int NREL, bool OBF>
__global__ __launch_bounds__(256) void k_gemm_m(
    const u16* __restrict__ A1, const u16* __restrict__ A2,
    const u16* __restrict__ Wt1h, const u16* __restrict__ Wt1l,
    const u16* __restrict__ Wt2h, const u16* __restrict__ Wt2l,
    const float* __restrict__ b1, const float* __restrict__ b2,
    void* __restrict__ outv, int nrows) {
  __shared__ u16 Ah[128][40];   // pad 40: 2-way-only LDS conflicts on b128 reads
  __shared__ u16 Wh[128][40];   // [n][k]
  __shared__ u16 Wl[128][40];
  int tid = threadIdx.x;
  int wv = tid >> 6, lane = tid & 63;
  int l15 = lane & 15, lg = lane >> 4;
  int r0 = blockIdx.x * 128;
  f32x4 acc[2][8];
#pragma unroll
  for (int i = 0; i < 2; ++i)
#pragma unroll
    for (int j = 0; j < 8; ++j) acc[i][j] = (f32x4){0.f, 0.f, 0.f, 0.f};

  int srow = tid >> 1;             // 0..127
  int c0 = (tid & 1) * 16;         // u16 col base 0 or 16
  int gr = r0 + srow;

  for (int rel = 0; rel < NREL; ++rel) {
    const u16* pA = (NREL == 2 && rel) ? A2 : A1;
    const u16* pWh = (NREL == 2 && rel) ? Wt2h : Wt1h;
    const u16* pWl = (NREL == 2 && rel) ? Wt2l : Wt1l;
    for (int k0 = 0; k0 < 128; k0 += 32) {
      __syncthreads();
      uint4 z = {0, 0, 0, 0};
      uint4 va0 = z, va1 = z;
      if (gr < nrows) {
        va0 = *(const uint4*)(pA + (size_t)gr * 128 + k0 + c0);
        va1 = *(const uint4*)(pA + (size_t)gr * 128 + k0 + c0 + 8);
      }
      *(uint4*)&Ah[srow][c0] = va0;
      *(uint4*)&Ah[srow][c0 + 8] = va1;
      *(uint4*)&Wh[srow][c0]     = *(const uint4*)(pWh + (size_t)srow * 128 + k0 + c0);
      *(uint4*)&Wh[srow][c0 + 8] = *(const uint4*)(pWh + (size_t)srow * 128 + k0 + c0 + 8);
      *(uint4*)&Wl[srow][c0]     = *(const uint4*)(pWl + (size_t)srow * 128 + k0 + c0);
      *(uint4*)&Wl[srow][c0 + 8] = *(const uint4*)(pWl + (size_t)srow * 128 + k0 + c0 + 8);
      __syncthreads();
      bf16x8 a0 = *(const bf16x8*)&Ah[wv * 32 + l15][lg * 8];
      bf16x8 a1 = *(const bf16x8*)&Ah[wv * 32 + 16 + l15][lg * 8];
#pragma unroll
      for (int ct = 0; ct < 8; ++ct) {
        bf16x8 bh = *(const bf16x8*)&Wh[ct * 16 + l15][lg * 8];
        bf16x8 bl = *(const bf16x8*)&Wl[ct * 16 + l15][lg * 8];
        acc[0][ct] = __builtin_amdgcn_mfma_f32_16x16x32_bf16(a0, bh, acc[0][ct], 0, 0, 0);
        acc[0][ct] = __builtin_amdgcn_mfma_f32_16x16x32_bf16(a0, bl, acc[0][ct], 0, 0, 0);
        acc[1][ct] = __builtin_amdgcn_mfma_f32_16x16x32_bf16(a1, bh, acc[1][ct], 0, 0, 0);
        acc[1][ct] = __builtin_amdgcn_mfma_f32_16x16x32_bf16(a1, bl, acc[1][ct], 0, 0, 0);
      }
    }
  }
  // epilogue: bias + relu; C layout col=lane&15, row=(lane>>4)*4+reg
#pragma unroll
  for (int ct = 0; ct < 8; ++ct) {
    int col = ct * 16 + l15;
    float bias = b1[col];
    if (NREL == 2) bias += b2[col];
#pragma unroll
    for (int rt = 0; rt < 2; ++rt) {
      int rowb = r0 + wv * 32 + rt * 16 + lg * 4;
#pragma unroll
      for (int r = 0; r < 4; ++r) {
        int row = rowb + r;
        if (row < nrows) {
          float v = fmaxf(acc[rt][ct][r] + bias, 0.f);
          if (OBF) ((u16*)outv)[(size_t)row * 128 + col] = f2bf(v);
          else ((float*)outv)[(size_t)row * 128 + col] = v;
        }
      }
    }
  }
}

// ---------------- per-graph mean pooling: 8 rows parallel, float4 cols ------
#define PCHUNK 256
__global__ __launch_bounds__(256) void k_pool(const float* __restrict__ H,
                                              const int* __restrict__ gid,
                                              float* __restrict__ sums,
                                              float* __restrict__ cnt, int n) {
  __shared__ float4 red[256];
  int tid = threadIdx.x;
  int c4 = tid & 31;        // float4 slot (32 x 4 = 128 cols)
  int slot = tid >> 5;      // 0..7 parallel row slots
  int start = blockIdx.x * PCHUNK;
  if (start >= n) return;
  int end = min(start + PCHUNK, n);
  if (gid[start] == gid[end - 1]) {
    int g = gid[start];
    float4 acc = make_float4(0.f, 0.f, 0.f, 0.f);
    for (int r = start + slot; r < end; r += 8) {
      float4 v = *(const float4*)(H + (size_t)r * D + c4 * 4);
      acc.x += v.x; acc.y += v.y; acc.z += v.z; acc.w += v.w;
    }
    red[tid] = acc;
    __syncthreads();
    if (slot == 0) {
      float4 a = red[c4];
#pragma unroll
      for (int s2 = 1; s2 < 8; ++s2) {
        float4 b = red[s2 * 32 + c4];
        a.x += b.x; a.y += b.y; a.z += b.z; a.w += b.w;
      }
      float* p = &sums[g * D + c4 * 4];
      atomicAdd(p + 0, a.x); atomicAdd(p + 1, a.y);
      atomicAdd(p + 2, a.z); atomicAdd(p + 3, a.w);
      if (c4 == 0) atomicAdd(&cnt[g], (float)(end - start));
    }
    return;
  }
  float4 acc = make_float4(0.f, 0.f, 0.f, 0.f);
  int cur = -1, cl = 0;
  for (int r = start + slot; r < end; r += 8) {
    int g = gid[r];
    if (g != cur) {
      if (cur >= 0) {
        float* p = &sums[cur * D + c4 * 4];
        atomicAdd(p + 0, acc.x); atomicAdd(p + 1, acc.y);
        atomicAdd(p + 2, acc.z); atomicAdd(p + 3, acc.w);
        if (c4 == 0) atomicAdd(&cnt[cur], (float)cl);
      }
      acc = make_float4(0.f, 0.f, 0.f, 0.f); cl = 0; cur = g;
    }
    float4 v = *(const float4*)(H + (size_t)r * D + c4 * 4);
    acc.x += v.x; acc.y += v.y; acc.z += v.z; acc.w += v.w;
    cl++;
  }
  if (cur >= 0) {
    float* p = &sums[cur * D + c4 * 4];
    atomicAdd(p + 0, acc.x); atomicAdd(p + 1, acc.y);
    atomicAdd(p + 2, acc.z); atomicAdd(p + 3, acc.w);
    if (c4 == 0) atomicAdd(&cnt[cur], (float)cl);
  }
}

// ---------------- final MLP on [16,128] ----------------
__global__ __launch_bounds__(256) void k_final(const float* __restrict__ sums,
                                               const float* __restrict__ cnt,
                                               const float* __restrict__ Wm1,
                                               const float* __restrict__ bm1,
                                               const float* __restrict__ Wm2,
                                               const float* __restrict__ bm2,
                                               float* __restrict__ out) {
  __shared__ float hg[16][128];
  __shared__ float t1[16][128];
  int tid = threadIdx.x;
  for (int i = tid; i < 16 * 128; i += 256) {
    int g = i >> 7, c = i & 127;
    hg[g][c] = sums[i] / fmaxf(cnt[g], 1.f);
  }
  __syncthreads();
  for (int i = tid; i < 16 * 128; i += 256) {
    int g = i >> 7, c = i & 127;
    float a = bm1[c];
    for (int k = 0; k < 128; ++k) a = fmaf(hg[g][k], Wm1[k * 128 + c], a);
    t1[g][c] = fmaxf(a, 0.f);
  }
  __syncthreads();
  int g = tid >> 4, l = tid & 15;
  float p = 0.f;
  for (int c = l; c < 128; c += 16) p = fmaf(t1[g][c], Wm2[c], p);
#pragma unroll
  for (int o = 8; o; o >>= 1) p += __shfl_down(p, o, 16);
  if (l == 0) out[g] = p + bm2[0];
}

extern "C" void kernel_launch(void* const* d_in, const int* in_sizes, int n_in,
                              void* d_out, int out_size, void* d_ws, size_t ws_size,
                              hipStream_t stream) {
  const float* x_tile = (const float*)d_in[0];
  const float* x_rr   = (const float*)d_in[1];
  const int* tt_src = (const int*)d_in[2];
  const int* tt_dst = (const int*)d_in[3];
  const int* rt_src = (const int*)d_in[4];
  const int* rt_dst = (const int*)d_in[5];
  const int* tr_src = (const int*)d_in[6];
  const int* tr_dst = (const int*)d_in[7];
  const int* tile_gid = (const int*)d_in[8];
  const float* W1_tt = (const float*)d_in[9];  const float* b1_tt = (const float*)d_in[10];
  const float* W1_rt = (const float*)d_in[11]; const float* b1_rt = (const float*)d_in[12];
  const float* W1_tr = (const float*)d_in[13]; const float* b1_tr = (const float*)d_in[14];
  const float* W2_tt = (const float*)d_in[15]; const float* b2_tt = (const float*)d_in[16];
  const float* W2_rt = (const float*)d_in[17]; const float* b2_rt = (const float*)d_in[18];
  const float* Wm1 = (const float*)d_in[21]; const float* bm1 = (const float*)d_in[22];
  const float* Wm2 = (const float*)d_in[23]; const float* bm2 = (const float*)d_in[24];

  char* ws = (char*)d_ws;
  size_t off = 0;
  auto allocB = [&](size_t bytes) {
    void* p = ws + off;
    off += (bytes + 255) & ~(size_t)255;
    return p;
  };
  // ---- zero region (memset each call) ----
  float* psum = (float*)allocB(N_G * D * 4);
  float* pcnt = (float*)allocB(N_G * 4);
  size_t zero_bytes = off;
  // ---- rest (all fully written before read) ----
  int* partial = (int*)allocB((size_t)6 * NCHK * N_TILE * 4);
  int* rank = (int*)allocB((size_t)E_ALL * 4);
  int* ideg_tt = (int*)allocB(N_TILE * 4);
  int* ideg_rt = (int*)allocB(N_TILE * 4);
  int* ideg_tr = (int*)allocB(N_RR * 4);
  int* pp_tt = (int*)allocB(N_TILE * 4);
  int* pp_rt = (int*)allocB(N_TILE * 4);
  int* pp_tr = (int*)allocB(N_RR * 4);
  int* bsum = (int*)allocB(3 * NB * 4);
  int* bs = (int*)allocB(3 * (NB + 1) * 4);
  int* rp_tt = (int*)allocB((N_TILE + 1) * 4);
  int* rp_rt = (int*)allocB((N_TILE + 1) * 4);
  int* rp_tr = (int*)allocB((N_RR + 1) * 4);
  int2* pr_tt = (int2*)allocB((size_t)E_TT * 8);
  int2* pr_rt = (int2*)allocB((size_t)E_RT * 8);
  int2* pr_tr = (int2*)allocB((size_t)E_TR * 8);
  float* osc_tt = (float*)allocB(N_TILE * 4);
  float* osc_rt = (float*)allocB(N_RR * 4);
  float* osc_tr = (float*)allocB(N_TILE * 4);
  float* isc_tt = (float*)allocB(N_TILE * 4);
  float* isc_rt = (float*)allocB(N_TILE * 4);
  float* isc_tr = (float*)allocB(N_RR * 4);
  u16* xt_bf = (u16*)allocB((size_t)N_TILE * D * 2);
  u16* xr_bf = (u16*)allocB((size_t)N_RR * D * 2);
  u16* Abf = (u16*)allocB((size_t)N_TILE * D * 2);
  u16* Bbf = (u16*)allocB((size_t)N_TILE * D * 2);
  u16* Cbf = (u16*)allocB((size_t)N_RR * D * 2);
  u16* Ht_bf = (u16*)allocB((size_t)N_TILE * D * 2);   // layer-1 tile output (bf16)
  u16* Hr_bf = (u16*)allocB((size_t)N_RR * D * 2);     // layer-1 rr output (bf16)
  float* Htile = (float*)allocB((size_t)N_TILE * D * 4); // layer-2 output (fp32, pooled)
  u16* Wt1tt_h = (u16*)allocB(D * D * 2); u16* Wt1tt_l = (u16*)allocB(D * D * 2);
  u16* Wt1rt_h = (u16*)allocB(D * D * 2); u16* Wt1rt_l = (u16*)allocB(D * D * 2);
  u16* Wt1tr_h = (u16*)allocB(D * D * 2); u16* Wt1tr_l = (u16*)allocB(D * D * 2);
  u16* Wt2tt_h = (u16*)allocB(D * D * 2); u16* Wt2tt_l = (u16*)allocB(D * D * 2);
  u16* Wt2rt_h = (u16*)allocB(D * D * 2); u16* Wt2rt_l = (u16*)allocB(D * D * 2);
  (void)ws_size; (void)in_sizes; (void)n_in; (void)out_size;

  hipMemsetAsync(d_ws, 0, zero_bytes, stream);

  // ---- fused prep: weight split + x->bf16 conversion ----
  {
    int convBlocks = (2 * N_TILE * (D / 8) + 255) / 256;
    k_prep<<<WPREP_BLOCKS + convBlocks, 256, 0, stream>>>(
        W1_tt, W1_rt, W1_tr, W2_tt, W2_rt,
        Wt1tt_h, Wt1tt_l, Wt1rt_h, Wt1rt_l, Wt1tr_h, Wt1tr_l,
        Wt2tt_h, Wt2tt_l, Wt2rt_h, Wt2rt_l,
        x_tile, x_rr, xt_bf, xr_bf);
  }

  // ---- CSR build: zero global atomics, atomic-free fill via hist-rank ----
  k_hist<<<6 * NBKT * NCHK, 512, 0, stream>>>(
      tt_src, tt_dst, rt_src, rt_dst, tr_src, tr_dst, partial, rank);
  k_hreduce<<<(6 * N_TILE + 255) / 256, 256, 0, stream>>>(
      partial, ideg_tt, ideg_rt, ideg_tr, osc_tt, osc_rt, osc_tr);
  k_scan1<<<3 * NB, 1024, 0, stream>>>(ideg_tt, ideg_rt, ideg_tr, pp_tt, pp_rt, pp_tr, bsum);
  k_scan2<<<1, 256, 0, stream>>>(bsum, bs);
  k_finalize<<<(N_TILE + 255) / 256, 256, 0, stream>>>(
      pp_tt, pp_rt, pp_tr, bs, rp_tt, rp_rt, rp_tr,
      ideg_tt, ideg_rt, ideg_tr, isc_tt, isc_rt, isc_tr);
  k_fill<<<(E_ALL + 255) / 256, 256, 0, stream>>>(
      tt_src, tt_dst, rt_src, rt_dst, tr_src, tr_dst,
      rp_tt, rp_rt, rp_tr, osc_tt, osc_rt, osc_tr,
      partial, rank, pr_tt, pr_rt, pr_tr);

  const int gemmBlocks = (N_TILE + 127) / 128;

  // ---- layer 1: all three aggs fused, bf16 gather -> bf16 rows ----
  {
    int totw = N_TILE + N_TILE + N_RR;
    k_agg3<<<(totw * 64 + 255) / 256, 256, 0, stream>>>(
        xt_bf, rp_tt, pr_tt, isc_tt, Abf, N_TILE,
        xr_bf, rp_rt, pr_rt, isc_rt, Bbf, N_TILE,
        xt_bf, rp_tr, pr_tr, isc_tr, Cbf, N_RR);
  }
  k_gemm_m<1, true><<<gemmBlocks, 256, 0, stream>>>(
      Cbf, nullptr, Wt1tr_h, Wt1tr_l, nullptr, nullptr,
      b1_tr, nullptr, Hr_bf, N_RR);
  k_gemm_m<2, true><<<gemmBlocks, 256, 0, stream>>>(
      Abf, Bbf, Wt1tt_h, Wt1tt_l, Wt1rt_h, Wt1rt_l,
      b1_tt, b1_rt, Ht_bf, N_TILE);

  // ---- layer 2: bf16 gather of layer-1 outputs (tr relation skipped) ----
  {
    int totw = N_TILE + N_TILE;
    k_agg3<<<(totw * 64 + 255) / 256, 256, 0, stream>>>(
        Ht_bf, rp_tt, pr_tt, isc_tt, Abf, N_TILE,
        Hr_bf, rp_rt, pr_rt, isc_rt, Bbf, N_TILE,
        nullptr, nullptr, nullptr, nullptr, nullptr, 0);
  }
  k_gemm_m<2, false><<<gemmBlocks, 256, 0, stream>>>(
      Abf, Bbf, Wt2tt_h, Wt2tt_l, Wt2rt_h, Wt2rt_l,
      b2_tt, b2_rt, Htile, N_TILE);

  // ---- pooling + MLP head ----
  k_pool<<<(N_TILE + PCHUNK - 1) / PCHUNK, 256, 0, stream>>>(Htile, tile_gid, psum, pcnt, N_TILE);
  k_final<<<1, 256, 0, stream>>>(psum, pcnt, Wm1, bm1, Wm2, bm2, (float*)d_out);
}

// Round 17
// 290.697 us; speedup vs baseline: 1.6068x; 1.0384x over previous
//
#include <hip/hip_runtime.h>

#define N_TILE 50000
#define N_RR   50000
#define D      128
#define E_TT   800000
#define E_RT   400000
#define E_TR   400000
#define N_G    16
#define NB     ((N_TILE + 1023) / 1024)   // scan blocks per array (=49)
#define E_ALL  (E_TT + E_RT + E_TR)
#define BKT    25600                       // bins per bucket (16-bit packed, 50KB LDS)
#define NBKT   2                           // buckets cover 51200 >= N_TILE
#define NCHK   32                          // edge chunks (all E divisible by 32)
#define HIST_BLOCKS (6 * NBKT * NCHK)      // 384
#define WPREP_BLOCKS 160                   // 5 weights * 32 blocks (512 thr)
#define CONV_UNITS  (2 * N_TILE * (D / 8)) // vec8 units over both x tables
#define CONV_BLOCKS ((CONV_UNITS + 511) / 512)

static_assert(NB <= 64, "inline scan uses one wave per array");
static_assert(N_TILE == N_RR, "shared bucket geometry assumes equal node counts");
static_assert((size_t)BKT * NBKT >= N_TILE, "bucket coverage");
static_assert(E_TT % NCHK == 0 && E_RT % NCHK == 0 && E_TR % NCHK == 0, "chunking");

typedef __attribute__((ext_vector_type(8))) short bf16x8;
typedef __attribute__((ext_vector_type(4))) float f32x4;
typedef __attribute__((ext_vector_type(2))) float v2f;
typedef unsigned short u16;

__device__ inline u16 f2bf(float f) {
  unsigned u = __float_as_uint(f);
  unsigned r = (u + 0x7FFFu + ((u >> 16) & 1u)) >> 16;   // RNE
  return (u16)r;
}
__device__ inline float bf2f(u16 h) { return __uint_as_float(((unsigned)h) << 16); }

// packed FMA: acc.{x,y} += pair.{x,y} * w.{x,y}  (one VOP3P instruction)
__device__ inline void pk_fma(v2f& acc, v2f pair, v2f w) {
  asm("v_pk_fma_f32 %0, %1, %2, %0" : "+v"(acc) : "v"(pair), "v"(w));
}
// unpack u32 (2 bf16) -> {lo, cheap-hi}; hi keeps low 16 bits as sub-ulp noise
__device__ inline v2f bfpair(unsigned w) {
  v2f p;
  p.x = __uint_as_float(w << 16);
  p.y = __uint_as_float(w);
  return p;
}

// ---------------- fused: bucketed LDS histogram + weight split + x->bf16 ----
// Blocks [0, HIST_BLOCKS): histogram + rank capture (LDS atomics only).
// Blocks [HIST_BLOCKS, +WPREP_BLOCKS): fp32 W[k][n] -> bf16 Wt{hi,lo}[n][k].
// Remaining blocks: x_tile/x_rr fp32 -> bf16 (streams; overlaps hist latency).
__global__ __launch_bounds__(512) void k_hist(
    const int* __restrict__ tt_src, const int* __restrict__ tt_dst,
    const int* __restrict__ rt_src, const int* __restrict__ rt_dst,
    const int* __restrict__ tr_src, const int* __restrict__ tr_dst,
    int* __restrict__ partial, int* __restrict__ rank,
    const float* __restrict__ W0, const float* __restrict__ W1,
    const float* __restrict__ W2, const float* __restrict__ W3,
    const float* __restrict__ W4,
    u16* __restrict__ T0h, u16* __restrict__ T0l,
    u16* __restrict__ T1h, u16* __restrict__ T1l,
    u16* __restrict__ T2h, u16* __restrict__ T2l,
    u16* __restrict__ T3h, u16* __restrict__ T3l,
    u16* __restrict__ T4h, u16* __restrict__ T4l,
    const float* __restrict__ xa, const float* __restrict__ xb,
    u16* __restrict__ oa, u16* __restrict__ ob) {
  __shared__ unsigned h[BKT / 2];
  int bid = blockIdx.x;
  if (bid >= HIST_BLOCKS) {
    int pb = bid - HIST_BLOCKS;
    if (pb < WPREP_BLOCKS) {
      int s = pb >> 5;                        // 32 blocks per weight
      int idx = ((pb & 31) << 9) + threadIdx.x;   // n*128+k
      const float* W = s == 0 ? W0 : (s == 1 ? W1 : (s == 2 ? W2 : (s == 3 ? W3 : W4)));
      u16* Th = s == 0 ? T0h : (s == 1 ? T1h : (s == 2 ? T2h : (s == 3 ? T3h : T4h)));
      u16* Tl = s == 0 ? T0l : (s == 1 ? T1l : (s == 2 ? T2l : (s == 3 ? T3l : T4l)));
      int n = idx >> 7, k = idx & 127;
      float w = W[k * 128 + n];
      u16 hh = f2bf(w);
      Th[idx] = hh;
      Tl[idx] = f2bf(w - bf2f(hh));
      return;
    }
    const size_t TOT = (size_t)N_TILE * D / 8;
    size_t i = (size_t)(pb - WPREP_BLOCKS) * 512 + threadIdx.x;
    if (i >= 2 * TOT) return;
    const float* src = (i < TOT) ? xa : xb;
    u16* dst = (i < TOT) ? oa : ob;
    size_t j = ((i < TOT) ? i : i - TOT) * 8;
    float4 v0 = *(const float4*)(src + j);
    float4 v1 = *(const float4*)(src + j + 4);
    ushort4 h0, h1;
    h0.x = f2bf(v0.x); h0.y = f2bf(v0.y); h0.z = f2bf(v0.z); h0.w = f2bf(v0.w);
    h1.x = f2bf(v1.x); h1.y = f2bf(v1.y); h1.z = f2bf(v1.z); h1.w = f2bf(v1.w);
    *(ushort4*)(dst + j) = h0;
    *(ushort4*)(dst + j + 4) = h1;
    return;
  }
  int s = bid / (NBKT * NCHK);
  int rem = bid % (NBKT * NCHK);
  int b = rem / NCHK;
  int c = rem % NCHK;
  const int* arr; int E; int roff = 0;
  switch (s) {
    case 0: arr = tt_dst; E = E_TT; roff = 0; break;
    case 1: arr = rt_dst; E = E_RT; roff = E_TT; break;
    case 2: arr = tr_dst; E = E_TR; roff = E_TT + E_RT; break;
    case 3: arr = tt_src; E = E_TT; break;
    case 4: arr = rt_src; E = E_RT; break;
    default: arr = tr_src; E = E_TR; break;
  }
  bool isdst = s < 3;
  for (int j = threadIdx.x; j < BKT / 2; j += 512) h[j] = 0;
  __syncthreads();
  int ec = E / NCHK;
  int lo = c * ec, hi = lo + ec;
  int base = b * BKT;
  for (int i = lo + threadIdx.x; i < hi; i += 512) {
    unsigned int off = (unsigned int)(arr[i] - base);
    if (off < BKT) {
      unsigned sh = (off & 1u) << 4;
      unsigned r = atomicAdd(&h[off >> 1], 1u << sh);
      if (isdst) rank[roff + i] = (int)((r >> sh) & 0xffffu);
    }
  }
  __syncthreads();
  int* dst = partial + (size_t)(s * NCHK + c) * N_TILE;
  for (int j = threadIdx.x; j < BKT; j += 512) {
    int bin = base + j;
    if (bin < N_TILE)
      dst[bin] = (int)((h[j >> 1] >> ((j & 1) << 4)) & 0xffffu);
  }
}

// ---------------- reduce partials ----------------
__global__ __launch_bounds__(256) void k_hreduce(
    int* __restrict__ partial,
    int* __restrict__ id_tt, int* __restrict__ id_rt, int* __restrict__ id_tr,
    float* __restrict__ os_tt, float* __restrict__ os_rt, float* __restrict__ os_tr) {
  int t = blockIdx.x * 256 + threadIdx.x;
  if (t >= 6 * N_TILE) return;
  int s = t / N_TILE;
  int i = t - s * N_TILE;
  int* p = partial + (size_t)s * NCHK * N_TILE + i;
  int run = 0;
  if (s < 3) {
#pragma unroll
    for (int c = 0; c < NCHK; ++c) {
      int v = p[(size_t)c * N_TILE];
      p[(size_t)c * N_TILE] = run;
      run += v;
    }
    if (s == 0) id_tt[i] = run;
    else if (s == 1) id_rt[i] = run;
    else id_tr[i] = run;
  } else {
#pragma unroll
    for (int c = 0; c < NCHK; ++c) run += p[(size_t)c * N_TILE];
    float v = rsqrtf((float)max(run, 1));
    if (s == 3) os_tt[i] = v;
    else if (s == 4) os_rt[i] = v;
    else os_tr[i] = v;
  }
}

// ---------------- scan stage 1 ----------------
__global__ __launch_bounds__(1024) void k_scan1(const int* __restrict__ d0,
                                                const int* __restrict__ d1,
                                                const int* __restrict__ d2,
                                                int* __restrict__ p0,
                                                int* __restrict__ p1,
                                                int* __restrict__ p2,
                                                int* __restrict__ bsum) {
  int arr = blockIdx.x / NB;
  int blk = blockIdx.x % NB;
  const int* deg = arr == 0 ? d0 : (arr == 1 ? d1 : d2);
  int* part = arr == 0 ? p0 : (arr == 1 ? p1 : p2);
  __shared__ int ts[1024];
  int tid = threadIdx.x;
  int i = blk * 1024 + tid;
  int v = (i < N_TILE) ? deg[i] : 0;
  ts[tid] = v;
  __syncthreads();
  for (int d = 1; d < 1024; d <<= 1) {
    int t = (tid >= d) ? ts[tid - d] : 0;
    __syncthreads();
    ts[tid] += t;
    __syncthreads();
  }
  if (i < N_TILE) part[i] = ts[tid] - v;
  if (tid == 1023) bsum[arr * NB + blk] = ts[1023];
}

// ---------------- finalize (inline block-sum scan) ----------------
// Each block re-derives the 49-entry exclusive prefix of bsum per array with
// a wave shfl-scan in LDS (cheap), then rp = part + prefix; ideg -> isc.
__global__ __launch_bounds__(256) void k_finalize(
    const int* __restrict__ pp_tt, const int* __restrict__ pp_rt,
    const int* __restrict__ pp_tr, const int* __restrict__ bsum,
    int* __restrict__ rp_tt, int* __restrict__ rp_rt, int* __restrict__ rp_tr,
    const int* __restrict__ id_tt, const int* __restrict__ id_rt,
    const int* __restrict__ id_tr,
    float* __restrict__ is_tt, float* __restrict__ is_rt,
    float* __restrict__ is_tr) {
  __shared__ int lbs[3][NB + 1];
  int tid = threadIdx.x;
  int wv = tid >> 6, lane = tid & 63;
  if (wv < 3) {
    int v = (lane < NB) ? bsum[wv * NB + lane] : 0;
    int orig = v;
#pragma unroll
    for (int o = 1; o < 64; o <<= 1) {
      int t = __shfl_up(v, o);
      if (lane >= o) v += t;
    }
    if (lane < NB) lbs[wv][lane] = v - orig;
    if (lane == NB - 1) lbs[wv][NB] = v;
  }
  __syncthreads();
  int i = blockIdx.x * blockDim.x + tid;
  if (i >= N_TILE) return;
  int b = i >> 10;
  rp_tt[i] = pp_tt[i] + lbs[0][b];
  rp_rt[i] = pp_rt[i] + lbs[1][b];
  rp_tr[i] = pp_tr[i] + lbs[2][b];
  if (i == 0) {
    rp_tt[N_TILE] = lbs[0][NB];
    rp_rt[N_TILE] = lbs[1][NB];
    rp_tr[N_RR] = lbs[2][NB];
  }
  is_tt[i] = rsqrtf((float)max(id_tt[i], 1));
  is_rt[i] = rsqrtf((float)max(id_rt[i], 1));
  is_tr[i] = rsqrtf((float)max(id_tr[i], 1));
}

// ---------------- CSR fill: one thread per edge, atomic-free ----------------
__global__ __launch_bounds__(256) void k_fill(
    const int* __restrict__ tt_src, const int* __restrict__ tt_dst,
    const int* __restrict__ rt_src, const int* __restrict__ rt_dst,
    const int* __restrict__ tr_src, const int* __restrict__ tr_dst,
    const int* __restrict__ rp_tt, const int* __restrict__ rp_rt,
    const int* __restrict__ rp_tr,
    const float* __restrict__ os_tt, const float* __restrict__ os_rt,
    const float* __restrict__ os_tr,
    const int* __restrict__ partial, const int* __restrict__ rank,
    int2* __restrict__ pr_tt, int2* __restrict__ pr_rt, int2* __restrict__ pr_tr) {
  int i = blockIdx.x * 256 + threadIdx.x;
  if (i >= E_ALL) return;
  const int* srcA; const int* dstA; const int* rp; const float* os; int2* pr;
  int j, s, ec;
  if (i < E_TT) {
    s = 0; j = i; ec = E_TT / NCHK;
    srcA = tt_src; dstA = tt_dst; rp = rp_tt; os = os_tt; pr = pr_tt;
  } else if (i < E_TT + E_RT) {
    s = 1; j = i - E_TT; ec = E_RT / NCHK;
    srcA = rt_src; dstA = rt_dst; rp = rp_rt; os = os_rt; pr = pr_rt;
  } else {
    s = 2; j = i - E_TT - E_RT; ec = E_TR / NCHK;
    srcA = tr_src; dstA = tr_dst; rp = rp_tr; os = os_tr; pr = pr_tr;
  }
  int d = dstA[j];
  int c = j / ec;
  int slot = rp[d] + partial[(size_t)(s * NCHK + c) * N_TILE + d] + rank[i];
  int sv = srcA[j];
  int2 v;
  v.x = sv;
  v.y = __float_as_int(os[sv]);
  pr[slot] = v;
}

// ---------------- fused aggregation (up to 3 relations) -> bf16 rows --------
// out[d][:] = bf16( isc[d] * sum_e w_e * x[src_e] );  x rows = bf16.
// Quarter q owns edge PAIR (e+2q, e+2q+1): ONE int4 load fetches both (src,w)
// descriptors; 2 row loads; 8 pk_fma. Bulk loop clamp-free.
__global__ __launch_bounds__(256) void k_agg3(
    const u16* __restrict__ x0, const int* __restrict__ rp0, const int2* __restrict__ pr0,
    const float* __restrict__ isc0, u16* __restrict__ oh0, int n0,
    const u16* __restrict__ x1, const int* __restrict__ rp1, const int2* __restrict__ pr1,
    const float* __restrict__ isc1, u16* __restrict__ oh1, int n1,
    const u16* __restrict__ x2, const int* __restrict__ rp2, const int2* __restrict__ pr2,
    const float* __restrict__ isc2, u16* __restrict__ oh2, int n2) {
  int gw = (blockIdx.x * blockDim.x + threadIdx.x) >> 6;
  int lane = threadIdx.x & 63;
  int q = lane >> 4;        // edge-pair slot
  int l4 = lane & 15;       // uint4 slot within the 256B row
  const u16* x; const int* rp; const int2* pr; const float* isc;
  u16* oh; int wid;
  if (gw < n0) { x = x0; rp = rp0; pr = pr0; isc = isc0; oh = oh0; wid = gw; }
  else if (gw < n0 + n1) { x = x1; rp = rp1; pr = pr1; isc = isc1; oh = oh1; wid = gw - n0; }
  else if (gw < n0 + n1 + n2) { x = x2; rp = rp2; pr = pr2; isc = isc2; oh = oh2; wid = gw - n0 - n1; }
  else return;
  int beg = rp[wid], end = rp[wid + 1];
  v2f a0[4], a1[4];
#pragma unroll
  for (int j = 0; j < 4; ++j) { a0[j] = (v2f){0.f, 0.f}; a1[j] = (v2f){0.f, 0.f}; }
  const uint4* xb = (const uint4*)x + l4;   // row = 128 bf16 = 16 uint4
  int nfull = (end - beg) & ~7;
  int efull = beg + nfull;
  for (int e = beg; e < efull; e += 8) {
    int4 pp = *(const int4*)(pr + e + 2 * q);   // 16B-aligned: e%8==0, 2q even
    v2f w02 = {__int_as_float(pp.y), __int_as_float(pp.y)};
    v2f w12 = {__int_as_float(pp.w), __int_as_float(pp.w)};
    uint4 u0 = xb[(size_t)pp.x * 16];
    uint4 u1 = xb[(size_t)pp.z * 16];
    pk_fma(a0[0], bfpair(u0.x), w02);
    pk_fma(a0[1], bfpair(u0.y), w02);
    pk_fma(a0[2], bfpair(u0.z), w02);
    pk_fma(a0[3], bfpair(u0.w), w02);
    pk_fma(a1[0], bfpair(u1.x), w12);
    pk_fma(a1[1], bfpair(u1.y), w12);
    pk_fma(a1[2], bfpair(u1.z), w12);
    pk_fma(a1[3], bfpair(u1.w), w12);
  }
  if (efull < end) {
    int lim = end - 1;
    int i0 = efull + 2 * q, i1 = i0 + 1;
    int2 p0 = pr[min(i0, lim)];
    int2 p1 = pr[min(i1, lim)];
    float w0 = (i0 < end) ? __int_as_float(p0.y) : 0.f;
    float w1 = (i1 < end) ? __int_as_float(p1.y) : 0.f;
    v2f w02 = {w0, w0}, w12 = {w1, w1};
    uint4 u0 = xb[(size_t)p0.x * 16];
    uint4 u1 = xb[(size_t)p1.x * 16];
    pk_fma(a0[0], bfpair(u0.x), w02);
    pk_fma(a0[1], bfpair(u0.y), w02);
    pk_fma(a0[2], bfpair(u0.z), w02);
    pk_fma(a0[3], bfpair(u0.w), w02);
    pk_fma(a1[0], bfpair(u1.x), w12);
    pk_fma(a1[1], bfpair(u1.y), w12);
    pk_fma(a1[2], bfpair(u1.z), w12);
    pk_fma(a1[3], bfpair(u1.w), w12);
  }
  float s[8];
#pragma unroll
  for (int j = 0; j < 4; ++j) {
    v2f t = a0[j] + a1[j];
    s[2 * j] = t.x;
    s[2 * j + 1] = t.y;
  }
#pragma unroll
  for (int j = 0; j < 8; ++j) {
    s[j] += __shfl_xor(s[j], 16);
    s[j] += __shfl_xor(s[j], 32);
  }
  if (q == 0) {
    float iv = isc[wid];
    unsigned hb[8];
#pragma unroll
    for (int j = 0; j < 8; ++j) hb[j] = f2bf(s[j] * iv);
    uint4 hw;
    hw.x = hb[0] | (hb[1] << 16); hw.y = hb[2] | (hb[3] << 16);
    hw.z = hb[4] | (hb[5] << 16); hw.w = hb[6] | (hb[7] << 16);
    *(uint4*)(oh + (size_t)wid * D + l4 * 8) = hw;
  }
}

// ---------------- MFMA bf16 GEMM(+GEMM) + bias + relu ----------------
// out = relu( A1@W1 (+ A2@W2) + b1 (+ b2) ); OBF: output bf16 rows, else fp32.
// C = A@Whi + A@Wlo (weight split kept: W rounding is systematic).
template<int NREL, bool OBF>
__global__ __launch_bounds__(256) void k_gemm_m(
    const u16* __restrict__ A1, const u16* __restrict__ A2,
    const u16* __restrict__ Wt1h, const u16* __restrict__ Wt1l,
    const u16* __restrict__ Wt2h, const u16* __restrict__ Wt2l,
    const float* __restrict__ b1, const float* __restrict__ b2,
    void* __restrict__ outv, int nrows) {
  __shared__ u16 Ah[128][40];   // pad 40: 2-way-only LDS conflicts on b128 reads
  __shared__ u16 Wh[128][40];   // [n][k]
  __shared__ u16 Wl[128][40];
  int tid = threadIdx.x;
  int wv = tid >> 6, lane = tid & 63;
  int l15 = lane & 15, lg = lane >> 4;
  int r0 = blockIdx.x * 128;
  f32x4 acc[2][8];
#pragma unroll
  for (int i = 0; i < 2; ++i)
#pragma unroll
    for (int j = 0; j < 8; ++j) acc[i][j] = (f32x4){0.f, 0.f, 0.f, 0.f};

  int srow = tid >> 1;             // 0..127
  int c0 = (tid & 1) * 16;         // u16 col base 0 or 16
  int gr = r0 + srow;

  for (int rel = 0; rel < NREL; ++rel) {
    const u16* pA = (NREL == 2 && rel) ? A2 : A1;
    const u16* pWh = (NREL == 2 && rel) ? Wt2h : Wt1h;
    const u16* pWl = (NREL == 2 && rel) ? Wt2l : Wt1l;
    for (int k0 = 0; k0 < 128; k0 += 32) {
      __syncthreads();
      uint4 z = {0, 0, 0, 0};
      uint4 va0 = z, va1 = z;
      if (gr < nrows) {
        va0 = *(const uint4*)(pA + (size_t)gr * 128 + k0 + c0);
        va1 = *(const uint4*)(pA + (size_t)gr * 128 + k0 + c0 + 8);
      }
      *(uint4*)&Ah[srow][c0] = va0;
      *(uint4*)&Ah[srow][c0 + 8] = va1;
      *(uint4*)&Wh[srow][c0]     = *(const uint4*)(pWh + (size_t)srow * 128 + k0 + c0);
      *(uint4*)&Wh[srow][c0 + 8] = *(const uint4*)(pWh + (size_t)srow * 128 + k0 + c0 + 8);
      *(uint4*)&Wl[srow][c0]     = *(const uint4*)(pWl + (size_t)srow * 128 + k0 + c0);
      *(uint4*)&Wl[srow][c0 + 8] = *(const uint4*)(pWl + (size_t)srow * 128 + k0 + c0 + 8);
      __syncthreads();
      bf16x8 a0 = *(const bf16x8*)&Ah[wv * 32 + l15][lg * 8];
      bf16x8 a1 = *(const bf16x8*)&Ah[wv * 32 + 16 + l15][lg * 8];
#pragma unroll
      for (int ct = 0; ct < 8; ++ct) {
        bf16x8 bh = *(const bf16x8*)&Wh[ct * 16 + l15][lg * 8];
        bf16x8 bl = *(const bf16x8*)&Wl[ct * 16 + l15][lg * 8];
        acc[0][ct] = __builtin_amdgcn_mfma_f32_16x16x32_bf16(a0, bh, acc[0][ct], 0, 0, 0);
        acc[0][ct] = __builtin_amdgcn_mfma_f32_16x16x32_bf16(a0, bl, acc[0][ct], 0, 0, 0);
        acc[1][ct] = __builtin_amdgcn_mfma_f32_16x16x32_bf16(a1, bh, acc[1][ct], 0, 0, 0);
        acc[1][ct] = __builtin_amdgcn_mfma_f32_16x16x32_bf16(a1, bl, acc[1][ct], 0, 0, 0);
      }
    }
  }
  // epilogue: bias + relu; C layout col=lane&15, row=(lane>>4)*4+reg
#pragma unroll
  for (int ct = 0; ct < 8; ++ct) {
    int col = ct * 16 + l15;
    float bias = b1[col];
    if (NREL == 2) bias += b2[col];
#pragma unroll
    for (int rt = 0; rt < 2; ++rt) {
      int rowb = r0 + wv * 32 + rt * 16 + lg * 4;
#pragma unroll
      for (int r = 0; r < 4; ++r) {
        int row = rowb + r;
        if (row < nrows) {
          float v = fmaxf(acc[rt][ct][r] + bias, 0.f);
          if (OBF) ((u16*)outv)[(size_t)row * 128 + col] = f2bf(v);
          else ((float*)outv)[(size_t)row * 128 + col] = v;
        }
      }
    }
  }
}

// ---------------- per-graph mean pooling: 8 rows parallel, float4 cols ------
#define PCHUNK 256
__global__ __launch_bounds__(256) void k_pool(const float* __restrict__ H,
                                              const int* __restrict__ gid,
                                              float* __restrict__ sums,
                                              float* __restrict__ cnt, int n) {
  __shared__ float4 red[256];
  int tid = threadIdx.x;
  int c4 = tid & 31;        // float4 slot (32 x 4 = 128 cols)
  int slot = tid >> 5;      // 0..7 parallel row slots
  int start = blockIdx.x * PCHUNK;
  if (start >= n) return;
  int end = min(start + PCHUNK, n);
  if (gid[start] == gid[end - 1]) {
    int g = gid[start];
    float4 acc = make_float4(0.f, 0.f, 0.f, 0.f);
    for (int r = start + slot; r < end; r += 8) {
      float4 v = *(const float4*)(H + (size_t)r * D + c4 * 4);
      acc.x += v.x; acc.y += v.y; acc.z += v.z; acc.w += v.w;
    }
    red[tid] = acc;
    __syncthreads();
    if (slot == 0) {
      float4 a = red[c4];
#pragma unroll
      for (int s2 = 1; s2 < 8; ++s2) {
        float4 b = red[s2 * 32 + c4];
        a.x += b.x; a.y += b.y; a.z += b.z; a.w += b.w;
      }
      float* p = &sums[g * D + c4 * 4];
      atomicAdd(p + 0, a.x); atomicAdd(p + 1, a.y);
      atomicAdd(p + 2, a.z); atomicAdd(p + 3, a.w);
      if (c4 == 0) atomicAdd(&cnt[g], (float)(end - start));
    }
    return;
  }
  float4 acc = make_float4(0.f, 0.f, 0.f, 0.f);
  int cur = -1, cl = 0;
  for (int r = start + slot; r < end; r += 8) {
    int g = gid[r];
    if (g != cur) {
      if (cur >= 0) {
        float* p = &sums[cur * D + c4 * 4];
        atomicAdd(p + 0, acc.x); atomicAdd(p + 1, acc.y);
        atomicAdd(p + 2, acc.z); atomicAdd(p + 3, acc.w);
        if (c4 == 0) atomicAdd(&cnt[cur], (float)cl);
      }
      acc = make_float4(0.f, 0.f, 0.f, 0.f); cl = 0; cur = g;
    }
    float4 v = *(const float4*)(H + (size_t)r * D + c4 * 4);
    acc.x += v.x; acc.y += v.y; acc.z += v.z; acc.w += v.w;
    cl++;
  }
  if (cur >= 0) {
    float* p = &sums[cur * D + c4 * 4];
    atomicAdd(p + 0, acc.x); atomicAdd(p + 1, acc.y);
    atomicAdd(p + 2, acc.z); atomicAdd(p + 3, acc.w);
    if (c4 == 0) atomicAdd(&cnt[cur], (float)cl);
  }
}

// ---------------- final MLP on [16,128] ----------------
__global__ __launch_bounds__(256) void k_final(const float* __restrict__ sums,
                                               const float* __restrict__ cnt,
                                               const float* __restrict__ Wm1,
                                               const float* __restrict__ bm1,
                                               const float* __restrict__ Wm2,
                                               const float* __restrict__ bm2,
                                               float* __restrict__ out) {
  __shared__ float hg[16][128];
  __shared__ float t1[16][128];
  int tid = threadIdx.x;
  for (int i = tid; i < 16 * 128; i += 256) {
    int g = i >> 7, c = i & 127;
    hg[g][c] = sums[i] / fmaxf(cnt[g], 1.f);
  }
  __syncthreads();
  for (int i = tid; i < 16 * 128; i += 256) {
    int g = i >> 7, c = i & 127;
    float a = bm1[c];
    for (int k = 0; k < 128; ++k) a = fmaf(hg[g][k], Wm1[k * 128 + c], a);
    t1[g][c] = fmaxf(a, 0.f);
  }
  __syncthreads();
  int g = tid >> 4, l = tid & 15;
  float p = 0.f;
  for (int c = l; c < 128; c += 16) p = fmaf(t1[g][c], Wm2[c], p);
#pragma unroll
  for (int o = 8; o; o >>= 1) p += __shfl_down(p, o, 16);
  if (l == 0) out[g] = p + bm2[0];
}

extern "C" void kernel_launch(void* const* d_in, const int* in_sizes, int n_in,
                              void* d_out, int out_size, void* d_ws, size_t ws_size,
                              hipStream_t stream) {
  const float* x_tile = (const float*)d_in[0];
  const float* x_rr   = (const float*)d_in[1];
  const int* tt_src = (const int*)d_in[2];
  const int* tt_dst = (const int*)d_in[3];
  const int* rt_src = (const int*)d_in[4];
  const int* rt_dst = (const int*)d_in[5];
  const int* tr_src = (const int*)d_in[6];
  const int* tr_dst = (const int*)d_in[7];
  const int* tile_gid = (const int*)d_in[8];
  const float* W1_tt = (const float*)d_in[9];  const float* b1_tt = (const float*)d_in[10];
  const float* W1_rt = (const float*)d_in[11]; const float* b1_rt = (const float*)d_in[12];
  const float* W1_tr = (const float*)d_in[13]; const float* b1_tr = (const float*)d_in[14];
  const float* W2_tt = (const float*)d_in[15]; const float* b2_tt = (const float*)d_in[16];
  const float* W2_rt = (const float*)d_in[17]; const float* b2_rt = (const float*)d_in[18];
  const float* Wm1 = (const float*)d_in[21]; const float* bm1 = (const float*)d_in[22];
  const float* Wm2 = (const float*)d_in[23]; const float* bm2 = (const float*)d_in[24];

  char* ws = (char*)d_ws;
  size_t off = 0;
  auto allocB = [&](size_t bytes) {
    void* p = ws + off;
    off += (bytes + 255) & ~(size_t)255;
    return p;
  };
  // ---- zero region (memset each call) ----
  float* psum = (float*)allocB(N_G * D * 4);
  float* pcnt = (float*)allocB(N_G * 4);
  size_t zero_bytes = off;
  // ---- rest (all fully written before read) ----
  int* partial = (int*)allocB((size_t)6 * NCHK * N_TILE * 4);
  int* rank = (int*)allocB((size_t)E_ALL * 4);
  int* ideg_tt = (int*)allocB(N_TILE * 4);
  int* ideg_rt = (int*)allocB(N_TILE * 4);
  int* ideg_tr = (int*)allocB(N_RR * 4);
  int* pp_tt = (int*)allocB(N_TILE * 4);
  int* pp_rt = (int*)allocB(N_TILE * 4);
  int* pp_tr = (int*)allocB(N_RR * 4);
  int* bsum = (int*)allocB(3 * NB * 4);
  int* rp_tt = (int*)allocB((N_TILE + 1) * 4);
  int* rp_rt = (int*)allocB((N_TILE + 1) * 4);
  int* rp_tr = (int*)allocB((N_RR + 1) * 4);
  int2* pr_tt = (int2*)allocB((size_t)E_TT * 8);
  int2* pr_rt = (int2*)allocB((size_t)E_RT * 8);
  int2* pr_tr = (int2*)allocB((size_t)E_TR * 8);
  float* osc_tt = (float*)allocB(N_TILE * 4);
  float* osc_rt = (float*)allocB(N_RR * 4);
  float* osc_tr = (float*)allocB(N_TILE * 4);
  float* isc_tt = (float*)allocB(N_TILE * 4);
  float* isc_rt = (float*)allocB(N_TILE * 4);
  float* isc_tr = (float*)allocB(N_RR * 4);
  u16* xt_bf = (u16*)allocB((size_t)N_TILE * D * 2);
  u16* xr_bf = (u16*)allocB((size_t)N_RR * D * 2);
  u16* Abf = (u16*)allocB((size_t)N_TILE * D * 2);
  u16* Bbf = (u16*)allocB((size_t)N_TILE * D * 2);
  u16* Cbf = (u16*)allocB((size_t)N_RR * D * 2);
  u16* Ht_bf = (u16*)allocB((size_t)N_TILE * D * 2);   // layer-1 tile output (bf16)
  u16* Hr_bf = (u16*)allocB((size_t)N_RR * D * 2);     // layer-1 rr output (bf16)
  float* Htile = (float*)allocB((size_t)N_TILE * D * 4); // layer-2 output (fp32, pooled)
  u16* Wt1tt_h = (u16*)allocB(D * D * 2); u16* Wt1tt_l = (u16*)allocB(D * D * 2);
  u16* Wt1rt_h = (u16*)allocB(D * D * 2); u16* Wt1rt_l = (u16*)allocB(D * D * 2);
  u16* Wt1tr_h = (u16*)allocB(D * D * 2); u16* Wt1tr_l = (u16*)allocB(D * D * 2);
  u16* Wt2tt_h = (u16*)allocB(D * D * 2); u16* Wt2tt_l = (u16*)allocB(D * D * 2);
  u16* Wt2rt_h = (u16*)allocB(D * D * 2); u16* Wt2rt_l = (u16*)allocB(D * D * 2);
  (void)ws_size; (void)in_sizes; (void)n_in; (void)out_size;

  hipMemsetAsync(d_ws, 0, zero_bytes, stream);

  // ---- fused: CSR histogram + weight split + x->bf16 (overlapped) ----
  k_hist<<<HIST_BLOCKS + WPREP_BLOCKS + CONV_BLOCKS, 512, 0, stream>>>(
      tt_src, tt_dst, rt_src, rt_dst, tr_src, tr_dst, partial, rank,
      W1_tt, W1_rt, W1_tr, W2_tt, W2_rt,
      Wt1tt_h, Wt1tt_l, Wt1rt_h, Wt1rt_l, Wt1tr_h, Wt1tr_l,
      Wt2tt_h, Wt2tt_l, Wt2rt_h, Wt2rt_l,
      x_tile, x_rr, xt_bf, xr_bf);
  k_hreduce<<<(6 * N_TILE + 255) / 256, 256, 0, stream>>>(
      partial, ideg_tt, ideg_rt, ideg_tr, osc_tt, osc_rt, osc_tr);
  k_scan1<<<3 * NB, 1024, 0, stream>>>(ideg_tt, ideg_rt, ideg_tr, pp_tt, pp_rt, pp_tr, bsum);
  k_finalize<<<(N_TILE + 255) / 256, 256, 0, stream>>>(
      pp_tt, pp_rt, pp_tr, bsum, rp_tt, rp_rt, rp_tr,
      ideg_tt, ideg_rt, ideg_tr, isc_tt, isc_rt, isc_tr);
  k_fill<<<(E_ALL + 255) / 256, 256, 0, stream>>>(
      tt_src, tt_dst, rt_src, rt_dst, tr_src, tr_dst,
      rp_tt, rp_rt, rp_tr, osc_tt, osc_rt, osc_tr,
      partial, rank, pr_tt, pr_rt, pr_tr);

  const int gemmBlocks = (N_TILE + 127) / 128;

  // ---- layer 1: all three aggs fused, bf16 gather -> bf16 rows ----
  {
    int totw = N_TILE + N_TILE + N_RR;
    k_agg3<<<(totw * 64 + 255) / 256, 256, 0, stream>>>(
        xt_bf, rp_tt, pr_tt, isc_tt, Abf, N_TILE,
        xr_bf, rp_rt, pr_rt, isc_rt, Bbf, N_TILE,
        xt_bf, rp_tr, pr_tr, isc_tr, Cbf, N_RR);
  }
  k_gemm_m<1, true><<<gemmBlocks, 256, 0, stream>>>(
      Cbf, nullptr, Wt1tr_h, Wt1tr_l, nullptr, nullptr,
      b1_tr, nullptr, Hr_bf, N_RR);
  k_gemm_m<2, true><<<gemmBlocks, 256, 0, stream>>>(
      Abf, Bbf, Wt1tt_h, Wt1tt_l, Wt1rt_h, Wt1rt_l,
      b1_tt, b1_rt, Ht_bf, N_TILE);

  // ---- layer 2: bf16 gather of layer-1 outputs (tr relation skipped) ----
  {
    int totw = N_TILE + N_TILE;
    k_agg3<<<(totw * 64 + 255) / 256, 256, 0, stream>>>(
        Ht_bf, rp_tt, pr_tt, isc_tt, Abf, N_TILE,
        Hr_bf, rp_rt, pr_rt, isc_rt, Bbf, N_TILE,
        nullptr, nullptr, nullptr, nullptr, nullptr, 0);
  }
  k_gemm_m<2, false><<<gemmBlocks, 256, 0, stream>>>(
      Abf, Bbf, Wt2tt_h, Wt2tt_l, Wt2rt_h, Wt2rt_l,
      b2_tt, b2_rt, Htile, N_TILE);

  // ---- pooling + MLP head ----
  k_pool<<<(N_TILE + PCHUNK - 1) / PCHUNK, 256, 0, stream>>>(Htile, tile_gid, psum, pcnt, N_TILE);
  k_final<<<1, 256, 0, stream>>>(psum, pcnt, Wm1, bm1, Wm2, bm2, (float*)d_out);
}